// Round 11
// baseline (332.663 us; speedup 1.0000x reference)
//
#include <hip/hip_runtime.h>
#include <hip/hip_bf16.h>
#include <math.h>

typedef __hip_bfloat16 bf16;
typedef __attribute__((ext_vector_type(8))) short short8;   // 8 bf16 (4 VGPRs)
typedef __attribute__((ext_vector_type(4))) float f32x4;
typedef __attribute__((ext_vector_type(2))) float f32x2;
#define DEVINL __device__ __forceinline__

constexpr int Bc  = 2;
constexpr int Nc  = 768;
constexpr int Dc  = 512;
constexpr int Hc  = 8;
constexpr int DKc = 64;
constexpr int BHc = Bc * Hc;
constexpr float SCALE    = 0.125f;   // 1/sqrt(64)
constexpr float EPSF     = 1e-6f;
constexpr float BETA_NOT = 0.5f;

DEVINL float ldf(const float* p, long i) { return p[i]; }
DEVINL float ldf(const bf16* p, long i) { return __bfloat162float(p[i]); }
DEVINL void stf(float* p, long i, float v) { p[i] = v; }
DEVINL void stf(bf16* p, long i, float v) { p[i] = __float2bfloat16(v); }

DEVINL float sigf(float x) { return __fdividef(1.f, 1.f + __expf(-x)); }

// packed fp32 pair helpers — backend selects v_pk_fma_f32/v_pk_mul_f32 (r3:
// validated -41% on gates_smix; r4 pair-dup operands -12%; r5 s_load weights).
DEVINL f32x2 fma2(f32x2 a, f32x2 b, f32x2 c) { return __builtin_elementwise_fma(a, b, c); }
DEVINL f32x2 splat2(float x) { return (f32x2){x, x}; }
// guard-free transcendentals (libm exp2f adds a denormal guard: +13% in r2)
DEVINL float vexp2(float x) { float r; asm("v_exp_f32 %0, %1" : "=v"(r) : "v"(x)); return r; }
DEVINL float vrcp(float x)  { float r; asm("v_rcp_f32 %0, %1" : "=v"(r) : "v"(x)); return r; }
DEVINL float vlog2(float x) { float r; asm("v_log_f32 %0, %1" : "=v"(r) : "v"(x)); return r; }

// async global->LDS, 16B per lane; LDS dest = wave-uniform base + lane*16.
DEVINL void gl_lds16(const void* g, void* l) {
    __builtin_amdgcn_global_load_lds(
        (const __attribute__((address_space(1))) void*)g,
        (__attribute__((address_space(3))) void*)l, 16, 0, 0);
}

// ---------------------------------------------------------------------------
// Dtype sniffer — vectorized (validated round 9).
// ---------------------------------------------------------------------------
DEVINL int sniff_is_fp32(const void* xraw) {
    const uint4* p4 = (const uint4*)xraw;
    float mx = 0.f;
#pragma unroll
    for (int j = 0; j < 16; ++j) {
        const uint4 u = p4[j];
        const unsigned w[4] = {u.x, u.y, u.z, u.w};
#pragma unroll
        for (int t = 0; t < 4; ++t) {
            mx = fmaxf(mx, fabsf(__uint_as_float((w[t] & 0xffffu) << 16)));
            mx = fmaxf(mx, fabsf(__uint_as_float(w[t] & 0xffff0000u)));
        }
    }
    return mx > 1000.f ? 1 : 0;
}

DEVINL float cvt_elem(const void* s, long j, int is32) {
    return is32 ? ((const float*)s)[j]
                : __bfloat162float(((const bf16*)s)[j]);
}

// smallf layout (round 15 — PAIR-DUPLICATED; read via uniform scalar loads):
//   [u*24 + 2k+{0,1}]  = w1[u][k]          k=0..5   (12 floats)
//   [u*24 + 12..13]    = b1[u] pair
//   [u*24 + 14..15]    = pad
//   [u*24 + 16 + 2o+{0,1}] = conv2_w[o][u] o=0..3   (8 floats)
//   [384..391]  conv2_b[o] pairs
//   [392..393]  chain_logit pair          (combine reads [392])
__global__ __launch_bounds__(256) void convert_all(
    const void* x, const void* w1, const void* w2, const void* pw,
    const void* c1w, const void* c1b, const void* c2w, const void* c2b,
    const void* ch,
    bf16* xb, bf16* w1b, bf16* w2b, bf16* pwb, float* smallf)
{
    __shared__ int is32s;
    if (threadIdx.x == 0) is32s = sniff_is_fp32(x);
    __syncthreads();
    const int is32 = is32s;
    const long i = (long)blockIdx.x * 256 + threadIdx.x;
    if (i < (long)Bc * Nc * Dc) {
        xb[i]  = __float2bfloat16(cvt_elem(x,  i, is32));
        w1b[i] = __float2bfloat16(cvt_elem(w1, i, is32));
        w2b[i] = __float2bfloat16(cvt_elem(w2, i, is32));
    }
    if (i < (long)Dc * Dc) pwb[i] = __float2bfloat16(cvt_elem(pw, i, is32));
    if (i < 384) {
        const int u = (int)i / 24, k = (int)i % 24;
        float v = 0.f;
        if (k < 12)      v = cvt_elem(c1w, u * 6 + (k >> 1), is32);
        else if (k < 14) v = cvt_elem(c1b, u, is32);
        else if (k >= 16) { const int o = (k - 16) >> 1; v = cvt_elem(c2w, o * 16 + u, is32); }
        smallf[i] = v;
    } else if (i < 392) smallf[i] = cvt_elem(c2b, ((int)i - 384) >> 1, is32);
    else if (i < 394) smallf[i] = cvt_elem(ch, 0, is32);
    else if (i < 512) smallf[i] = 0.f;
}

__global__ __launch_bounds__(256) void fill_sentinel(unsigned short* o) {
    const long i = (long)blockIdx.x * 256 + threadIdx.x;
    if (i < (long)Bc * Nc * Dc) o[i] = 0x40E0;  // bf16 7.0
}

// ---------------------------------------------------------------------------
// Generic bf16 transpose, 64x64 tiles: dst[c][r] = src[r][c]; src is (R,C).
// ---------------------------------------------------------------------------
__global__ __launch_bounds__(256) void transpose_bf16(
    const unsigned short* __restrict__ src, unsigned short* __restrict__ dst,
    int R, int C, long sS, long sD)
{
    __shared__ unsigned short tile[64][68];
    const unsigned short* s = src + (long)blockIdx.z * sS;
    unsigned short* d = dst + (long)blockIdx.z * sD;
    const int r0 = blockIdx.y * 64, c0 = blockIdx.x * 64;
    const int t = threadIdx.x;
    const int lr = t >> 4, lc4 = (t & 15) * 4;
#pragma unroll
    for (int i = 0; i < 4; ++i) {
        int r = lr + i * 16;
        *(uint2*)&tile[r][lc4] = *(const uint2*)&s[(long)(r0 + r) * C + c0 + lc4];
    }
    __syncthreads();
#pragma unroll
    for (int i = 0; i < 4; ++i) {
        int r = lr + i * 16;
        unsigned short v[4];
#pragma unroll
        for (int j = 0; j < 4; ++j) v[j] = tile[lc4 + j][r];
        *(uint2*)&d[(long)(c0 + r) * R + r0 + lc4] = *(uint2*)v;
    }
}

// ---------------------------------------------------------------------------
// Round 23: merged W + pw transpose — one launch (z=0,1: W sets; z=2: pw).
// ---------------------------------------------------------------------------
__global__ __launch_bounds__(256) void transpose_wpw(
    const unsigned short* __restrict__ wb, unsigned short* __restrict__ wt,
    const unsigned short* __restrict__ pwb, unsigned short* __restrict__ pwt)
{
    __shared__ unsigned short tile[64][68];
    const int z = blockIdx.z;
    const unsigned short* s;
    unsigned short* d;
    int R, C;
    if (z < 2) {
        s = wb + (long)z * (Dc * 3 * Dc);
        d = wt + (long)z * (Dc * 3 * Dc);
        R = Dc; C = 3 * Dc;
    } else {
        if (blockIdx.x >= 8) return;
        s = pwb; d = pwt; R = Dc; C = Dc;
    }
    const int r0 = blockIdx.y * 64, c0 = blockIdx.x * 64;
    const int t = threadIdx.x;
    const int lr = t >> 4, lc4 = (t & 15) * 4;
#pragma unroll
    for (int i = 0; i < 4; ++i) {
        int r = lr + i * 16;
        *(uint2*)&tile[r][lc4] = *(const uint2*)&s[(long)(r0 + r) * C + c0 + lc4];
    }
    __syncthreads();
#pragma unroll
    for (int i = 0; i < 4; ++i) {
        int r = lr + i * 16;
        unsigned short v[4];
#pragma unroll
        for (int j = 0; j < 4; ++j) v[j] = tile[lc4 + j][r];
        *(uint2*)&d[(long)(c0 + r) * R + r0 + lc4] = *(uint2*)v;
    }
}

// ---------------------------------------------------------------------------
// Round 22 (validated): FUSED S-GEMM + row softmax + A-transpose.
// ---------------------------------------------------------------------------
__global__ __launch_bounds__(256) void sgemm_softmax(
    const bf16* __restrict__ qg, const bf16* __restrict__ kg,
    float* __restrict__ Sg, bf16* __restrict__ Ag_, bf16* __restrict__ Atg)
{
    __shared__ unsigned short Bsm[256 * 72];   // 36 KB; aliased for A^T stage
    __shared__ unsigned short Asm16[16 * 72];  // 2.25 KB
    __shared__ float red[4][16];

    const int wg  = blockIdx.x;
    const int xcd = wg & 7, tt = wg >> 3;
    const int z   = xcd + 8 * (tt / 48);
    const int by  = tt % 48;
    const long MAT = (long)Nc * Nc;

    const bf16* Q  = qg + (long)z * (Nc * DKc) + (long)(by * 16) * DKc;
    const bf16* Km = kg + (long)z * (Nc * DKc);
    float* S  = Sg  + (long)z * MAT + (long)(by * 16) * Nc;
    bf16*  A  = Ag_ + (long)z * MAT + (long)(by * 16) * Nc;
    bf16*  At = Atg + (long)z * MAT;           // write At[m][by*16 + n]

    const int tid  = threadIdx.x;
    const int wv   = tid >> 6;
    const int lane = tid & 63;
    const int q    = lane >> 4;
    const int ln   = lane & 15;
    const int sr   = tid >> 3, k8 = tid & 7;

    if (tid < 128) {
        const int row = tid >> 3, kk = tid & 7;
        *(uint4*)&Asm16[row * 72 + kk * 8] = *(const uint4*)&Q[row * 64 + kk * 8];
    }

    f32x4 acc[12];
#pragma unroll
    for (int j = 0; j < 12; ++j) acc[j] = (f32x4){0.f, 0.f, 0.f, 0.f};

    for (int c = 0; c < 3; ++c) {
        __syncthreads();
#pragma unroll
        for (int i = 0; i < 8; ++i) {
            const int row = sr + i * 32;
            *(uint4*)&Bsm[row * 72 + k8 * 8] =
                *(const uint4*)&Km[(long)(c * 256 + row) * 64 + k8 * 8];
        }
        __syncthreads();
#pragma unroll
        for (int kc = 0; kc < 2; ++kc) {
            const short8 af = *(const short8*)&Asm16[ln * 72 + kc * 32 + q * 8];
#pragma unroll
            for (int t = 0; t < 4; ++t) {
                const int nl = wv * 64 + t * 16 + ln;
                const short8 bfr = *(const short8*)&Bsm[nl * 72 + kc * 32 + q * 8];
                acc[c * 4 + t] = __builtin_amdgcn_mfma_f32_16x16x32_bf16(
                    af, bfr, acc[c * 4 + t], 0, 0, 0);
            }
        }
    }

    float mrow[4] = {-1e30f, -1e30f, -1e30f, -1e30f};
#pragma unroll
    for (int j = 0; j < 12; ++j) {
        const int c = j >> 2, t = j & 3;
        const int col = c * 256 + wv * 64 + t * 16 + ln;
#pragma unroll
        for (int r = 0; r < 4; ++r) {
            const float v = acc[j][r] * SCALE;
            acc[j][r] = v;
            S[(long)(q * 4 + r) * Nc + col] = v;
            mrow[r] = fmaxf(mrow[r], v);
        }
    }
#pragma unroll
    for (int off = 8; off > 0; off >>= 1)
#pragma unroll
        for (int r = 0; r < 4; ++r)
            mrow[r] = fmaxf(mrow[r], __shfl_xor(mrow[r], off, 16));
    if (ln == 0)
#pragma unroll
        for (int r = 0; r < 4; ++r) red[wv][q * 4 + r] = mrow[r];
    __syncthreads();
    float m4[4];
#pragma unroll
    for (int r = 0; r < 4; ++r)
        m4[r] = fmaxf(fmaxf(red[0][q * 4 + r], red[1][q * 4 + r]),
                      fmaxf(red[2][q * 4 + r], red[3][q * 4 + r]));
    __syncthreads();

    float srow[4] = {0.f, 0.f, 0.f, 0.f};
#pragma unroll
    for (int j = 0; j < 12; ++j)
#pragma unroll
        for (int r = 0; r < 4; ++r) {
            const float e = __expf(acc[j][r] - m4[r]);
            acc[j][r] = e;
            srow[r] += e;
        }
#pragma unroll
    for (int off = 8; off > 0; off >>= 1)
#pragma unroll
        for (int r = 0; r < 4; ++r)
            srow[r] += __shfl_xor(srow[r], off, 16);
    if (ln == 0)
#pragma unroll
        for (int r = 0; r < 4; ++r) red[wv][q * 4 + r] = srow[r];
    __syncthreads();
    float inv[4];
#pragma unroll
    for (int r = 0; r < 4; ++r)
        inv[r] = 1.f / fmaxf(red[0][q * 4 + r] + red[1][q * 4 + r] +
                             red[2][q * 4 + r] + red[3][q * 4 + r], 1e-30f);

    unsigned short* ATl = Bsm;   // 768*20*2 = 30.7 KB <= 36 KB
#pragma unroll
    for (int j = 0; j < 12; ++j) {
        const int c = j >> 2, t = j & 3;
        const int col = c * 256 + wv * 64 + t * 16 + ln;
#pragma unroll
        for (int r = 0; r < 4; ++r) {
            const bf16 b = __float2bfloat16(acc[j][r] * inv[r]);
            const unsigned short u = *(const unsigned short*)&b;
            A[(long)(q * 4 + r) * Nc + col] = *(const bf16*)&u;
            ATl[col * 20 + q * 4 + r] = u;
        }
    }
    __syncthreads();
#pragma unroll
    for (int s = 0; s < 3; ++s) {
        const int m = tid + s * 256;
        uint2 v0 = *(const uint2*)&ATl[m * 20 + 0];
        uint2 v1 = *(const uint2*)&ATl[m * 20 + 4];
        uint2 v2 = *(const uint2*)&ATl[m * 20 + 8];
        uint2 v3 = *(const uint2*)&ATl[m * 20 + 12];
        unsigned short* d = (unsigned short*)&At[(long)m * Nc + by * 16];
        *(uint2*)&d[0]  = v0;
        *(uint2*)&d[4]  = v1;
        *(uint2*)&d[8]  = v2;
        *(uint2*)&d[12] = v3;
    }
}

// ---------------------------------------------------------------------------
// MFMA bf16 NT GEMM — 2-phase double-buffered K-loop (validated r7).
// ---------------------------------------------------------------------------
template <int EPI, typename TC, int XORB = 0, int XCDSWZ = 0, int RAW = 0>
__global__ __launch_bounds__(256) void gemm_nt_mfma(
    const bf16* __restrict__ Ag, const bf16* __restrict__ Btg,
    TC* __restrict__ Cg, bf16* __restrict__ Craw, int M, int N, int K,
    long sA, long sB, long sC, float alpha)
{
    __shared__ unsigned short Asm[2 * 128 * 32];
    __shared__ unsigned short Bsm[2 * 128 * 32];
    constexpr int BUF = 128 * 32;   // elements per buffer

    int bx, by, bz;
    if (XCDSWZ) {
        const int wg = blockIdx.x;
        const int xcd = wg & 7, t = wg >> 3;
        bz = xcd + 8 * (t / 36);
        const int tile = t % 36;
        bx = tile % 6; by = tile / 6;
    } else { bx = blockIdx.x; by = blockIdx.y; bz = blockIdx.z; }

    const int tid  = threadIdx.x;
    const int wv   = tid >> 6;
    const int lane = tid & 63;
    const int q    = lane >> 4;
    const int ln   = lane & 15;
    const int wm   = wv & 1;
    const int wn   = wv >> 1;

    const int zb = XORB ? (bz ^ 16) : bz;
    const bf16* A  = Ag  + (long)bz * sA + (long)(by * 128) * K;
    const bf16* Bt = Btg + (long)zb * sB + (long)(bx * 128) * K;
    TC*         C  = Cg  + (long)bz * sC;

    const int sr = lane >> 2, sc = lane & 3;
    const int scs = sc ^ (sr & 3);          // source col-block pre-swizzle
    const bf16* gA0 = A  + (long)(wv * 32 + sr)      * K + scs * 8;
    const bf16* gA1 = A  + (long)(wv * 32 + 16 + sr) * K + scs * 8;
    const bf16* gB0 = Bt + (long)(wv * 32 + sr)      * K + scs * 8;
    const bf16* gB1 = Bt + (long)(wv * 32 + 16 + sr) * K + scs * 8;
    unsigned short* lA0 = &Asm[(wv * 32)      * 32];
    unsigned short* lA1 = &Asm[(wv * 32 + 16) * 32];
    unsigned short* lB0 = &Bsm[(wv * 32)      * 32];
    unsigned short* lB1 = &Bsm[(wv * 32 + 16) * 32];

    f32x4 acc[4][4];
#pragma unroll
    for (int i = 0; i < 4; ++i)
#pragma unroll
        for (int j = 0; j < 4; ++j)
            acc[i][j] = (f32x4){0.f, 0.f, 0.f, 0.f};

    const int qs = (q ^ (ln & 3)) * 8;      // swizzled read block

    gl_lds16(gA0, lA0);
    gl_lds16(gA1, lA1);
    gl_lds16(gB0, lB0);
    gl_lds16(gB1, lB1);
    __syncthreads();

    int cur = 0;
    for (int k0 = 0; k0 < K; k0 += 32) {
        const int nxt = cur ^ 1;
        if (k0 + 32 < K) {
            const int no = nxt * BUF;
            gl_lds16(gA0 + k0 + 32, lA0 + no);
            gl_lds16(gA1 + k0 + 32, lA1 + no);
            gl_lds16(gB0 + k0 + 32, lB0 + no);
            gl_lds16(gB1 + k0 + 32, lB1 + no);
        }

        const unsigned short* Ac = &Asm[cur * BUF];
        const unsigned short* Bc = &Bsm[cur * BUF];
        short8 af[4], bfr[4];
#pragma unroll
        for (int mt = 0; mt < 4; ++mt) {
            int m = wm * 64 + mt * 16 + ln;
            af[mt] = *(const short8*)&Ac[m * 32 + qs];
        }
#pragma unroll
        for (int nt = 0; nt < 4; ++nt) {
            int n = wn * 64 + nt * 16 + ln;
            bfr[nt] = *(const short8*)&Bc[n * 32 + qs];
        }
#pragma unroll
        for (int mt = 0; mt < 4; ++mt)
#pragma unroll
            for (int nt = 0; nt < 4; ++nt)
                acc[mt][nt] = __builtin_amdgcn_mfma_f32_16x16x32_bf16(
                    af[mt], bfr[nt], acc[mt][nt], 0, 0, 0);

        __syncthreads();
        cur = nxt;
    }

#pragma unroll
    for (int mt = 0; mt < 4; ++mt) {
#pragma unroll
        for (int nt = 0; nt < 4; ++nt) {
            const int col = bx * 128 + wn * 64 + nt * 16 + ln;
            const int rowb = by * 128 + wm * 64 + mt * 16 + q * 4;
#pragma unroll
            for (int r = 0; r < 4; ++r) {
                float vraw = acc[mt][nt][r] * alpha;
                if (RAW) {
                    if (bz < 16)
                        Craw[(long)bz * M * N + (long)(rowb + r) * N + col] =
                            __float2bfloat16(vraw);
                }
                float v = vraw;
                if (EPI == 1) v = __logf(fmaxf(v, 0.f) + EPSF);
                stf(C, (long)(rowb + r) * N + col, v);
            }
        }
    }
}

// ---------------------------------------------------------------------------
// QKV via MFMA, merged sets — 2-phase double-buffered K-loop (r7).
// ---------------------------------------------------------------------------
__global__ __launch_bounds__(256) void qkv_mfma(
    const bf16* __restrict__ X,
    const bf16* __restrict__ w1t, const bf16* __restrict__ w2t,
    bf16* __restrict__ q1, bf16* __restrict__ k1, bf16* __restrict__ v1,
    bf16* __restrict__ q2, bf16* __restrict__ k2, bf16* __restrict__ v2)
{
    constexpr int K = Dc;  // 512
    __shared__ unsigned short Asm[2 * 128 * 32];
    __shared__ unsigned short Bsm[2 * 128 * 32];
    constexpr int BUF = 128 * 32;

    const int tid  = threadIdx.x;
    const int wv   = tid >> 6;
    const int lane = tid & 63;
    const int q    = lane >> 4;
    const int ln   = lane & 15;
    const int wm   = wv & 1;
    const int wn   = wv >> 1;
    const int set  = blockIdx.z;

    const bf16* Wt = set ? w2t : w1t;
    bf16* Q  = set ? q2 : q1;
    bf16* Ko = set ? k2 : k1;
    bf16* V  = set ? v2 : v1;

    const bf16* A  = X  + (long)(blockIdx.y * 128) * K;
    const bf16* Bt = Wt + (long)(blockIdx.x * 128) * K;

    const int sr = lane >> 2, sc = lane & 3;
    const int scs = sc ^ (sr & 3);
    const bf16* gA0 = A  + (long)(wv * 32 + sr)      * K + scs * 8;
    const bf16* gA1 = A  + (long)(wv * 32 + 16 + sr) * K + scs * 8;
    const bf16* gB0 = Bt + (long)(wv * 32 + sr)      * K + scs * 8;
    const bf16* gB1 = Bt + (long)(wv * 32 + 16 + sr) * K + scs * 8;
    unsigned short* lA0 = &Asm[(wv * 32)      * 32];
    unsigned short* lA1 = &Asm[(wv * 32 + 16) * 32];
    unsigned short* lB0 = &Bsm[(wv * 32)      * 32];
    unsigned short* lB1 = &Bsm[(wv * 32 + 16) * 32];

    f32x4 acc[4][4];
#pragma unroll
    for (int i = 0; i < 4; ++i)
#pragma unroll
        for (int j = 0; j < 4; ++j)
            acc[i][j] = (f32x4){0.f, 0.f, 0.f, 0.f};

    const int qs = (q ^ (ln & 3)) * 8;

    gl_lds16(gA0, lA0);
    gl_lds16(gA1, lA1);
    gl_lds16(gB0, lB0);
    gl_lds16(gB1, lB1);
    __syncthreads();

    int cur = 0;
    for (int k0 = 0; k0 < K; k0 += 32) {
        const int nxt = cur ^ 1;
        if (k0 + 32 < K) {
            const int no = nxt * BUF;
            gl_lds16(gA0 + k0 + 32, lA0 + no);
            gl_lds16(gA1 + k0 + 32, lA1 + no);
            gl_lds16(gB0 + k0 + 32, lB0 + no);
            gl_lds16(gB1 + k0 + 32, lB1 + no);
        }

        const unsigned short* Ac = &Asm[cur * BUF];
        const unsigned short* Bc = &Bsm[cur * BUF];
        short8 af[4], bfr[4];
#pragma unroll
        for (int mt = 0; mt < 4; ++mt) {
            int m = wm * 64 + mt * 16 + ln;
            af[mt] = *(const short8*)&Ac[m * 32 + qs];
        }
#pragma unroll
        for (int nt = 0; nt < 4; ++nt) {
            int n = wn * 64 + nt * 16 + ln;
            bfr[nt] = *(const short8*)&Bc[n * 32 + qs];
        }
#pragma unroll
        for (int mt = 0; mt < 4; ++mt)
#pragma unroll
            for (int nt = 0; nt < 4; ++nt)
                acc[mt][nt] = __builtin_amdgcn_mfma_f32_16x16x32_bf16(
                    af[mt], bfr[nt], acc[mt][nt], 0, 0, 0);

        __syncthreads();
        cur = nxt;
    }

#pragma unroll
    for (int mt = 0; mt < 4; ++mt) {
#pragma unroll
        for (int nt = 0; nt < 4; ++nt) {
            const int col  = blockIdx.x * 128 + wn * 64 + nt * 16 + ln;
            const int rowb = blockIdx.y * 128 + wm * 64 + mt * 16 + q * 4;
            const int t = col >> 9;
            const int h = (col >> 6) & 7;
            const int dk = col & 63;
            bf16* dst = (t == 0) ? Q : (t == 1) ? Ko : V;
#pragma unroll
            for (int r = 0; r < 4; ++r) {
                const int row = rowb + r;
                const int b = row >= Nc ? 1 : 0;
                const int n = row - b * Nc;
                dst[(((long)b * Hc + h) * Nc + n) * DKc + dk] =
                    __float2bfloat16(acc[mt][nt][r]);
            }
        }
    }
}

// ---------------------------------------------------------------------------
// MFMA bf16 NT narrow GEMM core (validated): acc = A(128,K) @ Bt(64,K)^T.
// ---------------------------------------------------------------------------
struct N64Acc { f32x4 acc[2][4]; };

template <typename DUMMY = void>
DEVINL void n64_core(const bf16* A, const bf16* Bt, int K,
                     unsigned short* Asm, unsigned short* Bsm, N64Acc& R)
{
    const int tid  = threadIdx.x;
    const int wave = tid >> 6;
    const int lane = tid & 63;
    const int q    = lane >> 4;
    const int ln   = lane & 15;

    const int sr = tid >> 3, k8 = tid & 7;
    const bf16* pa[4];
    const bf16* pb[2];
    int wa[4], wb[2];
#pragma unroll
    for (int i = 0; i < 4; ++i) {
        pa[i] = A + (long)(sr + i * 32) * K + k8 * 8;
        wa[i] = (sr + i * 32) * 72 + k8 * 8;
    }
#pragma unroll
    for (int i = 0; i < 2; ++i) {
        pb[i] = Bt + (long)(sr + i * 32) * K + k8 * 8;
        wb[i] = (sr + i * 32) * 72 + k8 * 8;
    }

#pragma unroll
    for (int i = 0; i < 2; ++i)
#pragma unroll
        for (int j = 0; j < 4; ++j)
            R.acc[i][j] = (f32x4){0.f, 0.f, 0.f, 0.f};

    for (int k0 = 0; k0 < K; k0 += 64) {
        uint4 va[4], vb[2];
#pragma unroll
        for (int i = 0; i < 4; ++i) va[i] = *(const uint4*)(pa[i] + k0);
#pragma unroll
        for (int i = 0; i < 2; ++i) vb[i] = *(const uint4*)(pb[i] + k0);
        __syncthreads();
#pragma unroll
        for (int i = 0; i < 4; ++i) *(uint4*)&Asm[wa[i]] = va[i];
#pragma unroll
        for (int i = 0; i < 2; ++i) *(uint4*)&Bsm[wb[i]] = vb[i];
        __syncthreads();

#pragma unroll
        for (int kc = 0; kc < 2; ++kc) {
            short8 af[2], bfr[4];
#pragma unroll
            for (int mt = 0; mt < 2; ++mt) {
                int m = wave * 32 + mt * 16 + ln;
                af[mt] = *(const short8*)&Asm[m * 72 + kc * 32 + q * 8];
            }
#pragma unroll
            for (int nt = 0; nt < 4; ++nt) {
                int n = nt * 16 + ln;
                bfr[nt] = *(const short8*)&Bsm[n * 72 + kc * 32 + q * 8];
            }
#pragma unroll
            for (int mt = 0; mt < 2; ++mt)
#pragma unroll
                for (int nt = 0; nt < 4; ++nt)
                    R.acc[mt][nt] = __builtin_amdgcn_mfma_f32_16x16x32_bf16(
                        af[mt], bfr[nt], R.acc[mt][nt], 0, 0, 0);
        }
    }
}

// ---------------------------------------------------------------------------
// HALF-HEIGHT n64 core — acc = A(64,K) @ Bt(64,K)^T (validated r9).
// ---------------------------------------------------------------------------
struct N64hAcc { f32x4 acc[4]; };

template <typename DUMMY = void>
DEVINL void n64h_core(const bf16* A, const bf16* Bt, int K,
                      unsigned short* Asm, unsigned short* Bsm, N64hAcc& R)
{
    const int tid  = threadIdx.x;
    const int wave = tid >> 6;
    const int lane = tid & 63;
    const int q    = lane >> 4;
    const int ln   = lane & 15;

    const int sr = tid >> 3, k8 = tid & 7;   // sr 0..31, k8 0..7
    const bf16* pa[2];
    const bf16* pb[2];
    int wa[2], wb[2];
#pragma unroll
    for (int i = 0; i < 2; ++i) {
        pa[i] = A  + (long)(sr + i * 32) * K + k8 * 8;
        wa[i] = (sr + i * 32) * 72 + k8 * 8;
        pb[i] = Bt + (long)(sr + i * 32) * K + k8 * 8;
        wb[i] = wa[i];
    }

#pragma unroll
    for (int j = 0; j < 4; ++j)
        R.acc[j] = (f32x4){0.f, 0.f, 0.f, 0.f};

    for (int k0 = 0; k0 < K; k0 += 64) {
        uint4 va[2], vb[2];
#pragma unroll
        for (int i = 0; i < 2; ++i) va[i] = *(const uint4*)(pa[i] + k0);
#pragma unroll
        for (int i = 0; i < 2; ++i) vb[i] = *(const uint4*)(pb[i] + k0);
        __syncthreads();
#pragma unroll
        for (int i = 0; i < 2; ++i) *(uint4*)&Asm[wa[i]] = va[i];
#pragma unroll
        for (int i = 0; i < 2; ++i) *(uint4*)&Bsm[wb[i]] = vb[i];
        __syncthreads();

#pragma unroll
        for (int kc = 0; kc < 2; ++kc) {
            short8 af;
            af = *(const short8*)&Asm[(wave * 16 + ln) * 72 + kc * 32 + q * 8];
            short8 bfr[4];
#pragma unroll
            for (int nt = 0; nt < 4; ++nt) {
                int n = nt * 16 + ln;
                bfr[nt] = *(const short8*)&Bsm[n * 72 + kc * 32 + q * 8];
            }
#pragma unroll
            for (int nt = 0; nt < 4; ++nt)
                R.acc[nt] = __builtin_amdgcn_mfma_f32_16x16x32_bf16(
                    af, bfr[nt], R.acc[nt], 0, 0, 0);
        }
    }
}

// ---------------------------------------------------------------------------
// Merged pair launch (Path-B fallback only; validated round 11).
// ---------------------------------------------------------------------------
__global__ __launch_bounds__(256) void gemm_n64_pair(
    const bf16* __restrict__ A0g, const bf16* __restrict__ B0g, bf16* __restrict__ C0tg,
    const bf16* __restrict__ A1g, const bf16* __restrict__ B1g, bf16* __restrict__ C1g,
    int M, int K, long sA, long sB, long sC)
{
    __shared__ unsigned short Asm[128 * 72];
    __shared__ unsigned short Bsm[64 * 72];

    const int zz = blockIdx.z & 15;
    const int second = blockIdx.z >> 4;
    const bf16* A  = (second ? A1g : A0g) + (long)zz * sA + (long)(blockIdx.y * 128) * K;
    const bf16* Bt = (second ? B1g : B0g) + (long)zz * sB;

    N64Acc R;
    n64_core(A, Bt, K, Asm, Bsm, R);

    const int tid = threadIdx.x;
    const int wave = tid >> 6, lane = tid & 63, q = lane >> 4, ln = lane & 15;

    if (second) {
        bf16* C = C1g + (long)zz * sC;
#pragma unroll
        for (int mt = 0; mt < 2; ++mt) {
#pragma unroll
            for (int nt = 0; nt < 4; ++nt) {
                const int col  = nt * 16 + ln;
                const int rowb = blockIdx.y * 128 + wave * 32 + mt * 16 + q * 4;
#pragma unroll
                for (int r = 0; r < 4; ++r)
                    C[(long)(rowb + r) * 64 + col] = __float2bfloat16(R.acc[mt][nt][r]);
            }
        }
    } else {
        __syncthreads();
#pragma unroll
        for (int mt = 0; mt < 2; ++mt) {
#pragma unroll
            for (int nt = 0; nt < 4; ++nt) {
                const int col = nt * 16 + ln;
                const int rwb = wave * 32 + mt * 16 + q * 4;
#pragma unroll
                for (int r = 0; r < 4; ++r)
                    *(bf16*)&Asm[col * 136 + rwb + r] = __float2bfloat16(R.acc[mt][nt][r]);
            }
        }
        __syncthreads();
        bf16* Ct = C0tg + (long)zz * sC;
        const int dk  = tid >> 2;
        const int nc0 = (tid & 3) * 32;
        const int gn0 = blockIdx.y * 128;
#pragma unroll
        for (int c8 = 0; c8 < 4; ++c8) {
            uint4 v = *(const uint4*)&Asm[dk * 136 + nc0 + c8 * 8];
            *(uint4*)&Ct[(long)dk * Nc + gn0 + nc0 + c8 * 8] = v;
        }
    }
}

// ---------------------------------------------------------------------------
// Merged y kernel, half-height tiles (Path A; validated r9). 192 blocks.
// ---------------------------------------------------------------------------
__global__ __launch_bounds__(256) void gemm_n64_both_h(
    const bf16* __restrict__ Ab, const bf16* __restrict__ v1t,
    const bf16* __restrict__ Craw, const bf16* __restrict__ v2t,
    const float* __restrict__ smallf, bf16* __restrict__ yc,
    int K, long sA, long sB)
{
    __shared__ unsigned short Asm[64 * 72];
    __shared__ unsigned short Bsm[64 * 72];

    const int bh = blockIdx.z;
    const long arow = (long)(blockIdx.y * 64) * K;

    N64hAcc R1;
    n64h_core(Ab + (long)bh * sA + arow, v1t + (long)bh * sB, K, Asm, Bsm, R1);
    N64hAcc R2;
    n64h_core(Craw + (long)bh * sA + arow, v2t + (long)bh * sB, K, Asm, Bsm, R2);

    const float w = sigf(smallf[392]);
    const int b = bh >> 3, h = bh & 7;

    const int tid = threadIdx.x;
    const int wave = tid >> 6, lane = tid & 63, q = lane >> 4, ln = lane & 15;
#pragma unroll
    for (int nt = 0; nt < 4; ++nt) {
        const int col  = nt * 16 + ln;
        const int rowb = blockIdx.y * 64 + wave * 16 + q * 4;
#pragma unroll
        for (int r = 0; r < 4; ++r) {
            const int n = rowb + r;
            yc[((long)(b * Nc + n)) * Dc + h * DKc + col] =
                __float2bfloat16(R1.acc[nt][r] + w * R2.acc[nt][r]);
        }
    }
}

// y_chain GEMM with fused combine + permute (Path-B fallback only).
__global__ __launch_bounds__(256) void gemm_n64_combine(
    const bf16* __restrict__ A1b, const bf16* __restrict__ trt,
    const bf16* __restrict__ yb1, const float* __restrict__ smallf,
    bf16* __restrict__ yc, int M, int K, long sA, long sB)
{
    __shared__ unsigned short Asm[128 * 72];
    __shared__ unsigned short Bsm[64 * 72];

    const int bh = blockIdx.z;
    const bf16* A  = A1b + (long)bh * sA + (long)(blockIdx.y * 128) * K;
    const bf16* Bt = trt + (long)bh * sB;

    N64Acc R;
    n64_core(A, Bt, K, Asm, Bsm, R);

    const float w = sigf(smallf[392]);
    const int b = bh >> 3, h = bh & 7;
    const long yb1base = (long)bh * Nc * DKc;

    const int tid = threadIdx.x;
    const int wave = tid >> 6, lane = tid & 63, q = lane >> 4, ln = lane & 15;
#pragma unroll
    for (int mt = 0; mt < 2; ++mt) {
#pragma unroll
        for (int nt = 0; nt < 4; ++nt) {
            const int col  = nt * 16 + ln;
            const int rowb = blockIdx.y * 128 + wave * 32 + mt * 16 + q * 4;
#pragma unroll
            for (int r = 0; r < 4; ++r) {
                const int n = rowb + r;
                const float base = __bfloat162float(yb1[yb1base + (long)n * 64 + col]);
                yc[((long)(b * Nc + n)) * Dc + h * DKc + col] =
                    __float2bfloat16(base + w * R.acc[mt][nt][r]);
            }
        }
    }
}

// Path-B y_base GEMM (fallback only).
__global__ __launch_bounds__(256) void gemm_n64_yb(
    const bf16* __restrict__ Ag, const bf16* __restrict__ Btg,
    bf16* __restrict__ Cg, int M, int K, long sA, long sB, long sC)
{
    __shared__ unsigned short Asm[128 * 72];
    __shared__ unsigned short Bsm[64 * 72];

    const int zz = blockIdx.z;
    const bf16* A  = Ag + (long)zz * sA + (long)(blockIdx.y * 128) * K;
    const bf16* Bt = Btg + (long)zz * sB;

    N64Acc R;
    n64_core(A, Bt, K, Asm, Bsm, R);

    bf16* C = Cg + (long)zz * sC;
    const int tid = threadIdx.x;
    const int wave = tid >> 6, lane = tid & 63, q = lane >> 4, ln = lane & 15;
#pragma unroll
    for (int mt = 0; mt < 2; ++mt) {
#pragma unroll
        for (int nt = 0; nt < 4; ++nt) {
            const int col  = nt * 16 + ln;
            const int rowb = blockIdx.y * 128 + wave * 32 + mt * 16 + q * 4;
#pragma unroll
            for (int r = 0; r < 4; ++r)
                C[(long)(rowb + r) * 64 + col] = __float2bfloat16(R.acc[mt][nt][r]);
        }
    }
}

// ---------------------------------------------------------------------------
// Row softmax over width 768 — wave-per-row (Path-B fallback only now).
// ---------------------------------------------------------------------------
__global__ __launch_bounds__(256) void softmax_rows_w(
    const float* __restrict__ src, bf16* __restrict__ dst)
{
    const int wid  = threadIdx.x >> 6;
    const int lane = threadIdx.x & 63;
    const long row = (long)blockIdx.x * 4 + wid;
    const float* s = src + row * Nc;

    float4 v[3];
#pragma unroll
    for (int i = 0; i < 3; ++i)
        v[i] = *(const float4*)&s[i * 256 + lane * 4];

    float m = -1e30f;
#pragma unroll
    for (int i = 0; i < 3; ++i)
        m = fmaxf(m, fmaxf(fmaxf(v[i].x, v[i].y), fmaxf(v[i].z, v[i].w)));
#pragma unroll
    for (int off = 32; off > 0; off >>= 1)
        m = fmaxf(m, __shfl_xor(m, off, 64));

    float e[12];
    float sum = 0.f;
#pragma unroll
    for (int i = 0; i < 3; ++i) {
        e[i * 4 + 0] = __expf(v[i].x - m);
        e[i * 4 + 1] = __expf(v[i].y - m);
        e[i * 4 + 2] = __expf(v[i].z - m);
        e[i * 4 + 3] = __expf(v[i].w - m);
        sum += e[i * 4 + 0] + e[i * 4 + 1] + e[i * 4 + 2] + e[i * 4 + 3];
    }
#pragma unroll
    for (int off = 32; off > 0; off >>= 1)
        sum += __shfl_xor(sum, off, 64);

    const float inv = 1.f / fmaxf(sum, 1e-30f);
    unsigned short* d = (unsigned short*)dst + row * Nc;
#pragma unroll
    for (int i = 0; i < 3; ++i) {
        unsigned short o[4];
#pragma unroll
        for (int j = 0; j < 4; ++j) {
            const bf16 b = __float2bfloat16(e[i * 4 + j] * inv);
            o[j] = *(const unsigned short*)&b;
        }
        *(uint2*)&d[i * 256 + lane * 4] = *(const uint2*)o;
    }
}

// ---------------------------------------------------------------------------
// Gate network + Smix — r7-validated 2-elem body (Path-B fallback only).
// ---------------------------------------------------------------------------
__global__ __launch_bounds__(256) void gates_smix(
    const float* __restrict__ S1g, const float* __restrict__ S2g,
    const bf16* __restrict__ Crg, const bf16* __restrict__ Clg,
    float* __restrict__ Smixg, const float* __restrict__ smallf)
{
    __shared__ float t1t[32][17], t2t[32][17];

    const long mat = (long)blockIdx.z * Nc * Nc;
    const float* S1 = S1g + mat;
    const float* S2 = S2g + mat;
    const unsigned short* Cr = (const unsigned short*)Crg + mat;
    const unsigned short* Cl = (const unsigned short*)Clg + mat;
    float* Smix = Smixg + mat;

    const int tid = threadIdx.x;

    const int n0 = blockIdx.y * 16, m0 = blockIdx.x * 32;
    {
        const int r = tid >> 3, c2 = (tid & 7) * 2;
        const float2 a = *(const float2*)&S1[(long)(m0 + r) * Nc + n0 + c2];
        const float2 b = *(const float2*)&S2[(long)(m0 + r) * Nc + n0 + c2];
        t1t[r][c2] = a.x; t1t[r][c2 + 1] = a.y;
        t2t[r][c2] = b.x; t2t[r][c2 + 1] = b.y;
    }
    __syncthreads();

    const int tx = tid & 15, ty = tid >> 4;
    const int n = n0 + ty;
    const long idx = (long)n * Nc + m0 + tx * 2;

    const float2 s1v = *(const float2*)&S1[idx];
    const float2 s2v = *(const float2*)&S2[idx];
    const unsigned cru = *(const unsigned*)&Cr[idx];
    const unsigned clu = *(const unsigned*)&Cl[idx];

    const f32x2 s1a = {s1v.x, s1v.y};
    const f32x2 s2a = {s2v.x, s2v.y};
    const f32x2 cra = {__uint_as_float((cru & 0xffffu) << 16),
                       __uint_as_float(cru & 0xffff0000u)};
    const f32x2 cla = {__uint_as_float((clu & 0xffffu) << 16),
                       __uint_as_float(clu & 0xffff0000u)};
    const f32x2 s1t = {t1t[tx * 2][ty], t1t[tx * 2 + 1][ty]};
    const f32x2 s2t = {t2t[tx * 2][ty], t2t[tx * 2 + 1][ty]};

    f32x2 g0 = *(const f32x2*)&smallf[384];
    f32x2 g1 = *(const f32x2*)&smallf[386];
    f32x2 g2 = *(const f32x2*)&smallf[388];
    f32x2 g3 = *(const f32x2*)&smallf[390];

    const f32x2 gc1  = splat2(-2.30220902f);
    const f32x2 gc3  = splat2(-0.10294357f);
    const f32x2 one2 = splat2(1.f);

#pragma unroll
    for (int u = 0; u < 16; ++u) {
        const f32x2* cw = (const f32x2*)&smallf[u * 24];
        f32x2 h = cw[6];
        h = fma2(s1a, cw[0], h);
        h = fma2(s2a, cw[1], h);
        h = fma2(s1t, cw[2], h);
        h = fma2(s2t, cw[3], h);
        h = fma2(cra, cw[4], h);
        h = fma2(cla, cw[5], h);
        const f32x2 hh = h * h;
        const f32x2 z2 = h * fma2(hh, gc3, gc1);
        f32x2 e;  e[0]  = vexp2(z2[0]); e[1]  = vexp2(z2[1]);
        const f32x2 d = one2 + e;
        f32x2 rc; rc[0] = vrcp(d[0]);   rc[1] = vrcp(d[1]);
        const f32x2 hid = h * rc;
        g0 = fma2(hid, cw[8],  g0);
        g1 = fma2(hid, cw[9],  g1);
        g2 = fma2(hid, cw[10], g2);
        g3 = fma2(hid, cw[11], g3);
    }

    const f32x2 nl2e = splat2(-1.44269504f);
    const f32x2 ln2v = splat2(0.69314718f);
    auto sig2 = [&](f32x2 x) -> f32x2 {
        const f32x2 t = x * nl2e;
        f32x2 e;  e[0] = vexp2(t[0]); e[1] = vexp2(t[1]);
        const f32x2 d = one2 + e;
        f32x2 r;  r[0] = vrcp(d[0]);  r[1] = vrcp(d[1]);
        return r;
    };
    const f32x2 ga2 = sig2(g0);
    const f32x2 go2 = sig2(g1);
    const f32x2 gn2 = sig2(g2);
    const f32x2 gc2 = sig2(g3);

    const f32x2 dd = s1a - s2a;
    f32x2 ad; ad[0] = fabsf(dd[0]); ad[1] = fabsf(dd[1]);
    const f32x2 t2 = ad * nl2e;
    f32x2 ee; ee[0] = vexp2(t2[0]); ee[1] = vexp2(t2[1]);
    const f32x2 lp = one2 + ee;
    f32x2 lg; lg[0] = vlog2(lp[0]); lg[1] = vlog2(lp[1]);
    const f32x2 mx2 = __builtin_elementwise_max(s1a, s2a);
    const f32x2 lae = fma2(lg, ln2v, mx2);

    f32x2 o2 = s1a;
    o2 = fma2(ga2, s2a, o2);
    o2 = fma2(go2, lae - s1a, o2);
    o2 = fma2(gn2, s2a * splat2(-BETA_NOT), o2);
    o2 = fma2(gc2, cra, o2);
    *(float2*)&Smix[idx] = (float2){o2[0], o2[1]};
}

// ---------------------------------------------------------------------------
// Round 23: FUSED gates + Smix + row softmax -> A (Path A).
// Block = 8 full rows (8n x 768m): 12 iterations of the r7-validated
// 64m x 8n pk-pair body, out accumulated in a 24.6 KB LDS row buffer
// (instead of the 37.7 MB global Smix round trip), then block-local row
// softmax (softmax_rows_w math, LDS source) writes A bf16 directly.
// Bit-identical math to gates_smix + softmax_rows_w. LDS 29.2 KB ->
// 5 blocks/CU -> 5 waves/SIMD (occ ~62%, near gates' validated regime).
// A must NOT alias S1 (other blocks still read S1 column slices) — the
// launcher passes the dead Smix region.
// ---------------------------------------------------------------------------
__global__ __launch_bounds__(256) void gates_smix_sm(
    const float* __restrict__ S1g, const float* __restrict__ S2g,
    const bf16* __restrict__ Crg, const bf16* __restrict__ Clg,
    bf16* __restrict__ Ag_, const float* __restrict__ smallf)
{
    __shared__ float osm[8 * Nc];            // 24.6 KB out rows
    __shared__ float t1t[64][9], t2t[64][9]; // 4.6 KB transposed tiles

    const long mat = (long)blockIdx.z * Nc * Nc;
    const float* S1 = S1g + mat;
    const float* S2 = S2g + mat;
    const unsigned short* Cr = (const unsigned short*)Crg + mat;
    const unsigned short* Cl = (const unsigned short*)Clg + mat;
    bf16* A = Ag_ + mat;

    const int tid = threadIdx.x;
    const int n0 = blockIdx.x * 8;
    const int tx = tid & 31, ty = tid >> 5;   // tx: m-pair 0..31, ty: row 0..7
    const int n = n0 + ty;

    const f32x2 gc1  = splat2(-2.30220902f);  // gelu c1 * log2e
    const f32x2 gc3  = splat2(-0.10294357f);  // gelu c3 * log2e
    const f32x2 one2 = splat2(1.f);
    const f32x2 nl2e = splat2(-1.44269504f);
    const f32x2 ln2v = splat2(0.69314718f);

    for (int it = 0; it < 12; ++it) {
        const int m0 = it * 64;
        __syncthreads();   // protect t-tiles from previous iteration readers
        {   // stage transposed tiles: S[m0..m0+63][n0..n0+7]
            const int r = tid >> 2, c2 = (tid & 3) * 2;
            const float2 a = *(const float2*)&S1[(long)(m0 + r) * Nc + n0 + c2];
            const float2 b = *(const float2*)&S2[(long)(m0 + r) * Nc + n0 + c2];
            t1t[r][c2] = a.x; t1t[r][c2 + 1] = a.y;
            t2t[r][c2] = b.x; t2t[r][c2 + 1] = b.y;
        }
        __syncthreads();

        const long idx = (long)n * Nc + m0 + tx * 2;
        const float2 s1v = *(const float2*)&S1[idx];
        const float2 s2v = *(const float2*)&S2[idx];
        const unsigned cru = *(const unsigned*)&Cr[idx];
        const unsigned clu = *(const unsigned*)&Cl[idx];

        const f32x2 s1a = {s1v.x, s1v.y};
        const f32x2 s2a = {s2v.x, s2v.y};
        const f32x2 cra = {__uint_as_float((cru & 0xffffu) << 16),
                           __uint_as_float(cru & 0xffff0000u)};
        const f32x2 cla = {__uint_as_float((clu & 0xffffu) << 16),
                           __uint_as_float(clu & 0xffff0000u)};
        const f32x2 s1t = {t1t[tx * 2][ty], t1t[tx * 2 + 1][ty]};
        const f32x2 s2t = {t2t[tx * 2][ty], t2t[tx * 2 + 1][ty]};

        f32x2 g0 = *(const f32x2*)&smallf[384];
        f32x2 g1 = *(const f32x2*)&smallf[386];
        f32x2 g2 = *(const f32x2*)&smallf[388];
        f32x2 g3 = *(const f32x2*)&smallf[390];

#pragma unroll
        for (int u = 0; u < 16; ++u) {
            const f32x2* cw = (const f32x2*)&smallf[u * 24];
            f32x2 h = cw[6];
            h = fma2(s1a, cw[0], h);
            h = fma2(s2a, cw[1], h);
            h = fma2(s1t, cw[2], h);
            h = fma2(s2t, cw[3], h);
            h = fma2(cra, cw[4], h);
            h = fma2(cla, cw[5], h);
            const f32x2 hh = h * h;
            const f32x2 z2 = h * fma2(hh, gc3, gc1);
            f32x2 e;  e[0]  = vexp2(z2[0]); e[1]  = vexp2(z2[1]);
            const f32x2 d = one2 + e;
            f32x2 rc; rc[0] = vrcp(d[0]);   rc[1] = vrcp(d[1]);
            const f32x2 hid = h * rc;
            g0 = fma2(hid, cw[8],  g0);
            g1 = fma2(hid, cw[9],  g1);
            g2 = fma2(hid, cw[10], g2);
            g3 = fma2(hid, cw[11], g3);
        }

        auto sig2 = [&](f32x2 x) -> f32x2 {
            const f32x2 t = x * nl2e;
            f32x2 e;  e[0] = vexp2(t[0]); e[1] = vexp2(t[1]);
            const f32x2 d = one2 + e;
            f32x2 r;  r[0] = vrcp(d[0]);  r[1] = vrcp(d[1]);
            return r;
        };
        const f32x2 ga2 = sig2(g0);
        const f32x2 go2 = sig2(g1);
        const f32x2 gn2 = sig2(g2);
        const f32x2 gc2 = sig2(g3);

        const f32x2 dd = s1a - s2a;
        f32x2 ad; ad[0] = fabsf(dd[0]); ad[1] = fabsf(dd[1]);
        const f32x2 t2 = ad * nl2e;
        f32x2 ee; ee[0] = vexp2(t2[0]); ee[1] = vexp2(t2[1]);
        const f32x2 lp = one2 + ee;
        f32x2 lg; lg[0] = vlog2(lp[0]); lg[1] = vlog2(lp[1]);
        const f32x2 mx2 = __builtin_elementwise_max(s1a, s2a);
        const f32x2 lae = fma2(lg, ln2v, mx2);

        f32x2 o2 = s1a;
        o2 = fma2(ga2, s2a, o2);
        o2 = fma2(go2, lae - s1a, o2);
        o2 = fma2(gn2, s2a * splat2(-BETA_NOT), o2);
        o2 = fma2(gc2, cra, o2);
        *(float2*)&osm[ty * Nc + m0 + tx * 2] = (float2){o2[0], o2[1]};
    }
    __syncthreads();

    // block-local row softmax (softmax_rows_w math, LDS source): 4 waves,
    // each handles 2 of the 8 rows.
    const int w = tid >> 6, lane = tid & 63;
#pragma unroll
    for (int rr = 0; rr < 2; ++rr) {
        const int row = w * 2 + rr;
        const float* s = &osm[row * Nc];
        float4 v[3];
#pragma unroll
        for (int i = 0; i < 3; ++i)
            v[i] = *(const float4*)&s[i * 256 + lane * 4];

        float m = -1e30f;
#pragma unroll
        for (int i = 0; i < 3; ++i)
            m = fmaxf(m, fmaxf(fmaxf(v[i].x, v[i].y), fmaxf(v[i].z, v[i].w)));
#pragma unroll
        for (int off = 32; off > 0; off >>= 1)
            m = fmaxf(m, __shfl_xor(m, off, 64));

        float e[12];
        float sum = 0.f;
#pragma unroll
        for (int i = 0; i < 3; ++i) {
            e[i * 4 + 0] = __expf(v[i].x - m);
            e[i * 4 + 1] = __expf(v[i].y - m);
            e[i * 4 + 2] = __expf(v[i].z - m);
            e[i * 4 + 3] = __expf(v[i].w - m);
            sum += e[i * 4 + 0] + e[i * 4 + 1] + e[i * 4 + 2] + e[i * 4 + 3];
        }
#pragma unroll
        for (int off = 32; off > 0; off >>= 1)
            sum += __shfl_xor(sum, off, 64);

        const float inv = 1.f / fmaxf(sum, 1e-30f);
        unsigned short* d = (unsigned short*)A + (long)(n0 + row) * Nc;
#pragma unroll
        for (int i = 0; i < 3; ++i) {
            unsigned short o[4];
#pragma unroll
            for (int j = 0; j < 4; ++j) {
                const bf16 b = __float2bfloat16(e[i * 4 + j] * inv);
                o[j] = *(const unsigned short*)&b;
            }
            *(uint2*)&d[i * 256 + lane * 4] = *(const uint2*)o;
        }
    }
}

// ---------------------------------------------------------------------------
// Final projection, half-height tiles — 192 blocks (validated r9).
// ---------------------------------------------------------------------------
__global__ __launch_bounds__(256) void proj_n64h(
    const bf16* __restrict__ yc, const bf16* __restrict__ pwt,
    const void* __restrict__ xraw, void* __restrict__ out)
{
    constexpr int K = Dc;  // 512
    constexpr int N = Dc;  // 512
    __shared__ unsigned short Asm[64 * 72];
    __shared__ unsigned short Bsm[64 * 72];
    __shared__ int is32s;
    if (threadIdx.x == 0) is32s = sniff_is_fp32(xraw);

    const bf16* A  = yc  + (long)(blockIdx.y * 64) * K;
    const bf16* Bt = pwt + (long)(blockIdx.x * 64) * K;

    N64hAcc R;
    n64h_core(A, Bt, K, Asm, Bsm, R);   // internal barriers publish is32s

    const int is32 = is32s;
    const int tid = threadIdx.x;
    const int wave = tid >> 6, lane = tid & 63, q = lane >> 4, ln = lane & 15;
#pragma unroll
    for (int nt = 0; nt < 4; ++nt) {
        const int col  = blockIdx.x * 64 + nt * 16 + ln;
        const int rowb = blockIdx.y * 64 + wave * 16 + q * 4;
#pragma unroll
        for (int r = 0; r < 4; ++r) {
            const long o = (long)(rowb + r) * N + col;
            if (is32) ((float*)out)[o] = R.acc[nt][r];
            else      ((bf16*)out)[o] = __float2bfloat16(R.acc[nt][r]);
        }
    }
}

// ---------------------------------------------------------------------------
extern "C" void kernel_launch(void* const* d_in, const int* in_sizes, int n_in,
                              void* d_out, int out_size, void* d_ws, size_t ws_size,
                              hipStream_t stream)
{
    const size_t HD   = (size_t)BHc * Nc * DKc;   // 786432
    const size_t HDh  = HD / 2;                   // float-slots for HD bf16
    const size_t MAT  = (size_t)Nc * Nc;          // 589824
    const size_t MATS = (size_t)BHc * MAT;        // 9437184
    const long   HSTR = (long)Nc * DKc;           // 49152 per-head stride

    float* ws = (float*)d_ws;
    size_t off = 0;
    auto alloc = [&](size_t n) { float* p = ws + off; off += n; return p; };

    bf16* xb  = (bf16*)alloc(HDh);
    bf16* w1b = (bf16*)alloc(HDh);   // w1b/w2b adjacent -> merged transpose
    bf16* w2b = (bf16*)alloc(HDh);
    bf16* w1t = (bf16*)alloc(HDh);
    bf16* w2t = (bf16*)alloc(HDh);
    bf16* pwb = (bf16*)alloc((size_t)Dc * Dc / 2);
    bf16* pwt = (bf16*)alloc((size_t)Dc * Dc / 2);
    float* smallf = alloc(512);
    // q1|q2 and k1|k2 adjacent -> single merged fused-S launch (32 batches)
    bf16* q1b = (bf16*)alloc(HDh); bf16* q2b = (bf16*)alloc(HDh);
    bf16* k1b = (bf16*)alloc(HDh); bf16* k2b = (bf16*)alloc(HDh);
    bf16* v1b = (bf16*)alloc(HDh); bf16* v2b = (bf16*)alloc(HDh);  // adjacent
    bf16* v1t = (bf16*)alloc(HDh); bf16* v2t = (bf16*)alloc(HDh);  // adjacent
    bf16* trt = (bf16*)alloc(HDh);
    float* S1   = alloc(MATS);       // S1/S2 adjacent
    float* S2   = alloc(MATS);
    float* Smix = alloc(MATS);       // region reused: A1tb|A2tb, then A (fused)
    bf16* A1b = (bf16*)alloc(MATS / 2);  // A1b/A2b adjacent
    bf16* A2b = (bf16*)alloc(MATS / 2);
    bf16* Crb = (bf16*)alloc(MATS / 2);  // Crb/Clb adjacent (merged launch)
    bf16* Clb = (bf16*)alloc(MATS / 2);
    bf16* yb1 = (bf16*)alloc(HDh);
    bf16* yc  = (bf16*)alloc(HDh);

    const size_t NEED_BASE = off * sizeof(float);
    bf16* Crawb = (bf16*)alloc(MATS / 2);          // raw C_right (Path A only)
    const size_t NEED_A = off * sizeof(float);
    const int pathA = ws_size >= NEED_A;

    // aliases into dead regions
    bf16* A1tb = (bf16*)Smix;            // live steps 3-4
    bf16* A2tb = ((bf16*)Smix) + MATS;
    bf16* AbA  = (bf16*)Smix;            // Path A: fused-gates A (Smix region
                                         //  dead after step-4's A1tb reads)
    bf16* Ab   = (bf16*)S1;              // Path B: S1 dead after gates

    if (ws_size < NEED_BASE) {
        fill_sentinel<<<dim3(3072), 256, 0, stream>>>((unsigned short*)d_out);
        return;
    }

    // 0. normalize inputs
    convert_all<<<dim3(3072), 256, 0, stream>>>(
        d_in[0], d_in[1], d_in[2], d_in[3], d_in[4], d_in[5], d_in[6], d_in[7],
        d_in[8], xb, w1b, w2b, pwb, smallf);

    // 1. merged W + pw transpose (one launch); merged QKV; v transposes
    transpose_wpw<<<dim3(24, 8, 3), 256, 0, stream>>>(
        (const unsigned short*)w1b, (unsigned short*)w1t,
        (const unsigned short*)pwb, (unsigned short*)pwt);
    qkv_mfma<<<dim3(12, 12, 2), 256, 0, stream>>>(
        xb, w1t, w2t, q1b, k1b, v1b, q2b, k2b, v2b);
    transpose_bf16<<<dim3(1, 12, 2 * BHc), 256, 0, stream>>>(
        (const unsigned short*)v1b, (unsigned short*)v1t, Nc, DKc, HSTR, HSTR);

    // 2+3. FUSED: S = scale*q@k^T, row softmax -> A, A^T (validated r10)
    sgemm_softmax<<<dim3(1536), 256, 0, stream>>>(
        q1b, k1b, S1, A1b, A1tb);

    // 4. Cr|Cl in ONE 32-batch launch; XCD-pinned 1-D grid; 2-phase K-loop;
    //    Path A also stores raw C_right.
    if (pathA)
        gemm_nt_mfma<1, bf16, 1, 1, 1><<<dim3(1152), 256, 0, stream>>>(
            A1b, A1tb, Crb, Crawb, Nc, Nc, Nc, (long)MAT, (long)MAT, (long)MAT, 1.f);
    else
        gemm_nt_mfma<1, bf16, 1, 1, 0><<<dim3(1152), 256, 0, stream>>>(
            A1b, A1tb, Crb, nullptr, Nc, Nc, Nc, (long)MAT, (long)MAT, (long)MAT, 1.f);

    if (pathA) {
        // 5+6. FUSED gates + Smix + row softmax -> A (into dead Smix region)
        gates_smix_sm<<<dim3(96, 1, BHc), 256, 0, stream>>>(
            S1, S2, Crb, Clb, AbA, smallf);

        // 7. merged y, half-height tiles: 192 blocks
        gemm_n64_both_h<<<dim3(1, 12, BHc), 256, 0, stream>>>(
            AbA, v1t, Crawb, v2t, smallf, yc, Nc, (long)MAT, HSTR);
    } else {
        // Path B fallback (round-10 structure)
        gates_smix<<<dim3(24, 48, BHc), 256, 0, stream>>>(
            S1, S2, Crb, Clb, Smix, smallf);
        softmax_rows_w<<<(BHc * Nc) / 4, 256, 0, stream>>>(Smix, Ab);
        gemm_n64_pair<<<dim3(1, 6, 2 * BHc), 256, 0, stream>>>(
            A2b, v2t, trt, Ab, v1t, yb1, Nc, Nc, (long)MAT, HSTR, HSTR);
        gemm_n64_combine<<<dim3(1, 6, BHc), 256, 0, stream>>>(
            A1b, trt, yb1, smallf, yc, Nc, Nc, (long)MAT, HSTR);
    }

    // 9. proj, half-height tiles: 192 blocks
    proj_n64h<<<dim3(8, 24, 1), 256, 0, stream>>>(yc, pwt, d_in[0], d_out);
}

// Round 12
// 330.631 us; speedup vs baseline: 1.0061x; 1.0061x over previous
//
#include <hip/hip_runtime.h>
#include <hip/hip_bf16.h>
#include <math.h>

typedef __hip_bfloat16 bf16;
typedef __attribute__((ext_vector_type(8))) short short8;   // 8 bf16 (4 VGPRs)
typedef __attribute__((ext_vector_type(4))) float f32x4;
typedef __attribute__((ext_vector_type(2))) float f32x2;
#define DEVINL __device__ __forceinline__

constexpr int Bc  = 2;
constexpr int Nc  = 768;
constexpr int Dc  = 512;
constexpr int Hc  = 8;
constexpr int DKc = 64;
constexpr int BHc = Bc * Hc;
constexpr float SCALE    = 0.125f;   // 1/sqrt(64)
constexpr float EPSF     = 1e-6f;
constexpr float BETA_NOT = 0.5f;

DEVINL float ldf(const float* p, long i) { return p[i]; }
DEVINL float ldf(const bf16* p, long i) { return __bfloat162float(p[i]); }
DEVINL void stf(float* p, long i, float v) { p[i] = v; }
DEVINL void stf(bf16* p, long i, float v) { p[i] = __float2bfloat16(v); }

DEVINL float sigf(float x) { return __fdividef(1.f, 1.f + __expf(-x)); }

// packed fp32 pair helpers — backend selects v_pk_fma_f32/v_pk_mul_f32 (r3:
// validated -41% on gates_smix; r4 pair-dup operands -12%; r5 s_load weights).
DEVINL f32x2 fma2(f32x2 a, f32x2 b, f32x2 c) { return __builtin_elementwise_fma(a, b, c); }
DEVINL f32x2 splat2(float x) { return (f32x2){x, x}; }
// guard-free transcendentals (libm exp2f adds a denormal guard: +13% in r2)
DEVINL float vexp2(float x) { float r; asm("v_exp_f32 %0, %1" : "=v"(r) : "v"(x)); return r; }
DEVINL float vrcp(float x)  { float r; asm("v_rcp_f32 %0, %1" : "=v"(r) : "v"(x)); return r; }
DEVINL float vlog2(float x) { float r; asm("v_log_f32 %0, %1" : "=v"(r) : "v"(x)); return r; }

// async global->LDS, 16B per lane; LDS dest = wave-uniform base + lane*16.
DEVINL void gl_lds16(const void* g, void* l) {
    __builtin_amdgcn_global_load_lds(
        (const __attribute__((address_space(1))) void*)g,
        (__attribute__((address_space(3))) void*)l, 16, 0, 0);
}

// ---------------------------------------------------------------------------
// Dtype sniffer — vectorized (validated round 9).
// ---------------------------------------------------------------------------
DEVINL int sniff_is_fp32(const void* xraw) {
    const uint4* p4 = (const uint4*)xraw;
    float mx = 0.f;
#pragma unroll
    for (int j = 0; j < 16; ++j) {
        const uint4 u = p4[j];
        const unsigned w[4] = {u.x, u.y, u.z, u.w};
#pragma unroll
        for (int t = 0; t < 4; ++t) {
            mx = fmaxf(mx, fabsf(__uint_as_float((w[t] & 0xffffu) << 16)));
            mx = fmaxf(mx, fabsf(__uint_as_float(w[t] & 0xffff0000u)));
        }
    }
    return mx > 1000.f ? 1 : 0;
}

DEVINL float cvt_elem(const void* s, long j, int is32) {
    return is32 ? ((const float*)s)[j]
                : __bfloat162float(((const bf16*)s)[j]);
}

// smallf layout (round 15 — PAIR-DUPLICATED; read via uniform scalar loads):
//   [u*24 + 2k+{0,1}]  = w1[u][k]          k=0..5   (12 floats)
//   [u*24 + 12..13]    = b1[u] pair
//   [u*24 + 14..15]    = pad
//   [u*24 + 16 + 2o+{0,1}] = conv2_w[o][u] o=0..3   (8 floats)
//   [384..391]  conv2_b[o] pairs
//   [392..393]  chain_logit pair          (combine reads [392])
__global__ __launch_bounds__(256) void convert_all(
    const void* x, const void* w1, const void* w2, const void* pw,
    const void* c1w, const void* c1b, const void* c2w, const void* c2b,
    const void* ch,
    bf16* xb, bf16* w1b, bf16* w2b, bf16* pwb, float* smallf)
{
    __shared__ int is32s;
    if (threadIdx.x == 0) is32s = sniff_is_fp32(x);
    __syncthreads();
    const int is32 = is32s;
    const long i = (long)blockIdx.x * 256 + threadIdx.x;
    if (i < (long)Bc * Nc * Dc) {
        xb[i]  = __float2bfloat16(cvt_elem(x,  i, is32));
        w1b[i] = __float2bfloat16(cvt_elem(w1, i, is32));
        w2b[i] = __float2bfloat16(cvt_elem(w2, i, is32));
    }
    if (i < (long)Dc * Dc) pwb[i] = __float2bfloat16(cvt_elem(pw, i, is32));
    if (i < 384) {
        const int u = (int)i / 24, k = (int)i % 24;
        float v = 0.f;
        if (k < 12)      v = cvt_elem(c1w, u * 6 + (k >> 1), is32);
        else if (k < 14) v = cvt_elem(c1b, u, is32);
        else if (k >= 16) { const int o = (k - 16) >> 1; v = cvt_elem(c2w, o * 16 + u, is32); }
        smallf[i] = v;
    } else if (i < 392) smallf[i] = cvt_elem(c2b, ((int)i - 384) >> 1, is32);
    else if (i < 394) smallf[i] = cvt_elem(ch, 0, is32);
    else if (i < 512) smallf[i] = 0.f;
}

__global__ __launch_bounds__(256) void fill_sentinel(unsigned short* o) {
    const long i = (long)blockIdx.x * 256 + threadIdx.x;
    if (i < (long)Bc * Nc * Dc) o[i] = 0x40E0;  // bf16 7.0
}

// ---------------------------------------------------------------------------
// Merged W + pw transpose — one launch (z=0,1: W sets; z=2: pw). (r11, kept)
// ---------------------------------------------------------------------------
__global__ __launch_bounds__(256) void transpose_wpw(
    const unsigned short* __restrict__ wb, unsigned short* __restrict__ wt,
    const unsigned short* __restrict__ pwb, unsigned short* __restrict__ pwt)
{
    __shared__ unsigned short tile[64][68];
    const int z = blockIdx.z;
    const unsigned short* s;
    unsigned short* d;
    int R, C;
    if (z < 2) {
        s = wb + (long)z * (Dc * 3 * Dc);
        d = wt + (long)z * (Dc * 3 * Dc);
        R = Dc; C = 3 * Dc;
    } else {
        if (blockIdx.x >= 8) return;
        s = pwb; d = pwt; R = Dc; C = Dc;
    }
    const int r0 = blockIdx.y * 64, c0 = blockIdx.x * 64;
    const int t = threadIdx.x;
    const int lr = t >> 4, lc4 = (t & 15) * 4;
#pragma unroll
    for (int i = 0; i < 4; ++i) {
        int r = lr + i * 16;
        *(uint2*)&tile[r][lc4] = *(const uint2*)&s[(long)(r0 + r) * C + c0 + lc4];
    }
    __syncthreads();
#pragma unroll
    for (int i = 0; i < 4; ++i) {
        int r = lr + i * 16;
        unsigned short v[4];
#pragma unroll
        for (int j = 0; j < 4; ++j) v[j] = tile[lc4 + j][r];
        *(uint2*)&d[(long)(c0 + r) * R + r0 + lc4] = *(uint2*)v;
    }
}

// ---------------------------------------------------------------------------
// Round 22 (validated): FUSED S-GEMM + row softmax + A-transpose.
// ---------------------------------------------------------------------------
__global__ __launch_bounds__(256) void sgemm_softmax(
    const bf16* __restrict__ qg, const bf16* __restrict__ kg,
    float* __restrict__ Sg, bf16* __restrict__ Ag_, bf16* __restrict__ Atg)
{
    __shared__ unsigned short Bsm[256 * 72];   // 36 KB; aliased for A^T stage
    __shared__ unsigned short Asm16[16 * 72];  // 2.25 KB
    __shared__ float red[4][16];

    const int wg  = blockIdx.x;
    const int xcd = wg & 7, tt = wg >> 3;
    const int z   = xcd + 8 * (tt / 48);
    const int by  = tt % 48;
    const long MAT = (long)Nc * Nc;

    const bf16* Q  = qg + (long)z * (Nc * DKc) + (long)(by * 16) * DKc;
    const bf16* Km = kg + (long)z * (Nc * DKc);
    float* S  = Sg  + (long)z * MAT + (long)(by * 16) * Nc;
    bf16*  A  = Ag_ + (long)z * MAT + (long)(by * 16) * Nc;
    bf16*  At = Atg + (long)z * MAT;           // write At[m][by*16 + n]

    const int tid  = threadIdx.x;
    const int wv   = tid >> 6;
    const int lane = tid & 63;
    const int q    = lane >> 4;
    const int ln   = lane & 15;
    const int sr   = tid >> 3, k8 = tid & 7;

    if (tid < 128) {
        const int row = tid >> 3, kk = tid & 7;
        *(uint4*)&Asm16[row * 72 + kk * 8] = *(const uint4*)&Q[row * 64 + kk * 8];
    }

    f32x4 acc[12];
#pragma unroll
    for (int j = 0; j < 12; ++j) acc[j] = (f32x4){0.f, 0.f, 0.f, 0.f};

    for (int c = 0; c < 3; ++c) {
        __syncthreads();
#pragma unroll
        for (int i = 0; i < 8; ++i) {
            const int row = sr + i * 32;
            *(uint4*)&Bsm[row * 72 + k8 * 8] =
                *(const uint4*)&Km[(long)(c * 256 + row) * 64 + k8 * 8];
        }
        __syncthreads();
#pragma unroll
        for (int kc = 0; kc < 2; ++kc) {
            const short8 af = *(const short8*)&Asm16[ln * 72 + kc * 32 + q * 8];
#pragma unroll
            for (int t = 0; t < 4; ++t) {
                const int nl = wv * 64 + t * 16 + ln;
                const short8 bfr = *(const short8*)&Bsm[nl * 72 + kc * 32 + q * 8];
                acc[c * 4 + t] = __builtin_amdgcn_mfma_f32_16x16x32_bf16(
                    af, bfr, acc[c * 4 + t], 0, 0, 0);
            }
        }
    }

    float mrow[4] = {-1e30f, -1e30f, -1e30f, -1e30f};
#pragma unroll
    for (int j = 0; j < 12; ++j) {
        const int c = j >> 2, t = j & 3;
        const int col = c * 256 + wv * 64 + t * 16 + ln;
#pragma unroll
        for (int r = 0; r < 4; ++r) {
            const float v = acc[j][r] * SCALE;
            acc[j][r] = v;
            S[(long)(q * 4 + r) * Nc + col] = v;
            mrow[r] = fmaxf(mrow[r], v);
        }
    }
#pragma unroll
    for (int off = 8; off > 0; off >>= 1)
#pragma unroll
        for (int r = 0; r < 4; ++r)
            mrow[r] = fmaxf(mrow[r], __shfl_xor(mrow[r], off, 16));
    if (ln == 0)
#pragma unroll
        for (int r = 0; r < 4; ++r) red[wv][q * 4 + r] = mrow[r];
    __syncthreads();
    float m4[4];
#pragma unroll
    for (int r = 0; r < 4; ++r)
        m4[r] = fmaxf(fmaxf(red[0][q * 4 + r], red[1][q * 4 + r]),
                      fmaxf(red[2][q * 4 + r], red[3][q * 4 + r]));
    __syncthreads();

    float srow[4] = {0.f, 0.f, 0.f, 0.f};
#pragma unroll
    for (int j = 0; j < 12; ++j)
#pragma unroll
        for (int r = 0; r < 4; ++r) {
            const float e = __expf(acc[j][r] - m4[r]);
            acc[j][r] = e;
            srow[r] += e;
        }
#pragma unroll
    for (int off = 8; off > 0; off >>= 1)
#pragma unroll
        for (int r = 0; r < 4; ++r)
            srow[r] += __shfl_xor(srow[r], off, 16);
    if (ln == 0)
#pragma unroll
        for (int r = 0; r < 4; ++r) red[wv][q * 4 + r] = srow[r];
    __syncthreads();
    float inv[4];
#pragma unroll
    for (int r = 0; r < 4; ++r)
        inv[r] = 1.f / fmaxf(red[0][q * 4 + r] + red[1][q * 4 + r] +
                             red[2][q * 4 + r] + red[3][q * 4 + r], 1e-30f);

    unsigned short* ATl = Bsm;   // 768*20*2 = 30.7 KB <= 36 KB
#pragma unroll
    for (int j = 0; j < 12; ++j) {
        const int c = j >> 2, t = j & 3;
        const int col = c * 256 + wv * 64 + t * 16 + ln;
#pragma unroll
        for (int r = 0; r < 4; ++r) {
            const bf16 b = __float2bfloat16(acc[j][r] * inv[r]);
            const unsigned short u = *(const unsigned short*)&b;
            A[(long)(q * 4 + r) * Nc + col] = *(const bf16*)&u;
            ATl[col * 20 + q * 4 + r] = u;
        }
    }
    __syncthreads();
#pragma unroll
    for (int s = 0; s < 3; ++s) {
        const int m = tid + s * 256;
        uint2 v0 = *(const uint2*)&ATl[m * 20 + 0];
        uint2 v1 = *(const uint2*)&ATl[m * 20 + 4];
        uint2 v2 = *(const uint2*)&ATl[m * 20 + 8];
        uint2 v3 = *(const uint2*)&ATl[m * 20 + 12];
        unsigned short* d = (unsigned short*)&At[(long)m * Nc + by * 16];
        *(uint2*)&d[0]  = v0;
        *(uint2*)&d[4]  = v1;
        *(uint2*)&d[8]  = v2;
        *(uint2*)&d[12] = v3;
    }
}

// ---------------------------------------------------------------------------
// MFMA bf16 NT GEMM — 2-phase double-buffered K-loop (validated r7).
// ---------------------------------------------------------------------------
template <int EPI, typename TC, int XORB = 0, int XCDSWZ = 0, int RAW = 0>
__global__ __launch_bounds__(256) void gemm_nt_mfma(
    const bf16* __restrict__ Ag, const bf16* __restrict__ Btg,
    TC* __restrict__ Cg, bf16* __restrict__ Craw, int M, int N, int K,
    long sA, long sB, long sC, float alpha)
{
    __shared__ unsigned short Asm[2 * 128 * 32];
    __shared__ unsigned short Bsm[2 * 128 * 32];
    constexpr int BUF = 128 * 32;   // elements per buffer

    int bx, by, bz;
    if (XCDSWZ) {
        const int wg = blockIdx.x;
        const int xcd = wg & 7, t = wg >> 3;
        bz = xcd + 8 * (t / 36);
        const int tile = t % 36;
        bx = tile % 6; by = tile / 6;
    } else { bx = blockIdx.x; by = blockIdx.y; bz = blockIdx.z; }

    const int tid  = threadIdx.x;
    const int wv   = tid >> 6;
    const int lane = tid & 63;
    const int q    = lane >> 4;
    const int ln   = lane & 15;
    const int wm   = wv & 1;
    const int wn   = wv >> 1;

    const int zb = XORB ? (bz ^ 16) : bz;
    const bf16* A  = Ag  + (long)bz * sA + (long)(by * 128) * K;
    const bf16* Bt = Btg + (long)zb * sB + (long)(bx * 128) * K;
    TC*         C  = Cg  + (long)bz * sC;

    const int sr = lane >> 2, sc = lane & 3;
    const int scs = sc ^ (sr & 3);          // source col-block pre-swizzle
    const bf16* gA0 = A  + (long)(wv * 32 + sr)      * K + scs * 8;
    const bf16* gA1 = A  + (long)(wv * 32 + 16 + sr) * K + scs * 8;
    const bf16* gB0 = Bt + (long)(wv * 32 + sr)      * K + scs * 8;
    const bf16* gB1 = Bt + (long)(wv * 32 + 16 + sr) * K + scs * 8;
    unsigned short* lA0 = &Asm[(wv * 32)      * 32];
    unsigned short* lA1 = &Asm[(wv * 32 + 16) * 32];
    unsigned short* lB0 = &Bsm[(wv * 32)      * 32];
    unsigned short* lB1 = &Bsm[(wv * 32 + 16) * 32];

    f32x4 acc[4][4];
#pragma unroll
    for (int i = 0; i < 4; ++i)
#pragma unroll
        for (int j = 0; j < 4; ++j)
            acc[i][j] = (f32x4){0.f, 0.f, 0.f, 0.f};

    const int qs = (q ^ (ln & 3)) * 8;      // swizzled read block

    gl_lds16(gA0, lA0);
    gl_lds16(gA1, lA1);
    gl_lds16(gB0, lB0);
    gl_lds16(gB1, lB1);
    __syncthreads();

    int cur = 0;
    for (int k0 = 0; k0 < K; k0 += 32) {
        const int nxt = cur ^ 1;
        if (k0 + 32 < K) {
            const int no = nxt * BUF;
            gl_lds16(gA0 + k0 + 32, lA0 + no);
            gl_lds16(gA1 + k0 + 32, lA1 + no);
            gl_lds16(gB0 + k0 + 32, lB0 + no);
            gl_lds16(gB1 + k0 + 32, lB1 + no);
        }

        const unsigned short* Ac = &Asm[cur * BUF];
        const unsigned short* Bc = &Bsm[cur * BUF];
        short8 af[4], bfr[4];
#pragma unroll
        for (int mt = 0; mt < 4; ++mt) {
            int m = wm * 64 + mt * 16 + ln;
            af[mt] = *(const short8*)&Ac[m * 32 + qs];
        }
#pragma unroll
        for (int nt = 0; nt < 4; ++nt) {
            int n = wn * 64 + nt * 16 + ln;
            bfr[nt] = *(const short8*)&Bc[n * 32 + qs];
        }
#pragma unroll
        for (int mt = 0; mt < 4; ++mt)
#pragma unroll
            for (int nt = 0; nt < 4; ++nt)
                acc[mt][nt] = __builtin_amdgcn_mfma_f32_16x16x32_bf16(
                    af[mt], bfr[nt], acc[mt][nt], 0, 0, 0);

        __syncthreads();
        cur = nxt;
    }

#pragma unroll
    for (int mt = 0; mt < 4; ++mt) {
#pragma unroll
        for (int nt = 0; nt < 4; ++nt) {
            const int col = bx * 128 + wn * 64 + nt * 16 + ln;
            const int rowb = by * 128 + wm * 64 + mt * 16 + q * 4;
#pragma unroll
            for (int r = 0; r < 4; ++r) {
                float vraw = acc[mt][nt][r] * alpha;
                if (RAW) {
                    if (bz < 16)
                        Craw[(long)bz * M * N + (long)(rowb + r) * N + col] =
                            __float2bfloat16(vraw);
                }
                float v = vraw;
                if (EPI == 1) v = __logf(fmaxf(v, 0.f) + EPSF);
                stf(C, (long)(rowb + r) * N + col, v);
            }
        }
    }
}

// ---------------------------------------------------------------------------
// QKV via MFMA, merged sets — 2-phase K-loop (r7). Round 24: V columns are
// written DIRECTLY TRANSPOSED to v1t/v2t[bh][dk][n] (4 consecutive rows pack
// into one 8B store; rowb & 768 both multiples of 4 so a group never
// straddles the batch boundary) — kills the v-transpose launch.
// ---------------------------------------------------------------------------
__global__ __launch_bounds__(256) void qkv_mfma(
    const bf16* __restrict__ X,
    const bf16* __restrict__ w1t, const bf16* __restrict__ w2t,
    bf16* __restrict__ q1, bf16* __restrict__ k1, bf16* __restrict__ v1t,
    bf16* __restrict__ q2, bf16* __restrict__ k2, bf16* __restrict__ v2t)
{
    constexpr int K = Dc;  // 512
    __shared__ unsigned short Asm[2 * 128 * 32];
    __shared__ unsigned short Bsm[2 * 128 * 32];
    constexpr int BUF = 128 * 32;

    const int tid  = threadIdx.x;
    const int wv   = tid >> 6;
    const int lane = tid & 63;
    const int q    = lane >> 4;
    const int ln   = lane & 15;
    const int wm   = wv & 1;
    const int wn   = wv >> 1;
    const int set  = blockIdx.z;

    const bf16* Wt = set ? w2t : w1t;
    bf16* Q  = set ? q2 : q1;
    bf16* Ko = set ? k2 : k1;
    bf16* Vt = set ? v2t : v1t;

    const bf16* A  = X  + (long)(blockIdx.y * 128) * K;
    const bf16* Bt = Wt + (long)(blockIdx.x * 128) * K;

    const int sr = lane >> 2, sc = lane & 3;
    const int scs = sc ^ (sr & 3);
    const bf16* gA0 = A  + (long)(wv * 32 + sr)      * K + scs * 8;
    const bf16* gA1 = A  + (long)(wv * 32 + 16 + sr) * K + scs * 8;
    const bf16* gB0 = Bt + (long)(wv * 32 + sr)      * K + scs * 8;
    const bf16* gB1 = Bt + (long)(wv * 32 + 16 + sr) * K + scs * 8;
    unsigned short* lA0 = &Asm[(wv * 32)      * 32];
    unsigned short* lA1 = &Asm[(wv * 32 + 16) * 32];
    unsigned short* lB0 = &Bsm[(wv * 32)      * 32];
    unsigned short* lB1 = &Bsm[(wv * 32 + 16) * 32];

    f32x4 acc[4][4];
#pragma unroll
    for (int i = 0; i < 4; ++i)
#pragma unroll
        for (int j = 0; j < 4; ++j)
            acc[i][j] = (f32x4){0.f, 0.f, 0.f, 0.f};

    const int qs = (q ^ (ln & 3)) * 8;

    gl_lds16(gA0, lA0);
    gl_lds16(gA1, lA1);
    gl_lds16(gB0, lB0);
    gl_lds16(gB1, lB1);
    __syncthreads();

    int cur = 0;
    for (int k0 = 0; k0 < K; k0 += 32) {
        const int nxt = cur ^ 1;
        if (k0 + 32 < K) {
            const int no = nxt * BUF;
            gl_lds16(gA0 + k0 + 32, lA0 + no);
            gl_lds16(gA1 + k0 + 32, lA1 + no);
            gl_lds16(gB0 + k0 + 32, lB0 + no);
            gl_lds16(gB1 + k0 + 32, lB1 + no);
        }

        const unsigned short* Ac = &Asm[cur * BUF];
        const unsigned short* Bc = &Bsm[cur * BUF];
        short8 af[4], bfr[4];
#pragma unroll
        for (int mt = 0; mt < 4; ++mt) {
            int m = wm * 64 + mt * 16 + ln;
            af[mt] = *(const short8*)&Ac[m * 32 + qs];
        }
#pragma unroll
        for (int nt = 0; nt < 4; ++nt) {
            int n = wn * 64 + nt * 16 + ln;
            bfr[nt] = *(const short8*)&Bc[n * 32 + qs];
        }
#pragma unroll
        for (int mt = 0; mt < 4; ++mt)
#pragma unroll
            for (int nt = 0; nt < 4; ++nt)
                acc[mt][nt] = __builtin_amdgcn_mfma_f32_16x16x32_bf16(
                    af[mt], bfr[nt], acc[mt][nt], 0, 0, 0);

        __syncthreads();
        cur = nxt;
    }

#pragma unroll
    for (int mt = 0; mt < 4; ++mt) {
#pragma unroll
        for (int nt = 0; nt < 4; ++nt) {
            const int col  = blockIdx.x * 128 + wn * 64 + nt * 16 + ln;
            const int rowb = blockIdx.y * 128 + wm * 64 + mt * 16 + q * 4;
            const int t = col >> 9;
            const int h = (col >> 6) & 7;
            const int dk = col & 63;
            if (t == 2) {
                // V: transposed store — 4 consecutive rows -> one 8B write
                const int b = rowb >= Nc ? 1 : 0;
                const int n = rowb - b * Nc;
                unsigned short o[4];
#pragma unroll
                for (int r = 0; r < 4; ++r) {
                    const bf16 bb = __float2bfloat16(acc[mt][nt][r]);
                    o[r] = *(const unsigned short*)&bb;
                }
                unsigned short* d = (unsigned short*)Vt +
                    (((long)b * Hc + h) * DKc + dk) * Nc + n;
                *(uint2*)d = *(const uint2*)o;
            } else {
                bf16* dst = (t == 0) ? Q : Ko;
#pragma unroll
                for (int r = 0; r < 4; ++r) {
                    const int row = rowb + r;
                    const int b = row >= Nc ? 1 : 0;
                    const int n = row - b * Nc;
                    dst[(((long)b * Hc + h) * Nc + n) * DKc + dk] =
                        __float2bfloat16(acc[mt][nt][r]);
                }
            }
        }
    }
}

// ---------------------------------------------------------------------------
// MFMA bf16 NT narrow GEMM core (validated): acc = A(128,K) @ Bt(64,K)^T.
// ---------------------------------------------------------------------------
struct N64Acc { f32x4 acc[2][4]; };

template <typename DUMMY = void>
DEVINL void n64_core(const bf16* A, const bf16* Bt, int K,
                     unsigned short* Asm, unsigned short* Bsm, N64Acc& R)
{
    const int tid  = threadIdx.x;
    const int wave = tid >> 6;
    const int lane = tid & 63;
    const int q    = lane >> 4;
    const int ln   = lane & 15;

    const int sr = tid >> 3, k8 = tid & 7;
    const bf16* pa[4];
    const bf16* pb[2];
    int wa[4], wb[2];
#pragma unroll
    for (int i = 0; i < 4; ++i) {
        pa[i] = A + (long)(sr + i * 32) * K + k8 * 8;
        wa[i] = (sr + i * 32) * 72 + k8 * 8;
    }
#pragma unroll
    for (int i = 0; i < 2; ++i) {
        pb[i] = Bt + (long)(sr + i * 32) * K + k8 * 8;
        wb[i] = (sr + i * 32) * 72 + k8 * 8;
    }

#pragma unroll
    for (int i = 0; i < 2; ++i)
#pragma unroll
        for (int j = 0; j < 4; ++j)
            R.acc[i][j] = (f32x4){0.f, 0.f, 0.f, 0.f};

    for (int k0 = 0; k0 < K; k0 += 64) {
        uint4 va[4], vb[2];
#pragma unroll
        for (int i = 0; i < 4; ++i) va[i] = *(const uint4*)(pa[i] + k0);
#pragma unroll
        for (int i = 0; i < 2; ++i) vb[i] = *(const uint4*)(pb[i] + k0);
        __syncthreads();
#pragma unroll
        for (int i = 0; i < 4; ++i) *(uint4*)&Asm[wa[i]] = va[i];
#pragma unroll
        for (int i = 0; i < 2; ++i) *(uint4*)&Bsm[wb[i]] = vb[i];
        __syncthreads();

#pragma unroll
        for (int kc = 0; kc < 2; ++kc) {
            short8 af[2], bfr[4];
#pragma unroll
            for (int mt = 0; mt < 2; ++mt) {
                int m = wave * 32 + mt * 16 + ln;
                af[mt] = *(const short8*)&Asm[m * 72 + kc * 32 + q * 8];
            }
#pragma unroll
            for (int nt = 0; nt < 4; ++nt) {
                int n = nt * 16 + ln;
                bfr[nt] = *(const short8*)&Bsm[n * 72 + kc * 32 + q * 8];
            }
#pragma unroll
            for (int mt = 0; mt < 2; ++mt)
#pragma unroll
                for (int nt = 0; nt < 4; ++nt)
                    R.acc[mt][nt] = __builtin_amdgcn_mfma_f32_16x16x32_bf16(
                        af[mt], bfr[nt], R.acc[mt][nt], 0, 0, 0);
        }
    }
}

// ---------------------------------------------------------------------------
// HALF-HEIGHT n64 core — acc = A(64,K) @ Bt(64,K)^T (validated r9).
// ---------------------------------------------------------------------------
struct N64hAcc { f32x4 acc[4]; };

template <typename DUMMY = void>
DEVINL void n64h_core(const bf16* A, const bf16* Bt, int K,
                      unsigned short* Asm, unsigned short* Bsm, N64hAcc& R)
{
    const int tid  = threadIdx.x;
    const int wave = tid >> 6;
    const int lane = tid & 63;
    const int q    = lane >> 4;
    const int ln   = lane & 15;

    const int sr = tid >> 3, k8 = tid & 7;   // sr 0..31, k8 0..7
    const bf16* pa[2];
    const bf16* pb[2];
    int wa[2], wb[2];
#pragma unroll
    for (int i = 0; i < 2; ++i) {
        pa[i] = A  + (long)(sr + i * 32) * K + k8 * 8;
        wa[i] = (sr + i * 32) * 72 + k8 * 8;
        pb[i] = Bt + (long)(sr + i * 32) * K + k8 * 8;
        wb[i] = wa[i];
    }

#pragma unroll
    for (int j = 0; j < 4; ++j)
        R.acc[j] = (f32x4){0.f, 0.f, 0.f, 0.f};

    for (int k0 = 0; k0 < K; k0 += 64) {
        uint4 va[2], vb[2];
#pragma unroll
        for (int i = 0; i < 2; ++i) va[i] = *(const uint4*)(pa[i] + k0);
#pragma unroll
        for (int i = 0; i < 2; ++i) vb[i] = *(const uint4*)(pb[i] + k0);
        __syncthreads();
#pragma unroll
        for (int i = 0; i < 2; ++i) *(uint4*)&Asm[wa[i]] = va[i];
#pragma unroll
        for (int i = 0; i < 2; ++i) *(uint4*)&Bsm[wb[i]] = vb[i];
        __syncthreads();

#pragma unroll
        for (int kc = 0; kc < 2; ++kc) {
            short8 af;
            af = *(const short8*)&Asm[(wave * 16 + ln) * 72 + kc * 32 + q * 8];
            short8 bfr[4];
#pragma unroll
            for (int nt = 0; nt < 4; ++nt) {
                int n = nt * 16 + ln;
                bfr[nt] = *(const short8*)&Bsm[n * 72 + kc * 32 + q * 8];
            }
#pragma unroll
            for (int nt = 0; nt < 4; ++nt)
                R.acc[nt] = __builtin_amdgcn_mfma_f32_16x16x32_bf16(
                    af, bfr[nt], R.acc[nt], 0, 0, 0);
        }
    }
}

// ---------------------------------------------------------------------------
// Merged pair launch (Path-B fallback only; validated round 11).
// ---------------------------------------------------------------------------
__global__ __launch_bounds__(256) void gemm_n64_pair(
    const bf16* __restrict__ A0g, const bf16* __restrict__ B0g, bf16* __restrict__ C0tg,
    const bf16* __restrict__ A1g, const bf16* __restrict__ B1g, bf16* __restrict__ C1g,
    int M, int K, long sA, long sB, long sC)
{
    __shared__ unsigned short Asm[128 * 72];
    __shared__ unsigned short Bsm[64 * 72];

    const int zz = blockIdx.z & 15;
    const int second = blockIdx.z >> 4;
    const bf16* A  = (second ? A1g : A0g) + (long)zz * sA + (long)(blockIdx.y * 128) * K;
    const bf16* Bt = (second ? B1g : B0g) + (long)zz * sB;

    N64Acc R;
    n64_core(A, Bt, K, Asm, Bsm, R);

    const int tid = threadIdx.x;
    const int wave = tid >> 6, lane = tid & 63, q = lane >> 4, ln = lane & 15;

    if (second) {
        bf16* C = C1g + (long)zz * sC;
#pragma unroll
        for (int mt = 0; mt < 2; ++mt) {
#pragma unroll
            for (int nt = 0; nt < 4; ++nt) {
                const int col  = nt * 16 + ln;
                const int rowb = blockIdx.y * 128 + wave * 32 + mt * 16 + q * 4;
#pragma unroll
                for (int r = 0; r < 4; ++r)
                    C[(long)(rowb + r) * 64 + col] = __float2bfloat16(R.acc[mt][nt][r]);
            }
        }
    } else {
        __syncthreads();
#pragma unroll
        for (int mt = 0; mt < 2; ++mt) {
#pragma unroll
            for (int nt = 0; nt < 4; ++nt) {
                const int col = nt * 16 + ln;
                const int rwb = wave * 32 + mt * 16 + q * 4;
#pragma unroll
                for (int r = 0; r < 4; ++r)
                    *(bf16*)&Asm[col * 136 + rwb + r] = __float2bfloat16(R.acc[mt][nt][r]);
            }
        }
        __syncthreads();
        bf16* Ct = C0tg + (long)zz * sC;
        const int dk  = tid >> 2;
        const int nc0 = (tid & 3) * 32;
        const int gn0 = blockIdx.y * 128;
#pragma unroll
        for (int c8 = 0; c8 < 4; ++c8) {
            uint4 v = *(const uint4*)&Asm[dk * 136 + nc0 + c8 * 8];
            *(uint4*)&Ct[(long)dk * Nc + gn0 + nc0 + c8 * 8] = v;
        }
    }
}

// ---------------------------------------------------------------------------
// Merged y kernel, half-height tiles (Path A; validated r9). 192 blocks.
// ---------------------------------------------------------------------------
__global__ __launch_bounds__(256) void gemm_n64_both_h(
    const bf16* __restrict__ Ab, const bf16* __restrict__ v1t,
    const bf16* __restrict__ Craw, const bf16* __restrict__ v2t,
    const float* __restrict__ smallf, bf16* __restrict__ yc,
    int K, long sA, long sB)
{
    __shared__ unsigned short Asm[64 * 72];
    __shared__ unsigned short Bsm[64 * 72];

    const int bh = blockIdx.z;
    const long arow = (long)(blockIdx.y * 64) * K;

    N64hAcc R1;
    n64h_core(Ab + (long)bh * sA + arow, v1t + (long)bh * sB, K, Asm, Bsm, R1);
    N64hAcc R2;
    n64h_core(Craw + (long)bh * sA + arow, v2t + (long)bh * sB, K, Asm, Bsm, R2);

    const float w = sigf(smallf[392]);
    const int b = bh >> 3, h = bh & 7;

    const int tid = threadIdx.x;
    const int wave = tid >> 6, lane = tid & 63, q = lane >> 4, ln = lane & 15;
#pragma unroll
    for (int nt = 0; nt < 4; ++nt) {
        const int col  = nt * 16 + ln;
        const int rowb = blockIdx.y * 64 + wave * 16 + q * 4;
#pragma unroll
        for (int r = 0; r < 4; ++r) {
            const int n = rowb + r;
            yc[((long)(b * Nc + n)) * Dc + h * DKc + col] =
                __float2bfloat16(R1.acc[nt][r] + w * R2.acc[nt][r]);
        }
    }
}

// y_chain GEMM with fused combine + permute (Path-B fallback only).
__global__ __launch_bounds__(256) void gemm_n64_combine(
    const bf16* __restrict__ A1b, const bf16* __restrict__ trt,
    const bf16* __restrict__ yb1, const float* __restrict__ smallf,
    bf16* __restrict__ yc, int M, int K, long sA, long sB)
{
    __shared__ unsigned short Asm[128 * 72];
    __shared__ unsigned short Bsm[64 * 72];

    const int bh = blockIdx.z;
    const bf16* A  = A1b + (long)bh * sA + (long)(blockIdx.y * 128) * K;
    const bf16* Bt = trt + (long)bh * sB;

    N64Acc R;
    n64_core(A, Bt, K, Asm, Bsm, R);

    const float w = sigf(smallf[392]);
    const int b = bh >> 3, h = bh & 7;
    const long yb1base = (long)bh * Nc * DKc;

    const int tid = threadIdx.x;
    const int wave = tid >> 6, lane = tid & 63, q = lane >> 4, ln = lane & 15;
#pragma unroll
    for (int mt = 0; mt < 2; ++mt) {
#pragma unroll
        for (int nt = 0; nt < 4; ++nt) {
            const int col  = nt * 16 + ln;
            const int rowb = blockIdx.y * 128 + wave * 32 + mt * 16 + q * 4;
#pragma unroll
            for (int r = 0; r < 4; ++r) {
                const int n = rowb + r;
                const float base = __bfloat162float(yb1[yb1base + (long)n * 64 + col]);
                yc[((long)(b * Nc + n)) * Dc + h * DKc + col] =
                    __float2bfloat16(base + w * R.acc[mt][nt][r]);
            }
        }
    }
}

// Path-B y_base GEMM (fallback only).
__global__ __launch_bounds__(256) void gemm_n64_yb(
    const bf16* __restrict__ Ag, const bf16* __restrict__ Btg,
    bf16* __restrict__ Cg, int M, int K, long sA, long sB, long sC)
{
    __shared__ unsigned short Asm[128 * 72];
    __shared__ unsigned short Bsm[64 * 72];

    const int zz = blockIdx.z;
    const bf16* A  = Ag + (long)zz * sA + (long)(blockIdx.y * 128) * K;
    const bf16* Bt = Btg + (long)zz * sB;

    N64Acc R;
    n64_core(A, Bt, K, Asm, Bsm, R);

    bf16* C = Cg + (long)zz * sC;
    const int tid = threadIdx.x;
    const int wave = tid >> 6, lane = tid & 63, q = lane >> 4, ln = lane & 15;
#pragma unroll
    for (int mt = 0; mt < 2; ++mt) {
#pragma unroll
        for (int nt = 0; nt < 4; ++nt) {
            const int col  = nt * 16 + ln;
            const int rowb = blockIdx.y * 128 + wave * 32 + mt * 16 + q * 4;
#pragma unroll
            for (int r = 0; r < 4; ++r)
                C[(long)(rowb + r) * 64 + col] = __float2bfloat16(R.acc[mt][nt][r]);
        }
    }
}

// ---------------------------------------------------------------------------
// Row softmax over width 768 — wave-per-row (validated round 16).
// ---------------------------------------------------------------------------
__global__ __launch_bounds__(256) void softmax_rows_w(
    const float* __restrict__ src, bf16* __restrict__ dst)
{
    const int wid  = threadIdx.x >> 6;
    const int lane = threadIdx.x & 63;
    const long row = (long)blockIdx.x * 4 + wid;
    const float* s = src + row * Nc;

    float4 v[3];
#pragma unroll
    for (int i = 0; i < 3; ++i)
        v[i] = *(const float4*)&s[i * 256 + lane * 4];

    float m = -1e30f;
#pragma unroll
    for (int i = 0; i < 3; ++i)
        m = fmaxf(m, fmaxf(fmaxf(v[i].x, v[i].y), fmaxf(v[i].z, v[i].w)));
#pragma unroll
    for (int off = 32; off > 0; off >>= 1)
        m = fmaxf(m, __shfl_xor(m, off, 64));

    float e[12];
    float sum = 0.f;
#pragma unroll
    for (int i = 0; i < 3; ++i) {
        e[i * 4 + 0] = __expf(v[i].x - m);
        e[i * 4 + 1] = __expf(v[i].y - m);
        e[i * 4 + 2] = __expf(v[i].z - m);
        e[i * 4 + 3] = __expf(v[i].w - m);
        sum += e[i * 4 + 0] + e[i * 4 + 1] + e[i * 4 + 2] + e[i * 4 + 3];
    }
#pragma unroll
    for (int off = 32; off > 0; off >>= 1)
        sum += __shfl_xor(sum, off, 64);

    const float inv = 1.f / fmaxf(sum, 1e-30f);
    unsigned short* d = (unsigned short*)dst + row * Nc;
#pragma unroll
    for (int i = 0; i < 3; ++i) {
        unsigned short o[4];
#pragma unroll
        for (int j = 0; j < 4; ++j) {
            const bf16 b = __float2bfloat16(e[i * 4 + j] * inv);
            o[j] = *(const unsigned short*)&b;
        }
        *(uint2*)&d[i * 256 + lane * 4] = *(const uint2*)o;
    }
}

// ---------------------------------------------------------------------------
// Gate network + Smix — r7-validated 2-elem body, 32x16 tiling (r11 lesson:
// this tiling is load-bearing for L2 reuse of the transposed S reads —
// the 8-row strip fusion doubled FETCH and lost occupancy; reverted).
// ---------------------------------------------------------------------------
__global__ __launch_bounds__(256) void gates_smix(
    const float* __restrict__ S1g, const float* __restrict__ S2g,
    const bf16* __restrict__ Crg, const bf16* __restrict__ Clg,
    float* __restrict__ Smixg, const float* __restrict__ smallf)
{
    __shared__ float t1t[32][17], t2t[32][17];

    const long mat = (long)blockIdx.z * Nc * Nc;
    const float* S1 = S1g + mat;
    const float* S2 = S2g + mat;
    const unsigned short* Cr = (const unsigned short*)Crg + mat;
    const unsigned short* Cl = (const unsigned short*)Clg + mat;
    float* Smix = Smixg + mat;

    const int tid = threadIdx.x;

    const int n0 = blockIdx.y * 16, m0 = blockIdx.x * 32;
    {
        const int r = tid >> 3, c2 = (tid & 7) * 2;
        const float2 a = *(const float2*)&S1[(long)(m0 + r) * Nc + n0 + c2];
        const float2 b = *(const float2*)&S2[(long)(m0 + r) * Nc + n0 + c2];
        t1t[r][c2] = a.x; t1t[r][c2 + 1] = a.y;
        t2t[r][c2] = b.x; t2t[r][c2 + 1] = b.y;
    }
    __syncthreads();

    const int tx = tid & 15, ty = tid >> 4;
    const int n = n0 + ty;
    const long idx = (long)n * Nc + m0 + tx * 2;

    const float2 s1v = *(const float2*)&S1[idx];
    const float2 s2v = *(const float2*)&S2[idx];
    const unsigned cru = *(const unsigned*)&Cr[idx];
    const unsigned clu = *(const unsigned*)&Cl[idx];

    const f32x2 s1a = {s1v.x, s1v.y};
    const f32x2 s2a = {s2v.x, s2v.y};
    const f32x2 cra = {__uint_as_float((cru & 0xffffu) << 16),
                       __uint_as_float(cru & 0xffff0000u)};
    const f32x2 cla = {__uint_as_float((clu & 0xffffu) << 16),
                       __uint_as_float(clu & 0xffff0000u)};
    const f32x2 s1t = {t1t[tx * 2][ty], t1t[tx * 2 + 1][ty]};
    const f32x2 s2t = {t2t[tx * 2][ty], t2t[tx * 2 + 1][ty]};

    f32x2 g0 = *(const f32x2*)&smallf[384];
    f32x2 g1 = *(const f32x2*)&smallf[386];
    f32x2 g2 = *(const f32x2*)&smallf[388];
    f32x2 g3 = *(const f32x2*)&smallf[390];

    const f32x2 gc1  = splat2(-2.30220902f);
    const f32x2 gc3  = splat2(-0.10294357f);
    const f32x2 one2 = splat2(1.f);

#pragma unroll
    for (int u = 0; u < 16; ++u) {
        const f32x2* cw = (const f32x2*)&smallf[u * 24];
        f32x2 h = cw[6];
        h = fma2(s1a, cw[0], h);
        h = fma2(s2a, cw[1], h);
        h = fma2(s1t, cw[2], h);
        h = fma2(s2t, cw[3], h);
        h = fma2(cra, cw[4], h);
        h = fma2(cla, cw[5], h);
        const f32x2 hh = h * h;
        const f32x2 z2 = h * fma2(hh, gc3, gc1);
        f32x2 e;  e[0]  = vexp2(z2[0]); e[1]  = vexp2(z2[1]);
        const f32x2 d = one2 + e;
        f32x2 rc; rc[0] = vrcp(d[0]);   rc[1] = vrcp(d[1]);
        const f32x2 hid = h * rc;
        g0 = fma2(hid, cw[8],  g0);
        g1 = fma2(hid, cw[9],  g1);
        g2 = fma2(hid, cw[10], g2);
        g3 = fma2(hid, cw[11], g3);
    }

    const f32x2 nl2e = splat2(-1.44269504f);
    const f32x2 ln2v = splat2(0.69314718f);
    auto sig2 = [&](f32x2 x) -> f32x2 {
        const f32x2 t = x * nl2e;
        f32x2 e;  e[0] = vexp2(t[0]); e[1] = vexp2(t[1]);
        const f32x2 d = one2 + e;
        f32x2 r;  r[0] = vrcp(d[0]);  r[1] = vrcp(d[1]);
        return r;
    };
    const f32x2 ga2 = sig2(g0);
    const f32x2 go2 = sig2(g1);
    const f32x2 gn2 = sig2(g2);
    const f32x2 gc2 = sig2(g3);

    const f32x2 dd = s1a - s2a;
    f32x2 ad; ad[0] = fabsf(dd[0]); ad[1] = fabsf(dd[1]);
    const f32x2 t2 = ad * nl2e;
    f32x2 ee; ee[0] = vexp2(t2[0]); ee[1] = vexp2(t2[1]);
    const f32x2 lp = one2 + ee;
    f32x2 lg; lg[0] = vlog2(lp[0]); lg[1] = vlog2(lp[1]);
    const f32x2 mx2 = __builtin_elementwise_max(s1a, s2a);
    const f32x2 lae = fma2(lg, ln2v, mx2);

    f32x2 o2 = s1a;
    o2 = fma2(ga2, s2a, o2);
    o2 = fma2(go2, lae - s1a, o2);
    o2 = fma2(gn2, s2a * splat2(-BETA_NOT), o2);
    o2 = fma2(gc2, cra, o2);
    *(float2*)&Smix[idx] = (float2){o2[0], o2[1]};
}

// ---------------------------------------------------------------------------
// Final projection, half-height tiles — 192 blocks (validated r9).
// ---------------------------------------------------------------------------
__global__ __launch_bounds__(256) void proj_n64h(
    const bf16* __restrict__ yc, const bf16* __restrict__ pwt,
    const void* __restrict__ xraw, void* __restrict__ out)
{
    constexpr int K = Dc;  // 512
    constexpr int N = Dc;  // 512
    __shared__ unsigned short Asm[64 * 72];
    __shared__ unsigned short Bsm[64 * 72];
    __shared__ int is32s;
    if (threadIdx.x == 0) is32s = sniff_is_fp32(xraw);

    const bf16* A  = yc  + (long)(blockIdx.y * 64) * K;
    const bf16* Bt = pwt + (long)(blockIdx.x * 64) * K;

    N64hAcc R;
    n64h_core(A, Bt, K, Asm, Bsm, R);   // internal barriers publish is32s

    const int is32 = is32s;
    const int tid = threadIdx.x;
    const int wave = tid >> 6, lane = tid & 63, q = lane >> 4, ln = lane & 15;
#pragma unroll
    for (int nt = 0; nt < 4; ++nt) {
        const int col  = blockIdx.x * 64 + nt * 16 + ln;
        const int rowb = blockIdx.y * 64 + wave * 16 + q * 4;
#pragma unroll
        for (int r = 0; r < 4; ++r) {
            const long o = (long)(rowb + r) * N + col;
            if (is32) ((float*)out)[o] = R.acc[nt][r];
            else      ((bf16*)out)[o] = __float2bfloat16(R.acc[nt][r]);
        }
    }
}

// ---------------------------------------------------------------------------
extern "C" void kernel_launch(void* const* d_in, const int* in_sizes, int n_in,
                              void* d_out, int out_size, void* d_ws, size_t ws_size,
                              hipStream_t stream)
{
    const size_t HD   = (size_t)BHc * Nc * DKc;   // 786432
    const size_t HDh  = HD / 2;                   // float-slots for HD bf16
    const size_t MAT  = (size_t)Nc * Nc;          // 589824
    const size_t MATS = (size_t)BHc * MAT;        // 9437184
    const long   HSTR = (long)Nc * DKc;           // 49152 per-head stride

    float* ws = (float*)d_ws;
    size_t off = 0;
    auto alloc = [&](size_t n) { float* p = ws + off; off += n; return p; };

    bf16* xb  = (bf16*)alloc(HDh);
    bf16* w1b = (bf16*)alloc(HDh);   // w1b/w2b adjacent -> merged transpose
    bf16* w2b = (bf16*)alloc(HDh);
    bf16* w1t = (bf16*)alloc(HDh);
    bf16* w2t = (bf16*)alloc(HDh);
    bf16* pwb = (bf16*)alloc((size_t)Dc * Dc / 2);
    bf16* pwt = (bf16*)alloc((size_t)Dc * Dc / 2);
    float* smallf = alloc(512);
    // q1|q2 and k1|k2 adjacent -> single merged fused-S launch (32 batches)
    bf16* q1b = (bf16*)alloc(HDh); bf16* q2b = (bf16*)alloc(HDh);
    bf16* k1b = (bf16*)alloc(HDh); bf16* k2b = (bf16*)alloc(HDh);
    bf16* v1b = (bf16*)alloc(HDh); bf16* v2b = (bf16*)alloc(HDh);  // (unused)
    bf16* v1t = (bf16*)alloc(HDh); bf16* v2t = (bf16*)alloc(HDh);  // adjacent
    bf16* trt = (bf16*)alloc(HDh);
    float* S1   = alloc(MATS);       // S1/S2 adjacent
    float* S2   = alloc(MATS);
    float* Smix = alloc(MATS);       // region reused: A1tb|A2tb, then Smix
    bf16* A1b = (bf16*)alloc(MATS / 2);  // A1b/A2b adjacent
    bf16* A2b = (bf16*)alloc(MATS / 2);
    bf16* Crb = (bf16*)alloc(MATS / 2);  // Crb/Clb adjacent (merged launch)
    bf16* Clb = (bf16*)alloc(MATS / 2);
    bf16* yb1 = (bf16*)alloc(HDh);
    bf16* yc  = (bf16*)alloc(HDh);

    const size_t NEED_BASE = off * sizeof(float);
    bf16* Crawb = (bf16*)alloc(MATS / 2);          // raw C_right (Path A only)
    const size_t NEED_A = off * sizeof(float);
    const int pathA = ws_size >= NEED_A;

    // aliases into dead regions
    bf16* A1tb = (bf16*)Smix;            // live steps 3-4 (dead once gates writes Smix)
    bf16* A2tb = ((bf16*)Smix) + MATS;
    bf16* Ab   = (bf16*)S1;              // S1 dead after gates

    if (ws_size < NEED_BASE) {
        fill_sentinel<<<dim3(3072), 256, 0, stream>>>((unsigned short*)d_out);
        return;
    }

    // 0. normalize inputs
    convert_all<<<dim3(3072), 256, 0, stream>>>(
        d_in[0], d_in[1], d_in[2], d_in[3], d_in[4], d_in[5], d_in[6], d_in[7],
        d_in[8], xb, w1b, w2b, pwb, smallf);

    // 1. merged W + pw transpose; QKV (V written transposed — no v-transpose)
    transpose_wpw<<<dim3(24, 8, 3), 256, 0, stream>>>(
        (const unsigned short*)w1b, (unsigned short*)w1t,
        (const unsigned short*)pwb, (unsigned short*)pwt);
    qkv_mfma<<<dim3(12, 12, 2), 256, 0, stream>>>(
        xb, w1t, w2t, q1b, k1b, v1t, q2b, k2b, v2t);

    // 2+3. FUSED: S = scale*q@k^T, row softmax -> A, A^T (validated r10)
    sgemm_softmax<<<dim3(1536), 256, 0, stream>>>(
        q1b, k1b, S1, A1b, A1tb);

    // 4. Cr|Cl in ONE 32-batch launch; XCD-pinned 1-D grid; 2-phase K-loop;
    //    Path A also stores raw C_right.
    if (pathA)
        gemm_nt_mfma<1, bf16, 1, 1, 1><<<dim3(1152), 256, 0, stream>>>(
            A1b, A1tb, Crb, Crawb, Nc, Nc, Nc, (long)MAT, (long)MAT, (long)MAT, 1.f);
    else
        gemm_nt_mfma<1, bf16, 1, 1, 0><<<dim3(1152), 256, 0, stream>>>(
            A1b, A1tb, Crb, nullptr, Nc, Nc, Nc, (long)MAT, (long)MAT, (long)MAT, 1.f);

    // 5. gates + Smix (r7-validated 2-elem body, 32x16 tiling)
    gates_smix<<<dim3(24, 48, BHc), 256, 0, stream>>>(S1, S2, Crb, Clb, Smix, smallf);

    // 6. A = softmax(Smix) -> bf16 (into S1 alias, wave-per-row)
    softmax_rows_w<<<(BHc * Nc) / 4, 256, 0, stream>>>(Smix, Ab);

    if (pathA) {
        // 7. merged y, half-height tiles: 192 blocks
        gemm_n64_both_h<<<dim3(1, 12, BHc), 256, 0, stream>>>(
            Ab, v1t, Crawb, v2t, smallf, yc, Nc, (long)MAT, HSTR);
    } else {
        // Path B fallback (needs trt path; v1t/v2t already transposed)
        gemm_n64_pair<<<dim3(1, 6, 2 * BHc), 256, 0, stream>>>(
            A2b, v2t, trt, Ab, v1t, yb1, Nc, Nc, (long)MAT, HSTR, HSTR);
        gemm_n64_combine<<<dim3(1, 6, BHc), 256, 0, stream>>>(
            A1b, trt, yb1, smallf, yc, Nc, Nc, (long)MAT, HSTR);
    }

    // 9. proj, half-height tiles: 192 blocks
    proj_n64h<<<dim3(8, 24, 1), 256, 0, stream>>>(yc, pwt, d_in[0], d_out);
}

// Round 13
// 326.239 us; speedup vs baseline: 1.0197x; 1.0135x over previous
//
#include <hip/hip_runtime.h>
#include <hip/hip_bf16.h>
#include <math.h>

typedef __hip_bfloat16 bf16;
typedef __attribute__((ext_vector_type(8))) short short8;   // 8 bf16 (4 VGPRs)
typedef __attribute__((ext_vector_type(4))) float f32x4;
typedef __attribute__((ext_vector_type(2))) float f32x2;
#define DEVINL __device__ __forceinline__

constexpr int Bc  = 2;
constexpr int Nc  = 768;
constexpr int Dc  = 512;
constexpr int Hc  = 8;
constexpr int DKc = 64;
constexpr int BHc = Bc * Hc;
constexpr float SCALE    = 0.125f;   // 1/sqrt(64)
constexpr float EPSF     = 1e-6f;
constexpr float BETA_NOT = 0.5f;

DEVINL float ldf(const float* p, long i) { return p[i]; }
DEVINL float ldf(const bf16* p, long i) { return __bfloat162float(p[i]); }
DEVINL void stf(float* p, long i, float v) { p[i] = v; }
DEVINL void stf(bf16* p, long i, float v) { p[i] = __float2bfloat16(v); }

DEVINL float sigf(float x) { return __fdividef(1.f, 1.f + __expf(-x)); }

// packed fp32 pair helpers — backend selects v_pk_fma_f32/v_pk_mul_f32 (r3:
// validated -41% on gates_smix; r4 pair-dup operands -12%; r5 s_load weights).
DEVINL f32x2 fma2(f32x2 a, f32x2 b, f32x2 c) { return __builtin_elementwise_fma(a, b, c); }
DEVINL f32x2 splat2(float x) { return (f32x2){x, x}; }
// guard-free transcendentals (libm exp2f adds a denormal guard: +13% in r2)
DEVINL float vexp2(float x) { float r; asm("v_exp_f32 %0, %1" : "=v"(r) : "v"(x)); return r; }
DEVINL float vrcp(float x)  { float r; asm("v_rcp_f32 %0, %1" : "=v"(r) : "v"(x)); return r; }
DEVINL float vlog2(float x) { float r; asm("v_log_f32 %0, %1" : "=v"(r) : "v"(x)); return r; }

// async global->LDS, 16B per lane; LDS dest = wave-uniform base + lane*16.
DEVINL void gl_lds16(const void* g, void* l) {
    __builtin_amdgcn_global_load_lds(
        (const __attribute__((address_space(1))) void*)g,
        (__attribute__((address_space(3))) void*)l, 16, 0, 0);
}

// ---------------------------------------------------------------------------
// Dtype sniffer — vectorized (validated round 9).
// ---------------------------------------------------------------------------
DEVINL int sniff_is_fp32(const void* xraw) {
    const uint4* p4 = (const uint4*)xraw;
    float mx = 0.f;
#pragma unroll
    for (int j = 0; j < 16; ++j) {
        const uint4 u = p4[j];
        const unsigned w[4] = {u.x, u.y, u.z, u.w};
#pragma unroll
        for (int t = 0; t < 4; ++t) {
            mx = fmaxf(mx, fabsf(__uint_as_float((w[t] & 0xffffu) << 16)));
            mx = fmaxf(mx, fabsf(__uint_as_float(w[t] & 0xffff0000u)));
        }
    }
    return mx > 1000.f ? 1 : 0;
}

DEVINL float cvt_elem(const void* s, long j, int is32) {
    return is32 ? ((const float*)s)[j]
                : __bfloat162float(((const bf16*)s)[j]);
}

// smallf layout (round 15 — PAIR-DUPLICATED; read via uniform scalar loads):
//   [u*24 + 2k+{0,1}]  = w1[u][k]          k=0..5   (12 floats)
//   [u*24 + 12..13]    = b1[u] pair
//   [u*24 + 14..15]    = pad
//   [u*24 + 16 + 2o+{0,1}] = conv2_w[o][u] o=0..3   (8 floats)
//   [384..391]  conv2_b[o] pairs
//   [392..393]  chain_logit pair          (combine reads [392])
__global__ __launch_bounds__(256) void convert_all(
    const void* x, const void* w1, const void* w2, const void* pw,
    const void* c1w, const void* c1b, const void* c2w, const void* c2b,
    const void* ch,
    bf16* xb, bf16* w1b, bf16* w2b, bf16* pwb, float* smallf)
{
    __shared__ int is32s;
    if (threadIdx.x == 0) is32s = sniff_is_fp32(x);
    __syncthreads();
    const int is32 = is32s;
    const long i = (long)blockIdx.x * 256 + threadIdx.x;
    if (i < (long)Bc * Nc * Dc) {
        xb[i]  = __float2bfloat16(cvt_elem(x,  i, is32));
        w1b[i] = __float2bfloat16(cvt_elem(w1, i, is32));
        w2b[i] = __float2bfloat16(cvt_elem(w2, i, is32));
    }
    if (i < (long)Dc * Dc) pwb[i] = __float2bfloat16(cvt_elem(pw, i, is32));
    if (i < 384) {
        const int u = (int)i / 24, k = (int)i % 24;
        float v = 0.f;
        if (k < 12)      v = cvt_elem(c1w, u * 6 + (k >> 1), is32);
        else if (k < 14) v = cvt_elem(c1b, u, is32);
        else if (k >= 16) { const int o = (k - 16) >> 1; v = cvt_elem(c2w, o * 16 + u, is32); }
        smallf[i] = v;
    } else if (i < 392) smallf[i] = cvt_elem(c2b, ((int)i - 384) >> 1, is32);
    else if (i < 394) smallf[i] = cvt_elem(ch, 0, is32);
    else if (i < 512) smallf[i] = 0.f;
}

__global__ __launch_bounds__(256) void fill_sentinel(unsigned short* o) {
    const long i = (long)blockIdx.x * 256 + threadIdx.x;
    if (i < (long)Bc * Nc * Dc) o[i] = 0x40E0;  // bf16 7.0
}

// ---------------------------------------------------------------------------
// Merged W + pw transpose — one launch (z=0,1: W sets; z=2: pw). (r11, kept)
// ---------------------------------------------------------------------------
__global__ __launch_bounds__(256) void transpose_wpw(
    const unsigned short* __restrict__ wb, unsigned short* __restrict__ wt,
    const unsigned short* __restrict__ pwb, unsigned short* __restrict__ pwt)
{
    __shared__ unsigned short tile[64][68];
    const int z = blockIdx.z;
    const unsigned short* s;
    unsigned short* d;
    int R, C;
    if (z < 2) {
        s = wb + (long)z * (Dc * 3 * Dc);
        d = wt + (long)z * (Dc * 3 * Dc);
        R = Dc; C = 3 * Dc;
    } else {
        if (blockIdx.x >= 8) return;
        s = pwb; d = pwt; R = Dc; C = Dc;
    }
    const int r0 = blockIdx.y * 64, c0 = blockIdx.x * 64;
    const int t = threadIdx.x;
    const int lr = t >> 4, lc4 = (t & 15) * 4;
#pragma unroll
    for (int i = 0; i < 4; ++i) {
        int r = lr + i * 16;
        *(uint2*)&tile[r][lc4] = *(const uint2*)&s[(long)(r0 + r) * C + c0 + lc4];
    }
    __syncthreads();
#pragma unroll
    for (int i = 0; i < 4; ++i) {
        int r = lr + i * 16;
        unsigned short v[4];
#pragma unroll
        for (int j = 0; j < 4; ++j) v[j] = tile[lc4 + j][r];
        *(uint2*)&d[(long)(c0 + r) * R + r0 + lc4] = *(uint2*)v;
    }
}

// ---------------------------------------------------------------------------
// Round 22 (validated): FUSED S-GEMM + row softmax + A-transpose.
// ---------------------------------------------------------------------------
__global__ __launch_bounds__(256) void sgemm_softmax(
    const bf16* __restrict__ qg, const bf16* __restrict__ kg,
    float* __restrict__ Sg, bf16* __restrict__ Ag_, bf16* __restrict__ Atg)
{
    __shared__ unsigned short Bsm[256 * 72];   // 36 KB; aliased for A^T stage
    __shared__ unsigned short Asm16[16 * 72];  // 2.25 KB
    __shared__ float red[4][16];

    const int wg  = blockIdx.x;
    const int xcd = wg & 7, tt = wg >> 3;
    const int z   = xcd + 8 * (tt / 48);
    const int by  = tt % 48;
    const long MAT = (long)Nc * Nc;

    const bf16* Q  = qg + (long)z * (Nc * DKc) + (long)(by * 16) * DKc;
    const bf16* Km = kg + (long)z * (Nc * DKc);
    float* S  = Sg  + (long)z * MAT + (long)(by * 16) * Nc;
    bf16*  A  = Ag_ + (long)z * MAT + (long)(by * 16) * Nc;
    bf16*  At = Atg + (long)z * MAT;           // write At[m][by*16 + n]

    const int tid  = threadIdx.x;
    const int wv   = tid >> 6;
    const int lane = tid & 63;
    const int q    = lane >> 4;
    const int ln   = lane & 15;
    const int sr   = tid >> 3, k8 = tid & 7;

    if (tid < 128) {
        const int row = tid >> 3, kk = tid & 7;
        *(uint4*)&Asm16[row * 72 + kk * 8] = *(const uint4*)&Q[row * 64 + kk * 8];
    }

    f32x4 acc[12];
#pragma unroll
    for (int j = 0; j < 12; ++j) acc[j] = (f32x4){0.f, 0.f, 0.f, 0.f};

    for (int c = 0; c < 3; ++c) {
        __syncthreads();
#pragma unroll
        for (int i = 0; i < 8; ++i) {
            const int row = sr + i * 32;
            *(uint4*)&Bsm[row * 72 + k8 * 8] =
                *(const uint4*)&Km[(long)(c * 256 + row) * 64 + k8 * 8];
        }
        __syncthreads();
#pragma unroll
        for (int kc = 0; kc < 2; ++kc) {
            const short8 af = *(const short8*)&Asm16[ln * 72 + kc * 32 + q * 8];
#pragma unroll
            for (int t = 0; t < 4; ++t) {
                const int nl = wv * 64 + t * 16 + ln;
                const short8 bfr = *(const short8*)&Bsm[nl * 72 + kc * 32 + q * 8];
                acc[c * 4 + t] = __builtin_amdgcn_mfma_f32_16x16x32_bf16(
                    af, bfr, acc[c * 4 + t], 0, 0, 0);
            }
        }
    }

    float mrow[4] = {-1e30f, -1e30f, -1e30f, -1e30f};
#pragma unroll
    for (int j = 0; j < 12; ++j) {
        const int c = j >> 2, t = j & 3;
        const int col = c * 256 + wv * 64 + t * 16 + ln;
#pragma unroll
        for (int r = 0; r < 4; ++r) {
            const float v = acc[j][r] * SCALE;
            acc[j][r] = v;
            S[(long)(q * 4 + r) * Nc + col] = v;
            mrow[r] = fmaxf(mrow[r], v);
        }
    }
#pragma unroll
    for (int off = 8; off > 0; off >>= 1)
#pragma unroll
        for (int r = 0; r < 4; ++r)
            mrow[r] = fmaxf(mrow[r], __shfl_xor(mrow[r], off, 16));
    if (ln == 0)
#pragma unroll
        for (int r = 0; r < 4; ++r) red[wv][q * 4 + r] = mrow[r];
    __syncthreads();
    float m4[4];
#pragma unroll
    for (int r = 0; r < 4; ++r)
        m4[r] = fmaxf(fmaxf(red[0][q * 4 + r], red[1][q * 4 + r]),
                      fmaxf(red[2][q * 4 + r], red[3][q * 4 + r]));
    __syncthreads();

    float srow[4] = {0.f, 0.f, 0.f, 0.f};
#pragma unroll
    for (int j = 0; j < 12; ++j)
#pragma unroll
        for (int r = 0; r < 4; ++r) {
            const float e = __expf(acc[j][r] - m4[r]);
            acc[j][r] = e;
            srow[r] += e;
        }
#pragma unroll
    for (int off = 8; off > 0; off >>= 1)
#pragma unroll
        for (int r = 0; r < 4; ++r)
            srow[r] += __shfl_xor(srow[r], off, 16);
    if (ln == 0)
#pragma unroll
        for (int r = 0; r < 4; ++r) red[wv][q * 4 + r] = srow[r];
    __syncthreads();
    float inv[4];
#pragma unroll
    for (int r = 0; r < 4; ++r)
        inv[r] = 1.f / fmaxf(red[0][q * 4 + r] + red[1][q * 4 + r] +
                             red[2][q * 4 + r] + red[3][q * 4 + r], 1e-30f);

    unsigned short* ATl = Bsm;   // 768*20*2 = 30.7 KB <= 36 KB
#pragma unroll
    for (int j = 0; j < 12; ++j) {
        const int c = j >> 2, t = j & 3;
        const int col = c * 256 + wv * 64 + t * 16 + ln;
#pragma unroll
        for (int r = 0; r < 4; ++r) {
            const bf16 b = __float2bfloat16(acc[j][r] * inv[r]);
            const unsigned short u = *(const unsigned short*)&b;
            A[(long)(q * 4 + r) * Nc + col] = *(const bf16*)&u;
            ATl[col * 20 + q * 4 + r] = u;
        }
    }
    __syncthreads();
#pragma unroll
    for (int s = 0; s < 3; ++s) {
        const int m = tid + s * 256;
        uint2 v0 = *(const uint2*)&ATl[m * 20 + 0];
        uint2 v1 = *(const uint2*)&ATl[m * 20 + 4];
        uint2 v2 = *(const uint2*)&ATl[m * 20 + 8];
        uint2 v3 = *(const uint2*)&ATl[m * 20 + 12];
        unsigned short* d = (unsigned short*)&At[(long)m * Nc + by * 16];
        *(uint2*)&d[0]  = v0;
        *(uint2*)&d[4]  = v1;
        *(uint2*)&d[8]  = v2;
        *(uint2*)&d[12] = v3;
    }
}

// ---------------------------------------------------------------------------
// MFMA bf16 NT GEMM — 2-phase double-buffered K-loop (validated r7).
// ---------------------------------------------------------------------------
template <int EPI, typename TC, int XORB = 0, int XCDSWZ = 0, int RAW = 0>
__global__ __launch_bounds__(256) void gemm_nt_mfma(
    const bf16* __restrict__ Ag, const bf16* __restrict__ Btg,
    TC* __restrict__ Cg, bf16* __restrict__ Craw, int M, int N, int K,
    long sA, long sB, long sC, float alpha)
{
    __shared__ unsigned short Asm[2 * 128 * 32];
    __shared__ unsigned short Bsm[2 * 128 * 32];
    constexpr int BUF = 128 * 32;   // elements per buffer

    int bx, by, bz;
    if (XCDSWZ) {
        const int wg = blockIdx.x;
        const int xcd = wg & 7, t = wg >> 3;
        bz = xcd + 8 * (t / 36);
        const int tile = t % 36;
        bx = tile % 6; by = tile / 6;
    } else { bx = blockIdx.x; by = blockIdx.y; bz = blockIdx.z; }

    const int tid  = threadIdx.x;
    const int wv   = tid >> 6;
    const int lane = tid & 63;
    const int q    = lane >> 4;
    const int ln   = lane & 15;
    const int wm   = wv & 1;
    const int wn   = wv >> 1;

    const int zb = XORB ? (bz ^ 16) : bz;
    const bf16* A  = Ag  + (long)bz * sA + (long)(by * 128) * K;
    const bf16* Bt = Btg + (long)zb * sB + (long)(bx * 128) * K;
    TC*         C  = Cg  + (long)bz * sC;

    const int sr = lane >> 2, sc = lane & 3;
    const int scs = sc ^ (sr & 3);          // source col-block pre-swizzle
    const bf16* gA0 = A  + (long)(wv * 32 + sr)      * K + scs * 8;
    const bf16* gA1 = A  + (long)(wv * 32 + 16 + sr) * K + scs * 8;
    const bf16* gB0 = Bt + (long)(wv * 32 + sr)      * K + scs * 8;
    const bf16* gB1 = Bt + (long)(wv * 32 + 16 + sr) * K + scs * 8;
    unsigned short* lA0 = &Asm[(wv * 32)      * 32];
    unsigned short* lA1 = &Asm[(wv * 32 + 16) * 32];
    unsigned short* lB0 = &Bsm[(wv * 32)      * 32];
    unsigned short* lB1 = &Bsm[(wv * 32 + 16) * 32];

    f32x4 acc[4][4];
#pragma unroll
    for (int i = 0; i < 4; ++i)
#pragma unroll
        for (int j = 0; j < 4; ++j)
            acc[i][j] = (f32x4){0.f, 0.f, 0.f, 0.f};

    const int qs = (q ^ (ln & 3)) * 8;      // swizzled read block

    gl_lds16(gA0, lA0);
    gl_lds16(gA1, lA1);
    gl_lds16(gB0, lB0);
    gl_lds16(gB1, lB1);
    __syncthreads();

    int cur = 0;
    for (int k0 = 0; k0 < K; k0 += 32) {
        const int nxt = cur ^ 1;
        if (k0 + 32 < K) {
            const int no = nxt * BUF;
            gl_lds16(gA0 + k0 + 32, lA0 + no);
            gl_lds16(gA1 + k0 + 32, lA1 + no);
            gl_lds16(gB0 + k0 + 32, lB0 + no);
            gl_lds16(gB1 + k0 + 32, lB1 + no);
        }

        const unsigned short* Ac = &Asm[cur * BUF];
        const unsigned short* Bc = &Bsm[cur * BUF];
        short8 af[4], bfr[4];
#pragma unroll
        for (int mt = 0; mt < 4; ++mt) {
            int m = wm * 64 + mt * 16 + ln;
            af[mt] = *(const short8*)&Ac[m * 32 + qs];
        }
#pragma unroll
        for (int nt = 0; nt < 4; ++nt) {
            int n = wn * 64 + nt * 16 + ln;
            bfr[nt] = *(const short8*)&Bc[n * 32 + qs];
        }
#pragma unroll
        for (int mt = 0; mt < 4; ++mt)
#pragma unroll
            for (int nt = 0; nt < 4; ++nt)
                acc[mt][nt] = __builtin_amdgcn_mfma_f32_16x16x32_bf16(
                    af[mt], bfr[nt], acc[mt][nt], 0, 0, 0);

        __syncthreads();
        cur = nxt;
    }

#pragma unroll
    for (int mt = 0; mt < 4; ++mt) {
#pragma unroll
        for (int nt = 0; nt < 4; ++nt) {
            const int col = bx * 128 + wn * 64 + nt * 16 + ln;
            const int rowb = by * 128 + wm * 64 + mt * 16 + q * 4;
#pragma unroll
            for (int r = 0; r < 4; ++r) {
                float vraw = acc[mt][nt][r] * alpha;
                if (RAW) {
                    if (bz < 16)
                        Craw[(long)bz * M * N + (long)(rowb + r) * N + col] =
                            __float2bfloat16(vraw);
                }
                float v = vraw;
                if (EPI == 1) v = __logf(fmaxf(v, 0.f) + EPSF);
                stf(C, (long)(rowb + r) * N + col, v);
            }
        }
    }
}

// ---------------------------------------------------------------------------
// QKV via MFMA — round 25: 64x128 tiles (grid 12x24x2 = 576 blocks; was 288
// at ~1.1/CU — same under-occupancy disease proj had in r8/r9). LDS 24 KB
// (A 8 + B 16 dbuf) -> 6 blocks/CU residency; acc[2][4]; 3 gl_lds/wave/step.
// Same 2-phase template + r12 V-direct-transposed epilogue.
// ---------------------------------------------------------------------------
__global__ __launch_bounds__(256) void qkv_mfma64(
    const bf16* __restrict__ X,
    const bf16* __restrict__ w1t, const bf16* __restrict__ w2t,
    bf16* __restrict__ q1, bf16* __restrict__ k1, bf16* __restrict__ v1t,
    bf16* __restrict__ q2, bf16* __restrict__ k2, bf16* __restrict__ v2t)
{
    constexpr int K = Dc;  // 512
    __shared__ unsigned short Asm[2 * 64 * 32];    // 8 KB
    __shared__ unsigned short Bsm[2 * 128 * 32];   // 16 KB
    constexpr int ABUF = 64 * 32, BBUF = 128 * 32;

    const int tid  = threadIdx.x;
    const int wv   = tid >> 6;
    const int lane = tid & 63;
    const int q    = lane >> 4;
    const int ln   = lane & 15;
    const int wm   = wv & 1;
    const int wn   = wv >> 1;
    const int set  = blockIdx.z;

    const bf16* Wt = set ? w2t : w1t;
    bf16* Q  = set ? q2 : q1;
    bf16* Ko = set ? k2 : k1;
    bf16* Vt = set ? v2t : v1t;

    const bf16* A  = X  + (long)(blockIdx.y * 64) * K;
    const bf16* Bt = Wt + (long)(blockIdx.x * 128) * K;

    const int sr = lane >> 2, sc = lane & 3;
    const int scs = sc ^ (sr & 3);
    // A: each wave stages 16 rows (one gl_lds). B: 32 rows (two gl_lds).
    const bf16* gA0 = A  + (long)(wv * 16 + sr)      * K + scs * 8;
    const bf16* gB0 = Bt + (long)(wv * 32 + sr)      * K + scs * 8;
    const bf16* gB1 = Bt + (long)(wv * 32 + 16 + sr) * K + scs * 8;
    unsigned short* lA0 = &Asm[(wv * 16)      * 32];
    unsigned short* lB0 = &Bsm[(wv * 32)      * 32];
    unsigned short* lB1 = &Bsm[(wv * 32 + 16) * 32];

    f32x4 acc[2][4];
#pragma unroll
    for (int i = 0; i < 2; ++i)
#pragma unroll
        for (int j = 0; j < 4; ++j)
            acc[i][j] = (f32x4){0.f, 0.f, 0.f, 0.f};

    const int qs = (q ^ (ln & 3)) * 8;

    gl_lds16(gA0, lA0);
    gl_lds16(gB0, lB0);
    gl_lds16(gB1, lB1);
    __syncthreads();

    int cur = 0;
    for (int k0 = 0; k0 < K; k0 += 32) {
        const int nxt = cur ^ 1;
        if (k0 + 32 < K) {
            gl_lds16(gA0 + k0 + 32, lA0 + nxt * ABUF);
            gl_lds16(gB0 + k0 + 32, lB0 + nxt * BBUF);
            gl_lds16(gB1 + k0 + 32, lB1 + nxt * BBUF);
        }

        const unsigned short* Ac = &Asm[cur * ABUF];
        const unsigned short* Bc = &Bsm[cur * BBUF];
        short8 af[2], bfr[4];
#pragma unroll
        for (int mt = 0; mt < 2; ++mt) {
            int m = wm * 32 + mt * 16 + ln;
            af[mt] = *(const short8*)&Ac[m * 32 + qs];
        }
#pragma unroll
        for (int nt = 0; nt < 4; ++nt) {
            int n = wn * 64 + nt * 16 + ln;
            bfr[nt] = *(const short8*)&Bc[n * 32 + qs];
        }
#pragma unroll
        for (int mt = 0; mt < 2; ++mt)
#pragma unroll
            for (int nt = 0; nt < 4; ++nt)
                acc[mt][nt] = __builtin_amdgcn_mfma_f32_16x16x32_bf16(
                    af[mt], bfr[nt], acc[mt][nt], 0, 0, 0);

        __syncthreads();
        cur = nxt;
    }

#pragma unroll
    for (int mt = 0; mt < 2; ++mt) {
#pragma unroll
        for (int nt = 0; nt < 4; ++nt) {
            const int col  = blockIdx.x * 128 + wn * 64 + nt * 16 + ln;
            const int rowb = blockIdx.y * 64 + wm * 32 + mt * 16 + q * 4;
            const int t = col >> 9;
            const int h = (col >> 6) & 7;
            const int dk = col & 63;
            if (t == 2) {
                // V: transposed store — 4 consecutive rows -> one 8B write
                const int b = rowb >= Nc ? 1 : 0;
                const int n = rowb - b * Nc;
                unsigned short o[4];
#pragma unroll
                for (int r = 0; r < 4; ++r) {
                    const bf16 bb = __float2bfloat16(acc[mt][nt][r]);
                    o[r] = *(const unsigned short*)&bb;
                }
                unsigned short* d = (unsigned short*)Vt +
                    (((long)b * Hc + h) * DKc + dk) * Nc + n;
                *(uint2*)d = *(const uint2*)o;
            } else {
                bf16* dst = (t == 0) ? Q : Ko;
#pragma unroll
                for (int r = 0; r < 4; ++r) {
                    const int row = rowb + r;
                    const int b = row >= Nc ? 1 : 0;
                    const int n = row - b * Nc;
                    dst[(((long)b * Hc + h) * Nc + n) * DKc + dk] =
                        __float2bfloat16(acc[mt][nt][r]);
                }
            }
        }
    }
}

// ---------------------------------------------------------------------------
// MFMA bf16 NT narrow GEMM core (validated): acc = A(128,K) @ Bt(64,K)^T.
// ---------------------------------------------------------------------------
struct N64Acc { f32x4 acc[2][4]; };

template <typename DUMMY = void>
DEVINL void n64_core(const bf16* A, const bf16* Bt, int K,
                     unsigned short* Asm, unsigned short* Bsm, N64Acc& R)
{
    const int tid  = threadIdx.x;
    const int wave = tid >> 6;
    const int lane = tid & 63;
    const int q    = lane >> 4;
    const int ln   = lane & 15;

    const int sr = tid >> 3, k8 = tid & 7;
    const bf16* pa[4];
    const bf16* pb[2];
    int wa[4], wb[2];
#pragma unroll
    for (int i = 0; i < 4; ++i) {
        pa[i] = A + (long)(sr + i * 32) * K + k8 * 8;
        wa[i] = (sr + i * 32) * 72 + k8 * 8;
    }
#pragma unroll
    for (int i = 0; i < 2; ++i) {
        pb[i] = Bt + (long)(sr + i * 32) * K + k8 * 8;
        wb[i] = (sr + i * 32) * 72 + k8 * 8;
    }

#pragma unroll
    for (int i = 0; i < 2; ++i)
#pragma unroll
        for (int j = 0; j < 4; ++j)
            R.acc[i][j] = (f32x4){0.f, 0.f, 0.f, 0.f};

    for (int k0 = 0; k0 < K; k0 += 64) {
        uint4 va[4], vb[2];
#pragma unroll
        for (int i = 0; i < 4; ++i) va[i] = *(const uint4*)(pa[i] + k0);
#pragma unroll
        for (int i = 0; i < 2; ++i) vb[i] = *(const uint4*)(pb[i] + k0);
        __syncthreads();
#pragma unroll
        for (int i = 0; i < 4; ++i) *(uint4*)&Asm[wa[i]] = va[i];
#pragma unroll
        for (int i = 0; i < 2; ++i) *(uint4*)&Bsm[wb[i]] = vb[i];
        __syncthreads();

#pragma unroll
        for (int kc = 0; kc < 2; ++kc) {
            short8 af[2], bfr[4];
#pragma unroll
            for (int mt = 0; mt < 2; ++mt) {
                int m = wave * 32 + mt * 16 + ln;
                af[mt] = *(const short8*)&Asm[m * 72 + kc * 32 + q * 8];
            }
#pragma unroll
            for (int nt = 0; nt < 4; ++nt) {
                int n = nt * 16 + ln;
                bfr[nt] = *(const short8*)&Bsm[n * 72 + kc * 32 + q * 8];
            }
#pragma unroll
            for (int mt = 0; mt < 2; ++mt)
#pragma unroll
                for (int nt = 0; nt < 4; ++nt)
                    R.acc[mt][nt] = __builtin_amdgcn_mfma_f32_16x16x32_bf16(
                        af[mt], bfr[nt], R.acc[mt][nt], 0, 0, 0);
        }
    }
}

// ---------------------------------------------------------------------------
// HALF-HEIGHT n64 core — acc = A(64,K) @ Bt(64,K)^T (validated r9).
// ---------------------------------------------------------------------------
struct N64hAcc { f32x4 acc[4]; };

template <typename DUMMY = void>
DEVINL void n64h_core(const bf16* A, const bf16* Bt, int K,
                      unsigned short* Asm, unsigned short* Bsm, N64hAcc& R)
{
    const int tid  = threadIdx.x;
    const int wave = tid >> 6;
    const int lane = tid & 63;
    const int q    = lane >> 4;
    const int ln   = lane & 15;

    const int sr = tid >> 3, k8 = tid & 7;   // sr 0..31, k8 0..7
    const bf16* pa[2];
    const bf16* pb[2];
    int wa[2], wb[2];
#pragma unroll
    for (int i = 0; i < 2; ++i) {
        pa[i] = A  + (long)(sr + i * 32) * K + k8 * 8;
        wa[i] = (sr + i * 32) * 72 + k8 * 8;
        pb[i] = Bt + (long)(sr + i * 32) * K + k8 * 8;
        wb[i] = wa[i];
    }

#pragma unroll
    for (int j = 0; j < 4; ++j)
        R.acc[j] = (f32x4){0.f, 0.f, 0.f, 0.f};

    for (int k0 = 0; k0 < K; k0 += 64) {
        uint4 va[2], vb[2];
#pragma unroll
        for (int i = 0; i < 2; ++i) va[i] = *(const uint4*)(pa[i] + k0);
#pragma unroll
        for (int i = 0; i < 2; ++i) vb[i] = *(const uint4*)(pb[i] + k0);
        __syncthreads();
#pragma unroll
        for (int i = 0; i < 2; ++i) *(uint4*)&Asm[wa[i]] = va[i];
#pragma unroll
        for (int i = 0; i < 2; ++i) *(uint4*)&Bsm[wb[i]] = vb[i];
        __syncthreads();

#pragma unroll
        for (int kc = 0; kc < 2; ++kc) {
            short8 af;
            af = *(const short8*)&Asm[(wave * 16 + ln) * 72 + kc * 32 + q * 8];
            short8 bfr[4];
#pragma unroll
            for (int nt = 0; nt < 4; ++nt) {
                int n = nt * 16 + ln;
                bfr[nt] = *(const short8*)&Bsm[n * 72 + kc * 32 + q * 8];
            }
#pragma unroll
            for (int nt = 0; nt < 4; ++nt)
                R.acc[nt] = __builtin_amdgcn_mfma_f32_16x16x32_bf16(
                    af, bfr[nt], R.acc[nt], 0, 0, 0);
        }
    }
}

// ---------------------------------------------------------------------------
// Merged pair launch (Path-B fallback only; validated round 11).
// ---------------------------------------------------------------------------
__global__ __launch_bounds__(256) void gemm_n64_pair(
    const bf16* __restrict__ A0g, const bf16* __restrict__ B0g, bf16* __restrict__ C0tg,
    const bf16* __restrict__ A1g, const bf16* __restrict__ B1g, bf16* __restrict__ C1g,
    int M, int K, long sA, long sB, long sC)
{
    __shared__ unsigned short Asm[128 * 72];
    __shared__ unsigned short Bsm[64 * 72];

    const int zz = blockIdx.z & 15;
    const int second = blockIdx.z >> 4;
    const bf16* A  = (second ? A1g : A0g) + (long)zz * sA + (long)(blockIdx.y * 128) * K;
    const bf16* Bt = (second ? B1g : B0g) + (long)zz * sB;

    N64Acc R;
    n64_core(A, Bt, K, Asm, Bsm, R);

    const int tid = threadIdx.x;
    const int wave = tid >> 6, lane = tid & 63, q = lane >> 4, ln = lane & 15;

    if (second) {
        bf16* C = C1g + (long)zz * sC;
#pragma unroll
        for (int mt = 0; mt < 2; ++mt) {
#pragma unroll
            for (int nt = 0; nt < 4; ++nt) {
                const int col  = nt * 16 + ln;
                const int rowb = blockIdx.y * 128 + wave * 32 + mt * 16 + q * 4;
#pragma unroll
                for (int r = 0; r < 4; ++r)
                    C[(long)(rowb + r) * 64 + col] = __float2bfloat16(R.acc[mt][nt][r]);
            }
        }
    } else {
        __syncthreads();
#pragma unroll
        for (int mt = 0; mt < 2; ++mt) {
#pragma unroll
            for (int nt = 0; nt < 4; ++nt) {
                const int col = nt * 16 + ln;
                const int rwb = wave * 32 + mt * 16 + q * 4;
#pragma unroll
                for (int r = 0; r < 4; ++r)
                    *(bf16*)&Asm[col * 136 + rwb + r] = __float2bfloat16(R.acc[mt][nt][r]);
            }
        }
        __syncthreads();
        bf16* Ct = C0tg + (long)zz * sC;
        const int dk  = tid >> 2;
        const int nc0 = (tid & 3) * 32;
        const int gn0 = blockIdx.y * 128;
#pragma unroll
        for (int c8 = 0; c8 < 4; ++c8) {
            uint4 v = *(const uint4*)&Asm[dk * 136 + nc0 + c8 * 8];
            *(uint4*)&Ct[(long)dk * Nc + gn0 + nc0 + c8 * 8] = v;
        }
    }
}

// ---------------------------------------------------------------------------
// Merged y kernel, half-height tiles (Path A; validated r9). 192 blocks.
// ---------------------------------------------------------------------------
__global__ __launch_bounds__(256) void gemm_n64_both_h(
    const bf16* __restrict__ Ab, const bf16* __restrict__ v1t,
    const bf16* __restrict__ Craw, const bf16* __restrict__ v2t,
    const float* __restrict__ smallf, bf16* __restrict__ yc,
    int K, long sA, long sB)
{
    __shared__ unsigned short Asm[64 * 72];
    __shared__ unsigned short Bsm[64 * 72];

    const int bh = blockIdx.z;
    const long arow = (long)(blockIdx.y * 64) * K;

    N64hAcc R1;
    n64h_core(Ab + (long)bh * sA + arow, v1t + (long)bh * sB, K, Asm, Bsm, R1);
    N64hAcc R2;
    n64h_core(Craw + (long)bh * sA + arow, v2t + (long)bh * sB, K, Asm, Bsm, R2);

    const float w = sigf(smallf[392]);
    const int b = bh >> 3, h = bh & 7;

    const int tid = threadIdx.x;
    const int wave = tid >> 6, lane = tid & 63, q = lane >> 4, ln = lane & 15;
#pragma unroll
    for (int nt = 0; nt < 4; ++nt) {
        const int col  = nt * 16 + ln;
        const int rowb = blockIdx.y * 64 + wave * 16 + q * 4;
#pragma unroll
        for (int r = 0; r < 4; ++r) {
            const int n = rowb + r;
            yc[((long)(b * Nc + n)) * Dc + h * DKc + col] =
                __float2bfloat16(R1.acc[nt][r] + w * R2.acc[nt][r]);
        }
    }
}

// y_chain GEMM with fused combine + permute (Path-B fallback only).
__global__ __launch_bounds__(256) void gemm_n64_combine(
    const bf16* __restrict__ A1b, const bf16* __restrict__ trt,
    const bf16* __restrict__ yb1, const float* __restrict__ smallf,
    bf16* __restrict__ yc, int M, int K, long sA, long sB)
{
    __shared__ unsigned short Asm[128 * 72];
    __shared__ unsigned short Bsm[64 * 72];

    const int bh = blockIdx.z;
    const bf16* A  = A1b + (long)bh * sA + (long)(blockIdx.y * 128) * K;
    const bf16* Bt = trt + (long)bh * sB;

    N64Acc R;
    n64_core(A, Bt, K, Asm, Bsm, R);

    const float w = sigf(smallf[392]);
    const int b = bh >> 3, h = bh & 7;
    const long yb1base = (long)bh * Nc * DKc;

    const int tid = threadIdx.x;
    const int wave = tid >> 6, lane = tid & 63, q = lane >> 4, ln = lane & 15;
#pragma unroll
    for (int mt = 0; mt < 2; ++mt) {
#pragma unroll
        for (int nt = 0; nt < 4; ++nt) {
            const int col  = nt * 16 + ln;
            const int rowb = blockIdx.y * 128 + wave * 32 + mt * 16 + q * 4;
#pragma unroll
            for (int r = 0; r < 4; ++r) {
                const int n = rowb + r;
                const float base = __bfloat162float(yb1[yb1base + (long)n * 64 + col]);
                yc[((long)(b * Nc + n)) * Dc + h * DKc + col] =
                    __float2bfloat16(base + w * R.acc[mt][nt][r]);
            }
        }
    }
}

// Path-B y_base GEMM (fallback only).
__global__ __launch_bounds__(256) void gemm_n64_yb(
    const bf16* __restrict__ Ag, const bf16* __restrict__ Btg,
    bf16* __restrict__ Cg, int M, int K, long sA, long sB, long sC)
{
    __shared__ unsigned short Asm[128 * 72];
    __shared__ unsigned short Bsm[64 * 72];

    const int zz = blockIdx.z;
    const bf16* A  = Ag + (long)zz * sA + (long)(blockIdx.y * 128) * K;
    const bf16* Bt = Btg + (long)zz * sB;

    N64Acc R;
    n64_core(A, Bt, K, Asm, Bsm, R);

    bf16* C = Cg + (long)zz * sC;
    const int tid = threadIdx.x;
    const int wave = tid >> 6, lane = tid & 63, q = lane >> 4, ln = lane & 15;
#pragma unroll
    for (int mt = 0; mt < 2; ++mt) {
#pragma unroll
        for (int nt = 0; nt < 4; ++nt) {
            const int col  = nt * 16 + ln;
            const int rowb = blockIdx.y * 128 + wave * 32 + mt * 16 + q * 4;
#pragma unroll
            for (int r = 0; r < 4; ++r)
                C[(long)(rowb + r) * 64 + col] = __float2bfloat16(R.acc[mt][nt][r]);
        }
    }
}

// ---------------------------------------------------------------------------
// Row softmax over width 768 — wave-per-row (validated round 16).
// ---------------------------------------------------------------------------
__global__ __launch_bounds__(256) void softmax_rows_w(
    const float* __restrict__ src, bf16* __restrict__ dst)
{
    const int wid  = threadIdx.x >> 6;
    const int lane = threadIdx.x & 63;
    const long row = (long)blockIdx.x * 4 + wid;
    const float* s = src + row * Nc;

    float4 v[3];
#pragma unroll
    for (int i = 0; i < 3; ++i)
        v[i] = *(const float4*)&s[i * 256 + lane * 4];

    float m = -1e30f;
#pragma unroll
    for (int i = 0; i < 3; ++i)
        m = fmaxf(m, fmaxf(fmaxf(v[i].x, v[i].y), fmaxf(v[i].z, v[i].w)));
#pragma unroll
    for (int off = 32; off > 0; off >>= 1)
        m = fmaxf(m, __shfl_xor(m, off, 64));

    float e[12];
    float sum = 0.f;
#pragma unroll
    for (int i = 0; i < 3; ++i) {
        e[i * 4 + 0] = __expf(v[i].x - m);
        e[i * 4 + 1] = __expf(v[i].y - m);
        e[i * 4 + 2] = __expf(v[i].z - m);
        e[i * 4 + 3] = __expf(v[i].w - m);
        sum += e[i * 4 + 0] + e[i * 4 + 1] + e[i * 4 + 2] + e[i * 4 + 3];
    }
#pragma unroll
    for (int off = 32; off > 0; off >>= 1)
        sum += __shfl_xor(sum, off, 64);

    const float inv = 1.f / fmaxf(sum, 1e-30f);
    unsigned short* d = (unsigned short*)dst + row * Nc;
#pragma unroll
    for (int i = 0; i < 3; ++i) {
        unsigned short o[4];
#pragma unroll
        for (int j = 0; j < 4; ++j) {
            const bf16 b = __float2bfloat16(e[i * 4 + j] * inv);
            o[j] = *(const unsigned short*)&b;
        }
        *(uint2*)&d[i * 256 + lane * 4] = *(const uint2*)o;
    }
}

// ---------------------------------------------------------------------------
// Gate network + Smix — r7-validated 2-elem body, 32x16 tiling (frozen;
// r11 lesson: this tiling is load-bearing for L2 reuse).
// ---------------------------------------------------------------------------
__global__ __launch_bounds__(256) void gates_smix(
    const float* __restrict__ S1g, const float* __restrict__ S2g,
    const bf16* __restrict__ Crg, const bf16* __restrict__ Clg,
    float* __restrict__ Smixg, const float* __restrict__ smallf)
{
    __shared__ float t1t[32][17], t2t[32][17];

    const long mat = (long)blockIdx.z * Nc * Nc;
    const float* S1 = S1g + mat;
    const float* S2 = S2g + mat;
    const unsigned short* Cr = (const unsigned short*)Crg + mat;
    const unsigned short* Cl = (const unsigned short*)Clg + mat;
    float* Smix = Smixg + mat;

    const int tid = threadIdx.x;

    const int n0 = blockIdx.y * 16, m0 = blockIdx.x * 32;
    {
        const int r = tid >> 3, c2 = (tid & 7) * 2;
        const float2 a = *(const float2*)&S1[(long)(m0 + r) * Nc + n0 + c2];
        const float2 b = *(const float2*)&S2[(long)(m0 + r) * Nc + n0 + c2];
        t1t[r][c2] = a.x; t1t[r][c2 + 1] = a.y;
        t2t[r][c2] = b.x; t2t[r][c2 + 1] = b.y;
    }
    __syncthreads();

    const int tx = tid & 15, ty = tid >> 4;
    const int n = n0 + ty;
    const long idx = (long)n * Nc + m0 + tx * 2;

    const float2 s1v = *(const float2*)&S1[idx];
    const float2 s2v = *(const float2*)&S2[idx];
    const unsigned cru = *(const unsigned*)&Cr[idx];
    const unsigned clu = *(const unsigned*)&Cl[idx];

    const f32x2 s1a = {s1v.x, s1v.y};
    const f32x2 s2a = {s2v.x, s2v.y};
    const f32x2 cra = {__uint_as_float((cru & 0xffffu) << 16),
                       __uint_as_float(cru & 0xffff0000u)};
    const f32x2 cla = {__uint_as_float((clu & 0xffffu) << 16),
                       __uint_as_float(clu & 0xffff0000u)};
    const f32x2 s1t = {t1t[tx * 2][ty], t1t[tx * 2 + 1][ty]};
    const f32x2 s2t = {t2t[tx * 2][ty], t2t[tx * 2 + 1][ty]};

    f32x2 g0 = *(const f32x2*)&smallf[384];
    f32x2 g1 = *(const f32x2*)&smallf[386];
    f32x2 g2 = *(const f32x2*)&smallf[388];
    f32x2 g3 = *(const f32x2*)&smallf[390];

    const f32x2 gc1  = splat2(-2.30220902f);
    const f32x2 gc3  = splat2(-0.10294357f);
    const f32x2 one2 = splat2(1.f);

#pragma unroll
    for (int u = 0; u < 16; ++u) {
        const f32x2* cw = (const f32x2*)&smallf[u * 24];
        f32x2 h = cw[6];
        h = fma2(s1a, cw[0], h);
        h = fma2(s2a, cw[1], h);
        h = fma2(s1t, cw[2], h);
        h = fma2(s2t, cw[3], h);
        h = fma2(cra, cw[4], h);
        h = fma2(cla, cw[5], h);
        const f32x2 hh = h * h;
        const f32x2 z2 = h * fma2(hh, gc3, gc1);
        f32x2 e;  e[0]  = vexp2(z2[0]); e[1]  = vexp2(z2[1]);
        const f32x2 d = one2 + e;
        f32x2 rc; rc[0] = vrcp(d[0]);   rc[1] = vrcp(d[1]);
        const f32x2 hid = h * rc;
        g0 = fma2(hid, cw[8],  g0);
        g1 = fma2(hid, cw[9],  g1);
        g2 = fma2(hid, cw[10], g2);
        g3 = fma2(hid, cw[11], g3);
    }

    const f32x2 nl2e = splat2(-1.44269504f);
    const f32x2 ln2v = splat2(0.69314718f);
    auto sig2 = [&](f32x2 x) -> f32x2 {
        const f32x2 t = x * nl2e;
        f32x2 e;  e[0] = vexp2(t[0]); e[1] = vexp2(t[1]);
        const f32x2 d = one2 + e;
        f32x2 r;  r[0] = vrcp(d[0]);  r[1] = vrcp(d[1]);
        return r;
    };
    const f32x2 ga2 = sig2(g0);
    const f32x2 go2 = sig2(g1);
    const f32x2 gn2 = sig2(g2);
    const f32x2 gc2 = sig2(g3);

    const f32x2 dd = s1a - s2a;
    f32x2 ad; ad[0] = fabsf(dd[0]); ad[1] = fabsf(dd[1]);
    const f32x2 t2 = ad * nl2e;
    f32x2 ee; ee[0] = vexp2(t2[0]); ee[1] = vexp2(t2[1]);
    const f32x2 lp = one2 + ee;
    f32x2 lg; lg[0] = vlog2(lp[0]); lg[1] = vlog2(lp[1]);
    const f32x2 mx2 = __builtin_elementwise_max(s1a, s2a);
    const f32x2 lae = fma2(lg, ln2v, mx2);

    f32x2 o2 = s1a;
    o2 = fma2(ga2, s2a, o2);
    o2 = fma2(go2, lae - s1a, o2);
    o2 = fma2(gn2, s2a * splat2(-BETA_NOT), o2);
    o2 = fma2(gc2, cra, o2);
    *(float2*)&Smix[idx] = (float2){o2[0], o2[1]};
}

// ---------------------------------------------------------------------------
// Final projection, half-height tiles — 192 blocks (validated r9).
// ---------------------------------------------------------------------------
__global__ __launch_bounds__(256) void proj_n64h(
    const bf16* __restrict__ yc, const bf16* __restrict__ pwt,
    const void* __restrict__ xraw, void* __restrict__ out)
{
    constexpr int K = Dc;  // 512
    constexpr int N = Dc;  // 512
    __shared__ unsigned short Asm[64 * 72];
    __shared__ unsigned short Bsm[64 * 72];
    __shared__ int is32s;
    if (threadIdx.x == 0) is32s = sniff_is_fp32(xraw);

    const bf16* A  = yc  + (long)(blockIdx.y * 64) * K;
    const bf16* Bt = pwt + (long)(blockIdx.x * 64) * K;

    N64hAcc R;
    n64h_core(A, Bt, K, Asm, Bsm, R);   // internal barriers publish is32s

    const int is32 = is32s;
    const int tid = threadIdx.x;
    const int wave = tid >> 6, lane = tid & 63, q = lane >> 4, ln = lane & 15;
#pragma unroll
    for (int nt = 0; nt < 4; ++nt) {
        const int col  = blockIdx.x * 64 + nt * 16 + ln;
        const int rowb = blockIdx.y * 64 + wave * 16 + q * 4;
#pragma unroll
        for (int r = 0; r < 4; ++r) {
            const long o = (long)(rowb + r) * N + col;
            if (is32) ((float*)out)[o] = R.acc[nt][r];
            else      ((bf16*)out)[o] = __float2bfloat16(R.acc[nt][r]);
        }
    }
}

// ---------------------------------------------------------------------------
extern "C" void kernel_launch(void* const* d_in, const int* in_sizes, int n_in,
                              void* d_out, int out_size, void* d_ws, size_t ws_size,
                              hipStream_t stream)
{
    const size_t HD   = (size_t)BHc * Nc * DKc;   // 786432
    const size_t HDh  = HD / 2;                   // float-slots for HD bf16
    const size_t MAT  = (size_t)Nc * Nc;          // 589824
    const size_t MATS = (size_t)BHc * MAT;        // 9437184
    const long   HSTR = (long)Nc * DKc;           // 49152 per-head stride

    float* ws = (float*)d_ws;
    size_t off = 0;
    auto alloc = [&](size_t n) { float* p = ws + off; off += n; return p; };

    bf16* xb  = (bf16*)alloc(HDh);
    bf16* w1b = (bf16*)alloc(HDh);   // w1b/w2b adjacent -> merged transpose
    bf16* w2b = (bf16*)alloc(HDh);
    bf16* w1t = (bf16*)alloc(HDh);
    bf16* w2t = (bf16*)alloc(HDh);
    bf16* pwb = (bf16*)alloc((size_t)Dc * Dc / 2);
    bf16* pwt = (bf16*)alloc((size_t)Dc * Dc / 2);
    float* smallf = alloc(512);
    // q1|q2 and k1|k2 adjacent -> single merged fused-S launch (32 batches)
    bf16* q1b = (bf16*)alloc(HDh); bf16* q2b = (bf16*)alloc(HDh);
    bf16* k1b = (bf16*)alloc(HDh); bf16* k2b = (bf16*)alloc(HDh);
    bf16* v1b = (bf16*)alloc(HDh); bf16* v2b = (bf16*)alloc(HDh);  // (unused)
    bf16* v1t = (bf16*)alloc(HDh); bf16* v2t = (bf16*)alloc(HDh);  // adjacent
    bf16* trt = (bf16*)alloc(HDh);
    float* S1   = alloc(MATS);       // S1/S2 adjacent
    float* S2   = alloc(MATS);
    float* Smix = alloc(MATS);       // region reused: A1tb|A2tb, then Smix
    bf16* A1b = (bf16*)alloc(MATS / 2);  // A1b/A2b adjacent
    bf16* A2b = (bf16*)alloc(MATS / 2);
    bf16* Crb = (bf16*)alloc(MATS / 2);  // Crb/Clb adjacent (merged launch)
    bf16* Clb = (bf16*)alloc(MATS / 2);
    bf16* yb1 = (bf16*)alloc(HDh);
    bf16* yc  = (bf16*)alloc(HDh);

    const size_t NEED_BASE = off * sizeof(float);
    bf16* Crawb = (bf16*)alloc(MATS / 2);          // raw C_right (Path A only)
    const size_t NEED_A = off * sizeof(float);
    const int pathA = ws_size >= NEED_A;

    // aliases into dead regions
    bf16* A1tb = (bf16*)Smix;            // live steps 3-4 (dead once gates writes Smix)
    bf16* A2tb = ((bf16*)Smix) + MATS;
    bf16* Ab   = (bf16*)S1;              // S1 dead after gates

    if (ws_size < NEED_BASE) {
        fill_sentinel<<<dim3(3072), 256, 0, stream>>>((unsigned short*)d_out);
        return;
    }

    // 0. normalize inputs
    convert_all<<<dim3(3072), 256, 0, stream>>>(
        d_in[0], d_in[1], d_in[2], d_in[3], d_in[4], d_in[5], d_in[6], d_in[7],
        d_in[8], xb, w1b, w2b, pwb, smallf);

    // 1. merged W + pw transpose; QKV 64x128 tiles (576 blocks; V transposed)
    transpose_wpw<<<dim3(24, 8, 3), 256, 0, stream>>>(
        (const unsigned short*)w1b, (unsigned short*)w1t,
        (const unsigned short*)pwb, (unsigned short*)pwt);
    qkv_mfma64<<<dim3(12, 24, 2), 256, 0, stream>>>(
        xb, w1t, w2t, q1b, k1b, v1t, q2b, k2b, v2t);

    // 2+3. FUSED: S = scale*q@k^T, row softmax -> A, A^T (validated r10)
    sgemm_softmax<<<dim3(1536), 256, 0, stream>>>(
        q1b, k1b, S1, A1b, A1tb);

    // 4. Cr|Cl in ONE 32-batch launch; XCD-pinned 1-D grid; 2-phase K-loop;
    //    Path A also stores raw C_right.
    if (pathA)
        gemm_nt_mfma<1, bf16, 1, 1, 1><<<dim3(1152), 256, 0, stream>>>(
            A1b, A1tb, Crb, Crawb, Nc, Nc, Nc, (long)MAT, (long)MAT, (long)MAT, 1.f);
    else
        gemm_nt_mfma<1, bf16, 1, 1, 0><<<dim3(1152), 256, 0, stream>>>(
            A1b, A1tb, Crb, nullptr, Nc, Nc, Nc, (long)MAT, (long)MAT, (long)MAT, 1.f);

    // 5. gates + Smix (r7-validated 2-elem body, 32x16 tiling)
    gates_smix<<<dim3(24, 48, BHc), 256, 0, stream>>>(S1, S2, Crb, Clb, Smix, smallf);

    // 6. A = softmax(Smix) -> bf16 (into S1 alias, wave-per-row)
    softmax_rows_w<<<(BHc * Nc) / 4, 256, 0, stream>>>(Smix, Ab);

    if (pathA) {
        // 7. merged y, half-height tiles: 192 blocks
        gemm_n64_both_h<<<dim3(1, 12, BHc), 256, 0, stream>>>(
            Ab, v1t, Crawb, v2t, smallf, yc, Nc, (long)MAT, HSTR);
    } else {
        // Path B fallback (v1t/v2t already transposed)
        gemm_n64_pair<<<dim3(1, 6, 2 * BHc), 256, 0, stream>>>(
            A2b, v2t, trt, Ab, v1t, yb1, Nc, Nc, (long)MAT, HSTR, HSTR);
        gemm_n64_combine<<<dim3(1, 6, BHc), 256, 0, stream>>>(
            A1b, trt, yb1, smallf, yc, Nc, Nc, (long)MAT, HSTR);
    }

    // 9. proj, half-height tiles: 192 blocks
    proj_n64h<<<dim3(8, 24, 1), 256, 0, stream>>>(yc, pwt, d_in[0], d_out);
}

// Round 14
// 325.522 us; speedup vs baseline: 1.0219x; 1.0022x over previous
//
#include <hip/hip_runtime.h>
#include <hip/hip_bf16.h>
#include <math.h>

typedef __hip_bfloat16 bf16;
typedef __attribute__((ext_vector_type(8))) short short8;   // 8 bf16 (4 VGPRs)
typedef __attribute__((ext_vector_type(4))) float f32x4;
typedef __attribute__((ext_vector_type(2))) float f32x2;
#define DEVINL __device__ __forceinline__

constexpr int Bc  = 2;
constexpr int Nc  = 768;
constexpr int Dc  = 512;
constexpr int Hc  = 8;
constexpr int DKc = 64;
constexpr int BHc = Bc * Hc;
constexpr float SCALE    = 0.125f;   // 1/sqrt(64)
constexpr float EPSF     = 1e-6f;
constexpr float BETA_NOT = 0.5f;

DEVINL float ldf(const float* p, long i) { return p[i]; }
DEVINL float ldf(const bf16* p, long i) { return __bfloat162float(p[i]); }
DEVINL void stf(float* p, long i, float v) { p[i] = v; }
DEVINL void stf(bf16* p, long i, float v) { p[i] = __float2bfloat16(v); }

DEVINL float sigf(float x) { return __fdividef(1.f, 1.f + __expf(-x)); }

// packed fp32 pair helpers — backend selects v_pk_fma_f32/v_pk_mul_f32 (r3:
// validated -41% on gates_smix; r4 pair-dup operands -12%; r5 s_load weights).
DEVINL f32x2 fma2(f32x2 a, f32x2 b, f32x2 c) { return __builtin_elementwise_fma(a, b, c); }
DEVINL f32x2 splat2(float x) { return (f32x2){x, x}; }
// guard-free transcendentals (libm exp2f adds a denormal guard: +13% in r2)
DEVINL float vexp2(float x) { float r; asm("v_exp_f32 %0, %1" : "=v"(r) : "v"(x)); return r; }
DEVINL float vrcp(float x)  { float r; asm("v_rcp_f32 %0, %1" : "=v"(r) : "v"(x)); return r; }
DEVINL float vlog2(float x) { float r; asm("v_log_f32 %0, %1" : "=v"(r) : "v"(x)); return r; }

// async global->LDS, 16B per lane; LDS dest = wave-uniform base + lane*16.
DEVINL void gl_lds16(const void* g, void* l) {
    __builtin_amdgcn_global_load_lds(
        (const __attribute__((address_space(1))) void*)g,
        (__attribute__((address_space(3))) void*)l, 16, 0, 0);
}

// ---------------------------------------------------------------------------
// Dtype sniffer — vectorized (validated round 9).
// ---------------------------------------------------------------------------
DEVINL int sniff_is_fp32(const void* xraw) {
    const uint4* p4 = (const uint4*)xraw;
    float mx = 0.f;
#pragma unroll
    for (int j = 0; j < 16; ++j) {
        const uint4 u = p4[j];
        const unsigned w[4] = {u.x, u.y, u.z, u.w};
#pragma unroll
        for (int t = 0; t < 4; ++t) {
            mx = fmaxf(mx, fabsf(__uint_as_float((w[t] & 0xffffu) << 16)));
            mx = fmaxf(mx, fabsf(__uint_as_float(w[t] & 0xffff0000u)));
        }
    }
    return mx > 1000.f ? 1 : 0;
}

DEVINL float cvt_elem(const void* s, long j, int is32) {
    return is32 ? ((const float*)s)[j]
                : __bfloat162float(((const bf16*)s)[j]);
}

// ---------------------------------------------------------------------------
// Round 26: FUSED convert + W/pw TRANSPOSE — kills the w1b/w2b/pwb bf16
// round-trip (6.3 MB write + 6.3 MB read) and one launch.
// Block roles (grid 833):
//   t <  192 : W1 64x64 tile -> convert -> transposed write to w1t
//   t <  384 : W2 tile -> w2t
//   t <  448 : pw tile -> pwt
//   t <  832 : xb convert, 2048 elems/block, 8/thread vectorized
//   t == 832 : smallf build (round-15 pair-duplicated layout:
//     [u*24+2k+{0,1}]=w1c[u][k] k=0..5; [u*24+12..13]=b1[u]; pad;
//     [u*24+16+2o+{0,1}]=conv2_w[o][u]; [384..391]=c2b pairs; [392]=chain)
// ---------------------------------------------------------------------------
__global__ __launch_bounds__(256) void convert_tr(
    const void* x, const void* w1, const void* w2, const void* pw,
    const void* c1w, const void* c1b, const void* c2w, const void* c2b,
    const void* ch,
    bf16* xb, bf16* w1t, bf16* w2t, bf16* pwt, float* smallf)
{
    __shared__ unsigned short tile[64][68];
    __shared__ int is32s;
    if (threadIdx.x == 0) is32s = sniff_is_fp32(x);
    __syncthreads();
    const int is32 = is32s;
    const int t = blockIdx.x;
    const int tid = threadIdx.x;

    if (t < 448) {
        const void* src; bf16* dst; int R, C, bx, by;
        if (t < 192)      { src = w1; dst = w1t; R = Dc; C = 3 * Dc;
                            bx = t % 24;         by = t / 24; }
        else if (t < 384) { src = w2; dst = w2t; R = Dc; C = 3 * Dc;
                            bx = (t - 192) % 24; by = (t - 192) / 24; }
        else              { src = pw; dst = pwt; R = Dc; C = Dc;
                            bx = (t - 384) % 8;  by = (t - 384) / 8; }
        const int r0 = by * 64, c0 = bx * 64;
        const int lr = tid >> 4, lc4 = (tid & 15) * 4;
#pragma unroll
        for (int i = 0; i < 4; ++i) {
            const int r = lr + i * 16;
            const long base = (long)(r0 + r) * C + c0 + lc4;
            unsigned short v[4];
            if (is32) {
                const float4 f = *(const float4*)&((const float*)src)[base];
                const bf16 b0 = __float2bfloat16(f.x);
                const bf16 b1 = __float2bfloat16(f.y);
                const bf16 b2 = __float2bfloat16(f.z);
                const bf16 b3 = __float2bfloat16(f.w);
                v[0] = *(const unsigned short*)&b0;
                v[1] = *(const unsigned short*)&b1;
                v[2] = *(const unsigned short*)&b2;
                v[3] = *(const unsigned short*)&b3;
            } else {
                *(uint2*)v = *(const uint2*)&((const unsigned short*)src)[base];
            }
            *(uint2*)&tile[r][lc4] = *(const uint2*)v;
        }
        __syncthreads();
#pragma unroll
        for (int i = 0; i < 4; ++i) {
            const int r = lr + i * 16;
            unsigned short v[4];
#pragma unroll
            for (int j = 0; j < 4; ++j) v[j] = tile[lc4 + j][r];
            *(uint2*)&((unsigned short*)dst)[(long)(c0 + r) * R + r0 + lc4] =
                *(const uint2*)v;
        }
    } else if (t < 832) {
        const long i0 = (long)(t - 448) * 2048 + tid * 8;
        if (is32) {
            const float4 a = *(const float4*)&((const float*)x)[i0];
            const float4 b = *(const float4*)&((const float*)x)[i0 + 4];
            const float f[8] = {a.x, a.y, a.z, a.w, b.x, b.y, b.z, b.w};
            unsigned short o[8];
#pragma unroll
            for (int j = 0; j < 8; ++j) {
                const bf16 bb = __float2bfloat16(f[j]);
                o[j] = *(const unsigned short*)&bb;
            }
            *(uint4*)&((unsigned short*)xb)[i0] = *(const uint4*)o;
        } else {
            *(uint4*)&((unsigned short*)xb)[i0] =
                *(const uint4*)&((const unsigned short*)x)[i0];
        }
    } else {
#pragma unroll
        for (int base = 0; base < 512; base += 256) {
            const int i = base + tid;
            if (i < 384) {
                const int u = i / 24, k = i % 24;
                float v = 0.f;
                if (k < 12)      v = cvt_elem(c1w, u * 6 + (k >> 1), is32);
                else if (k < 14) v = cvt_elem(c1b, u, is32);
                else if (k >= 16) { const int o = (k - 16) >> 1;
                                    v = cvt_elem(c2w, o * 16 + u, is32); }
                smallf[i] = v;
            } else if (i < 392) smallf[i] = cvt_elem(c2b, (i - 384) >> 1, is32);
            else if (i < 394) smallf[i] = cvt_elem(ch, 0, is32);
            else smallf[i] = 0.f;
        }
    }
}

__global__ __launch_bounds__(256) void fill_sentinel(unsigned short* o) {
    const long i = (long)blockIdx.x * 256 + threadIdx.x;
    if (i < (long)Bc * Nc * Dc) o[i] = 0x40E0;  // bf16 7.0
}

// ---------------------------------------------------------------------------
// Round 22 (validated): FUSED S-GEMM + row softmax + A-transpose.
// ---------------------------------------------------------------------------
__global__ __launch_bounds__(256) void sgemm_softmax(
    const bf16* __restrict__ qg, const bf16* __restrict__ kg,
    float* __restrict__ Sg, bf16* __restrict__ Ag_, bf16* __restrict__ Atg)
{
    __shared__ unsigned short Bsm[256 * 72];   // 36 KB; aliased for A^T stage
    __shared__ unsigned short Asm16[16 * 72];  // 2.25 KB
    __shared__ float red[4][16];

    const int wg  = blockIdx.x;
    const int xcd = wg & 7, tt = wg >> 3;
    const int z   = xcd + 8 * (tt / 48);
    const int by  = tt % 48;
    const long MAT = (long)Nc * Nc;

    const bf16* Q  = qg + (long)z * (Nc * DKc) + (long)(by * 16) * DKc;
    const bf16* Km = kg + (long)z * (Nc * DKc);
    float* S  = Sg  + (long)z * MAT + (long)(by * 16) * Nc;
    bf16*  A  = Ag_ + (long)z * MAT + (long)(by * 16) * Nc;
    bf16*  At = Atg + (long)z * MAT;           // write At[m][by*16 + n]

    const int tid  = threadIdx.x;
    const int wv   = tid >> 6;
    const int lane = tid & 63;
    const int q    = lane >> 4;
    const int ln   = lane & 15;
    const int sr   = tid >> 3, k8 = tid & 7;

    if (tid < 128) {
        const int row = tid >> 3, kk = tid & 7;
        *(uint4*)&Asm16[row * 72 + kk * 8] = *(const uint4*)&Q[row * 64 + kk * 8];
    }

    f32x4 acc[12];
#pragma unroll
    for (int j = 0; j < 12; ++j) acc[j] = (f32x4){0.f, 0.f, 0.f, 0.f};

    for (int c = 0; c < 3; ++c) {
        __syncthreads();
#pragma unroll
        for (int i = 0; i < 8; ++i) {
            const int row = sr + i * 32;
            *(uint4*)&Bsm[row * 72 + k8 * 8] =
                *(const uint4*)&Km[(long)(c * 256 + row) * 64 + k8 * 8];
        }
        __syncthreads();
#pragma unroll
        for (int kc = 0; kc < 2; ++kc) {
            const short8 af = *(const short8*)&Asm16[ln * 72 + kc * 32 + q * 8];
#pragma unroll
            for (int t = 0; t < 4; ++t) {
                const int nl = wv * 64 + t * 16 + ln;
                const short8 bfr = *(const short8*)&Bsm[nl * 72 + kc * 32 + q * 8];
                acc[c * 4 + t] = __builtin_amdgcn_mfma_f32_16x16x32_bf16(
                    af, bfr, acc[c * 4 + t], 0, 0, 0);
            }
        }
    }

    float mrow[4] = {-1e30f, -1e30f, -1e30f, -1e30f};
#pragma unroll
    for (int j = 0; j < 12; ++j) {
        const int c = j >> 2, t = j & 3;
        const int col = c * 256 + wv * 64 + t * 16 + ln;
#pragma unroll
        for (int r = 0; r < 4; ++r) {
            const float v = acc[j][r] * SCALE;
            acc[j][r] = v;
            S[(long)(q * 4 + r) * Nc + col] = v;
            mrow[r] = fmaxf(mrow[r], v);
        }
    }
#pragma unroll
    for (int off = 8; off > 0; off >>= 1)
#pragma unroll
        for (int r = 0; r < 4; ++r)
            mrow[r] = fmaxf(mrow[r], __shfl_xor(mrow[r], off, 16));
    if (ln == 0)
#pragma unroll
        for (int r = 0; r < 4; ++r) red[wv][q * 4 + r] = mrow[r];
    __syncthreads();
    float m4[4];
#pragma unroll
    for (int r = 0; r < 4; ++r)
        m4[r] = fmaxf(fmaxf(red[0][q * 4 + r], red[1][q * 4 + r]),
                      fmaxf(red[2][q * 4 + r], red[3][q * 4 + r]));
    __syncthreads();

    float srow[4] = {0.f, 0.f, 0.f, 0.f};
#pragma unroll
    for (int j = 0; j < 12; ++j)
#pragma unroll
        for (int r = 0; r < 4; ++r) {
            const float e = __expf(acc[j][r] - m4[r]);
            acc[j][r] = e;
            srow[r] += e;
        }
#pragma unroll
    for (int off = 8; off > 0; off >>= 1)
#pragma unroll
        for (int r = 0; r < 4; ++r)
            srow[r] += __shfl_xor(srow[r], off, 16);
    if (ln == 0)
#pragma unroll
        for (int r = 0; r < 4; ++r) red[wv][q * 4 + r] = srow[r];
    __syncthreads();
    float inv[4];
#pragma unroll
    for (int r = 0; r < 4; ++r)
        inv[r] = 1.f / fmaxf(red[0][q * 4 + r] + red[1][q * 4 + r] +
                             red[2][q * 4 + r] + red[3][q * 4 + r], 1e-30f);

    unsigned short* ATl = Bsm;   // 768*20*2 = 30.7 KB <= 36 KB
#pragma unroll
    for (int j = 0; j < 12; ++j) {
        const int c = j >> 2, t = j & 3;
        const int col = c * 256 + wv * 64 + t * 16 + ln;
#pragma unroll
        for (int r = 0; r < 4; ++r) {
            const bf16 b = __float2bfloat16(acc[j][r] * inv[r]);
            const unsigned short u = *(const unsigned short*)&b;
            A[(long)(q * 4 + r) * Nc + col] = *(const bf16*)&u;
            ATl[col * 20 + q * 4 + r] = u;
        }
    }
    __syncthreads();
#pragma unroll
    for (int s = 0; s < 3; ++s) {
        const int m = tid + s * 256;
        uint2 v0 = *(const uint2*)&ATl[m * 20 + 0];
        uint2 v1 = *(const uint2*)&ATl[m * 20 + 4];
        uint2 v2 = *(const uint2*)&ATl[m * 20 + 8];
        uint2 v3 = *(const uint2*)&ATl[m * 20 + 12];
        unsigned short* d = (unsigned short*)&At[(long)m * Nc + by * 16];
        *(uint2*)&d[0]  = v0;
        *(uint2*)&d[4]  = v1;
        *(uint2*)&d[8]  = v2;
        *(uint2*)&d[12] = v3;
    }
}

// ---------------------------------------------------------------------------
// MFMA bf16 NT GEMM — 2-phase double-buffered K-loop (validated r7).
// ---------------------------------------------------------------------------
template <int EPI, typename TC, int XORB = 0, int XCDSWZ = 0, int RAW = 0>
__global__ __launch_bounds__(256) void gemm_nt_mfma(
    const bf16* __restrict__ Ag, const bf16* __restrict__ Btg,
    TC* __restrict__ Cg, bf16* __restrict__ Craw, int M, int N, int K,
    long sA, long sB, long sC, float alpha)
{
    __shared__ unsigned short Asm[2 * 128 * 32];
    __shared__ unsigned short Bsm[2 * 128 * 32];
    constexpr int BUF = 128 * 32;   // elements per buffer

    int bx, by, bz;
    if (XCDSWZ) {
        const int wg = blockIdx.x;
        const int xcd = wg & 7, t = wg >> 3;
        bz = xcd + 8 * (t / 36);
        const int tile = t % 36;
        bx = tile % 6; by = tile / 6;
    } else { bx = blockIdx.x; by = blockIdx.y; bz = blockIdx.z; }

    const int tid  = threadIdx.x;
    const int wv   = tid >> 6;
    const int lane = tid & 63;
    const int q    = lane >> 4;
    const int ln   = lane & 15;
    const int wm   = wv & 1;
    const int wn   = wv >> 1;

    const int zb = XORB ? (bz ^ 16) : bz;
    const bf16* A  = Ag  + (long)bz * sA + (long)(by * 128) * K;
    const bf16* Bt = Btg + (long)zb * sB + (long)(bx * 128) * K;
    TC*         C  = Cg  + (long)bz * sC;

    const int sr = lane >> 2, sc = lane & 3;
    const int scs = sc ^ (sr & 3);          // source col-block pre-swizzle
    const bf16* gA0 = A  + (long)(wv * 32 + sr)      * K + scs * 8;
    const bf16* gA1 = A  + (long)(wv * 32 + 16 + sr) * K + scs * 8;
    const bf16* gB0 = Bt + (long)(wv * 32 + sr)      * K + scs * 8;
    const bf16* gB1 = Bt + (long)(wv * 32 + 16 + sr) * K + scs * 8;
    unsigned short* lA0 = &Asm[(wv * 32)      * 32];
    unsigned short* lA1 = &Asm[(wv * 32 + 16) * 32];
    unsigned short* lB0 = &Bsm[(wv * 32)      * 32];
    unsigned short* lB1 = &Bsm[(wv * 32 + 16) * 32];

    f32x4 acc[4][4];
#pragma unroll
    for (int i = 0; i < 4; ++i)
#pragma unroll
        for (int j = 0; j < 4; ++j)
            acc[i][j] = (f32x4){0.f, 0.f, 0.f, 0.f};

    const int qs = (q ^ (ln & 3)) * 8;      // swizzled read block

    gl_lds16(gA0, lA0);
    gl_lds16(gA1, lA1);
    gl_lds16(gB0, lB0);
    gl_lds16(gB1, lB1);
    __syncthreads();

    int cur = 0;
    for (int k0 = 0; k0 < K; k0 += 32) {
        const int nxt = cur ^ 1;
        if (k0 + 32 < K) {
            const int no = nxt * BUF;
            gl_lds16(gA0 + k0 + 32, lA0 + no);
            gl_lds16(gA1 + k0 + 32, lA1 + no);
            gl_lds16(gB0 + k0 + 32, lB0 + no);
            gl_lds16(gB1 + k0 + 32, lB1 + no);
        }

        const unsigned short* Ac = &Asm[cur * BUF];
        const unsigned short* Bc = &Bsm[cur * BUF];
        short8 af[4], bfr[4];
#pragma unroll
        for (int mt = 0; mt < 4; ++mt) {
            int m = wm * 64 + mt * 16 + ln;
            af[mt] = *(const short8*)&Ac[m * 32 + qs];
        }
#pragma unroll
        for (int nt = 0; nt < 4; ++nt) {
            int n = wn * 64 + nt * 16 + ln;
            bfr[nt] = *(const short8*)&Bc[n * 32 + qs];
        }
#pragma unroll
        for (int mt = 0; mt < 4; ++mt)
#pragma unroll
            for (int nt = 0; nt < 4; ++nt)
                acc[mt][nt] = __builtin_amdgcn_mfma_f32_16x16x32_bf16(
                    af[mt], bfr[nt], acc[mt][nt], 0, 0, 0);

        __syncthreads();
        cur = nxt;
    }

#pragma unroll
    for (int mt = 0; mt < 4; ++mt) {
#pragma unroll
        for (int nt = 0; nt < 4; ++nt) {
            const int col = bx * 128 + wn * 64 + nt * 16 + ln;
            const int rowb = by * 128 + wm * 64 + mt * 16 + q * 4;
#pragma unroll
            for (int r = 0; r < 4; ++r) {
                float vraw = acc[mt][nt][r] * alpha;
                if (RAW) {
                    if (bz < 16)
                        Craw[(long)bz * M * N + (long)(rowb + r) * N + col] =
                            __float2bfloat16(vraw);
                }
                float v = vraw;
                if (EPI == 1) v = __logf(fmaxf(v, 0.f) + EPSF);
                stf(C, (long)(rowb + r) * N + col, v);
            }
        }
    }
}

// ---------------------------------------------------------------------------
// QKV via MFMA — 64x128 tiles (validated r13: 576 blocks, 24 KB LDS,
// 2-phase K-loop, V written directly transposed).
// ---------------------------------------------------------------------------
__global__ __launch_bounds__(256) void qkv_mfma64(
    const bf16* __restrict__ X,
    const bf16* __restrict__ w1t, const bf16* __restrict__ w2t,
    bf16* __restrict__ q1, bf16* __restrict__ k1, bf16* __restrict__ v1t,
    bf16* __restrict__ q2, bf16* __restrict__ k2, bf16* __restrict__ v2t)
{
    constexpr int K = Dc;  // 512
    __shared__ unsigned short Asm[2 * 64 * 32];    // 8 KB
    __shared__ unsigned short Bsm[2 * 128 * 32];   // 16 KB
    constexpr int ABUF = 64 * 32, BBUF = 128 * 32;

    const int tid  = threadIdx.x;
    const int wv   = tid >> 6;
    const int lane = tid & 63;
    const int q    = lane >> 4;
    const int ln   = lane & 15;
    const int wm   = wv & 1;
    const int wn   = wv >> 1;
    const int set  = blockIdx.z;

    const bf16* Wt = set ? w2t : w1t;
    bf16* Q  = set ? q2 : q1;
    bf16* Ko = set ? k2 : k1;
    bf16* Vt = set ? v2t : v1t;

    const bf16* A  = X  + (long)(blockIdx.y * 64) * K;
    const bf16* Bt = Wt + (long)(blockIdx.x * 128) * K;

    const int sr = lane >> 2, sc = lane & 3;
    const int scs = sc ^ (sr & 3);
    const bf16* gA0 = A  + (long)(wv * 16 + sr)      * K + scs * 8;
    const bf16* gB0 = Bt + (long)(wv * 32 + sr)      * K + scs * 8;
    const bf16* gB1 = Bt + (long)(wv * 32 + 16 + sr) * K + scs * 8;
    unsigned short* lA0 = &Asm[(wv * 16)      * 32];
    unsigned short* lB0 = &Bsm[(wv * 32)      * 32];
    unsigned short* lB1 = &Bsm[(wv * 32 + 16) * 32];

    f32x4 acc[2][4];
#pragma unroll
    for (int i = 0; i < 2; ++i)
#pragma unroll
        for (int j = 0; j < 4; ++j)
            acc[i][j] = (f32x4){0.f, 0.f, 0.f, 0.f};

    const int qs = (q ^ (ln & 3)) * 8;

    gl_lds16(gA0, lA0);
    gl_lds16(gB0, lB0);
    gl_lds16(gB1, lB1);
    __syncthreads();

    int cur = 0;
    for (int k0 = 0; k0 < K; k0 += 32) {
        const int nxt = cur ^ 1;
        if (k0 + 32 < K) {
            gl_lds16(gA0 + k0 + 32, lA0 + nxt * ABUF);
            gl_lds16(gB0 + k0 + 32, lB0 + nxt * BBUF);
            gl_lds16(gB1 + k0 + 32, lB1 + nxt * BBUF);
        }

        const unsigned short* Ac = &Asm[cur * ABUF];
        const unsigned short* Bc = &Bsm[cur * BBUF];
        short8 af[2], bfr[4];
#pragma unroll
        for (int mt = 0; mt < 2; ++mt) {
            int m = wm * 32 + mt * 16 + ln;
            af[mt] = *(const short8*)&Ac[m * 32 + qs];
        }
#pragma unroll
        for (int nt = 0; nt < 4; ++nt) {
            int n = wn * 64 + nt * 16 + ln;
            bfr[nt] = *(const short8*)&Bc[n * 32 + qs];
        }
#pragma unroll
        for (int mt = 0; mt < 2; ++mt)
#pragma unroll
            for (int nt = 0; nt < 4; ++nt)
                acc[mt][nt] = __builtin_amdgcn_mfma_f32_16x16x32_bf16(
                    af[mt], bfr[nt], acc[mt][nt], 0, 0, 0);

        __syncthreads();
        cur = nxt;
    }

#pragma unroll
    for (int mt = 0; mt < 2; ++mt) {
#pragma unroll
        for (int nt = 0; nt < 4; ++nt) {
            const int col  = blockIdx.x * 128 + wn * 64 + nt * 16 + ln;
            const int rowb = blockIdx.y * 64 + wm * 32 + mt * 16 + q * 4;
            const int t = col >> 9;
            const int h = (col >> 6) & 7;
            const int dk = col & 63;
            if (t == 2) {
                // V: transposed store — 4 consecutive rows -> one 8B write
                const int b = rowb >= Nc ? 1 : 0;
                const int n = rowb - b * Nc;
                unsigned short o[4];
#pragma unroll
                for (int r = 0; r < 4; ++r) {
                    const bf16 bb = __float2bfloat16(acc[mt][nt][r]);
                    o[r] = *(const unsigned short*)&bb;
                }
                unsigned short* d = (unsigned short*)Vt +
                    (((long)b * Hc + h) * DKc + dk) * Nc + n;
                *(uint2*)d = *(const uint2*)o;
            } else {
                bf16* dst = (t == 0) ? Q : Ko;
#pragma unroll
                for (int r = 0; r < 4; ++r) {
                    const int row = rowb + r;
                    const int b = row >= Nc ? 1 : 0;
                    const int n = row - b * Nc;
                    dst[(((long)b * Hc + h) * Nc + n) * DKc + dk] =
                        __float2bfloat16(acc[mt][nt][r]);
                }
            }
        }
    }
}

// ---------------------------------------------------------------------------
// MFMA bf16 NT narrow GEMM core (validated): acc = A(128,K) @ Bt(64,K)^T.
// ---------------------------------------------------------------------------
struct N64Acc { f32x4 acc[2][4]; };

template <typename DUMMY = void>
DEVINL void n64_core(const bf16* A, const bf16* Bt, int K,
                     unsigned short* Asm, unsigned short* Bsm, N64Acc& R)
{
    const int tid  = threadIdx.x;
    const int wave = tid >> 6;
    const int lane = tid & 63;
    const int q    = lane >> 4;
    const int ln   = lane & 15;

    const int sr = tid >> 3, k8 = tid & 7;
    const bf16* pa[4];
    const bf16* pb[2];
    int wa[4], wb[2];
#pragma unroll
    for (int i = 0; i < 4; ++i) {
        pa[i] = A + (long)(sr + i * 32) * K + k8 * 8;
        wa[i] = (sr + i * 32) * 72 + k8 * 8;
    }
#pragma unroll
    for (int i = 0; i < 2; ++i) {
        pb[i] = Bt + (long)(sr + i * 32) * K + k8 * 8;
        wb[i] = (sr + i * 32) * 72 + k8 * 8;
    }

#pragma unroll
    for (int i = 0; i < 2; ++i)
#pragma unroll
        for (int j = 0; j < 4; ++j)
            R.acc[i][j] = (f32x4){0.f, 0.f, 0.f, 0.f};

    for (int k0 = 0; k0 < K; k0 += 64) {
        uint4 va[4], vb[2];
#pragma unroll
        for (int i = 0; i < 4; ++i) va[i] = *(const uint4*)(pa[i] + k0);
#pragma unroll
        for (int i = 0; i < 2; ++i) vb[i] = *(const uint4*)(pb[i] + k0);
        __syncthreads();
#pragma unroll
        for (int i = 0; i < 4; ++i) *(uint4*)&Asm[wa[i]] = va[i];
#pragma unroll
        for (int i = 0; i < 2; ++i) *(uint4*)&Bsm[wb[i]] = vb[i];
        __syncthreads();

#pragma unroll
        for (int kc = 0; kc < 2; ++kc) {
            short8 af[2], bfr[4];
#pragma unroll
            for (int mt = 0; mt < 2; ++mt) {
                int m = wave * 32 + mt * 16 + ln;
                af[mt] = *(const short8*)&Asm[m * 72 + kc * 32 + q * 8];
            }
#pragma unroll
            for (int nt = 0; nt < 4; ++nt) {
                int n = nt * 16 + ln;
                bfr[nt] = *(const short8*)&Bsm[n * 72 + kc * 32 + q * 8];
            }
#pragma unroll
            for (int mt = 0; mt < 2; ++mt)
#pragma unroll
                for (int nt = 0; nt < 4; ++nt)
                    R.acc[mt][nt] = __builtin_amdgcn_mfma_f32_16x16x32_bf16(
                        af[mt], bfr[nt], R.acc[mt][nt], 0, 0, 0);
        }
    }
}

// ---------------------------------------------------------------------------
// HALF-HEIGHT n64 core — acc = A(64,K) @ Bt(64,K)^T (validated r9).
// ---------------------------------------------------------------------------
struct N64hAcc { f32x4 acc[4]; };

template <typename DUMMY = void>
DEVINL void n64h_core(const bf16* A, const bf16* Bt, int K,
                      unsigned short* Asm, unsigned short* Bsm, N64hAcc& R)
{
    const int tid  = threadIdx.x;
    const int wave = tid >> 6;
    const int lane = tid & 63;
    const int q    = lane >> 4;
    const int ln   = lane & 15;

    const int sr = tid >> 3, k8 = tid & 7;   // sr 0..31, k8 0..7
    const bf16* pa[2];
    const bf16* pb[2];
    int wa[2], wb[2];
#pragma unroll
    for (int i = 0; i < 2; ++i) {
        pa[i] = A  + (long)(sr + i * 32) * K + k8 * 8;
        wa[i] = (sr + i * 32) * 72 + k8 * 8;
        pb[i] = Bt + (long)(sr + i * 32) * K + k8 * 8;
        wb[i] = wa[i];
    }

#pragma unroll
    for (int j = 0; j < 4; ++j)
        R.acc[j] = (f32x4){0.f, 0.f, 0.f, 0.f};

    for (int k0 = 0; k0 < K; k0 += 64) {
        uint4 va[2], vb[2];
#pragma unroll
        for (int i = 0; i < 2; ++i) va[i] = *(const uint4*)(pa[i] + k0);
#pragma unroll
        for (int i = 0; i < 2; ++i) vb[i] = *(const uint4*)(pb[i] + k0);
        __syncthreads();
#pragma unroll
        for (int i = 0; i < 2; ++i) *(uint4*)&Asm[wa[i]] = va[i];
#pragma unroll
        for (int i = 0; i < 2; ++i) *(uint4*)&Bsm[wb[i]] = vb[i];
        __syncthreads();

#pragma unroll
        for (int kc = 0; kc < 2; ++kc) {
            short8 af;
            af = *(const short8*)&Asm[(wave * 16 + ln) * 72 + kc * 32 + q * 8];
            short8 bfr[4];
#pragma unroll
            for (int nt = 0; nt < 4; ++nt) {
                int n = nt * 16 + ln;
                bfr[nt] = *(const short8*)&Bsm[n * 72 + kc * 32 + q * 8];
            }
#pragma unroll
            for (int nt = 0; nt < 4; ++nt)
                R.acc[nt] = __builtin_amdgcn_mfma_f32_16x16x32_bf16(
                    af, bfr[nt], R.acc[nt], 0, 0, 0);
        }
    }
}

// ---------------------------------------------------------------------------
// Merged pair launch (Path-B fallback only; validated round 11).
// ---------------------------------------------------------------------------
__global__ __launch_bounds__(256) void gemm_n64_pair(
    const bf16* __restrict__ A0g, const bf16* __restrict__ B0g, bf16* __restrict__ C0tg,
    const bf16* __restrict__ A1g, const bf16* __restrict__ B1g, bf16* __restrict__ C1g,
    int M, int K, long sA, long sB, long sC)
{
    __shared__ unsigned short Asm[128 * 72];
    __shared__ unsigned short Bsm[64 * 72];

    const int zz = blockIdx.z & 15;
    const int second = blockIdx.z >> 4;
    const bf16* A  = (second ? A1g : A0g) + (long)zz * sA + (long)(blockIdx.y * 128) * K;
    const bf16* Bt = (second ? B1g : B0g) + (long)zz * sB;

    N64Acc R;
    n64_core(A, Bt, K, Asm, Bsm, R);

    const int tid = threadIdx.x;
    const int wave = tid >> 6, lane = tid & 63, q = lane >> 4, ln = lane & 15;

    if (second) {
        bf16* C = C1g + (long)zz * sC;
#pragma unroll
        for (int mt = 0; mt < 2; ++mt) {
#pragma unroll
            for (int nt = 0; nt < 4; ++nt) {
                const int col  = nt * 16 + ln;
                const int rowb = blockIdx.y * 128 + wave * 32 + mt * 16 + q * 4;
#pragma unroll
                for (int r = 0; r < 4; ++r)
                    C[(long)(rowb + r) * 64 + col] = __float2bfloat16(R.acc[mt][nt][r]);
            }
        }
    } else {
        __syncthreads();
#pragma unroll
        for (int mt = 0; mt < 2; ++mt) {
#pragma unroll
            for (int nt = 0; nt < 4; ++nt) {
                const int col = nt * 16 + ln;
                const int rwb = wave * 32 + mt * 16 + q * 4;
#pragma unroll
                for (int r = 0; r < 4; ++r)
                    *(bf16*)&Asm[col * 136 + rwb + r] = __float2bfloat16(R.acc[mt][nt][r]);
            }
        }
        __syncthreads();
        bf16* Ct = C0tg + (long)zz * sC;
        const int dk  = tid >> 2;
        const int nc0 = (tid & 3) * 32;
        const int gn0 = blockIdx.y * 128;
#pragma unroll
        for (int c8 = 0; c8 < 4; ++c8) {
            uint4 v = *(const uint4*)&Asm[dk * 136 + nc0 + c8 * 8];
            *(uint4*)&Ct[(long)dk * Nc + gn0 + nc0 + c8 * 8] = v;
        }
    }
}

// ---------------------------------------------------------------------------
// Merged y kernel, half-height tiles (Path A; validated r9). 192 blocks.
// ---------------------------------------------------------------------------
__global__ __launch_bounds__(256) void gemm_n64_both_h(
    const bf16* __restrict__ Ab, const bf16* __restrict__ v1t,
    const bf16* __restrict__ Craw, const bf16* __restrict__ v2t,
    const float* __restrict__ smallf, bf16* __restrict__ yc,
    int K, long sA, long sB)
{
    __shared__ unsigned short Asm[64 * 72];
    __shared__ unsigned short Bsm[64 * 72];

    const int bh = blockIdx.z;
    const long arow = (long)(blockIdx.y * 64) * K;

    N64hAcc R1;
    n64h_core(Ab + (long)bh * sA + arow, v1t + (long)bh * sB, K, Asm, Bsm, R1);
    N64hAcc R2;
    n64h_core(Craw + (long)bh * sA + arow, v2t + (long)bh * sB, K, Asm, Bsm, R2);

    const float w = sigf(smallf[392]);
    const int b = bh >> 3, h = bh & 7;

    const int tid = threadIdx.x;
    const int wave = tid >> 6, lane = tid & 63, q = lane >> 4, ln = lane & 15;
#pragma unroll
    for (int nt = 0; nt < 4; ++nt) {
        const int col  = nt * 16 + ln;
        const int rowb = blockIdx.y * 64 + wave * 16 + q * 4;
#pragma unroll
        for (int r = 0; r < 4; ++r) {
            const int n = rowb + r;
            yc[((long)(b * Nc + n)) * Dc + h * DKc + col] =
                __float2bfloat16(R1.acc[nt][r] + w * R2.acc[nt][r]);
        }
    }
}

// y_chain GEMM with fused combine + permute (Path-B fallback only).
__global__ __launch_bounds__(256) void gemm_n64_combine(
    const bf16* __restrict__ A1b, const bf16* __restrict__ trt,
    const bf16* __restrict__ yb1, const float* __restrict__ smallf,
    bf16* __restrict__ yc, int M, int K, long sA, long sB)
{
    __shared__ unsigned short Asm[128 * 72];
    __shared__ unsigned short Bsm[64 * 72];

    const int bh = blockIdx.z;
    const bf16* A  = A1b + (long)bh * sA + (long)(blockIdx.y * 128) * K;
    const bf16* Bt = trt + (long)bh * sB;

    N64Acc R;
    n64_core(A, Bt, K, Asm, Bsm, R);

    const float w = sigf(smallf[392]);
    const int b = bh >> 3, h = bh & 7;
    const long yb1base = (long)bh * Nc * DKc;

    const int tid = threadIdx.x;
    const int wave = tid >> 6, lane = tid & 63, q = lane >> 4, ln = lane & 15;
#pragma unroll
    for (int mt = 0; mt < 2; ++mt) {
#pragma unroll
        for (int nt = 0; nt < 4; ++nt) {
            const int col  = nt * 16 + ln;
            const int rowb = blockIdx.y * 128 + wave * 32 + mt * 16 + q * 4;
#pragma unroll
            for (int r = 0; r < 4; ++r) {
                const int n = rowb + r;
                const float base = __bfloat162float(yb1[yb1base + (long)n * 64 + col]);
                yc[((long)(b * Nc + n)) * Dc + h * DKc + col] =
                    __float2bfloat16(base + w * R.acc[mt][nt][r]);
            }
        }
    }
}

// Path-B y_base GEMM (fallback only).
__global__ __launch_bounds__(256) void gemm_n64_yb(
    const bf16* __restrict__ Ag, const bf16* __restrict__ Btg,
    bf16* __restrict__ Cg, int M, int K, long sA, long sB, long sC)
{
    __shared__ unsigned short Asm[128 * 72];
    __shared__ unsigned short Bsm[64 * 72];

    const int zz = blockIdx.z;
    const bf16* A  = Ag + (long)zz * sA + (long)(blockIdx.y * 128) * K;
    const bf16* Bt = Btg + (long)zz * sB;

    N64Acc R;
    n64_core(A, Bt, K, Asm, Bsm, R);

    bf16* C = Cg + (long)zz * sC;
    const int tid = threadIdx.x;
    const int wave = tid >> 6, lane = tid & 63, q = lane >> 4, ln = lane & 15;
#pragma unroll
    for (int mt = 0; mt < 2; ++mt) {
#pragma unroll
        for (int nt = 0; nt < 4; ++nt) {
            const int col  = nt * 16 + ln;
            const int rowb = blockIdx.y * 128 + wave * 32 + mt * 16 + q * 4;
#pragma unroll
            for (int r = 0; r < 4; ++r)
                C[(long)(rowb + r) * 64 + col] = __float2bfloat16(R.acc[mt][nt][r]);
        }
    }
}

// ---------------------------------------------------------------------------
// Row softmax over width 768 — wave-per-row (validated round 16).
// ---------------------------------------------------------------------------
__global__ __launch_bounds__(256) void softmax_rows_w(
    const float* __restrict__ src, bf16* __restrict__ dst)
{
    const int wid  = threadIdx.x >> 6;
    const int lane = threadIdx.x & 63;
    const long row = (long)blockIdx.x * 4 + wid;
    const float* s = src + row * Nc;

    float4 v[3];
#pragma unroll
    for (int i = 0; i < 3; ++i)
        v[i] = *(const float4*)&s[i * 256 + lane * 4];

    float m = -1e30f;
#pragma unroll
    for (int i = 0; i < 3; ++i)
        m = fmaxf(m, fmaxf(fmaxf(v[i].x, v[i].y), fmaxf(v[i].z, v[i].w)));
#pragma unroll
    for (int off = 32; off > 0; off >>= 1)
        m = fmaxf(m, __shfl_xor(m, off, 64));

    float e[12];
    float sum = 0.f;
#pragma unroll
    for (int i = 0; i < 3; ++i) {
        e[i * 4 + 0] = __expf(v[i].x - m);
        e[i * 4 + 1] = __expf(v[i].y - m);
        e[i * 4 + 2] = __expf(v[i].z - m);
        e[i * 4 + 3] = __expf(v[i].w - m);
        sum += e[i * 4 + 0] + e[i * 4 + 1] + e[i * 4 + 2] + e[i * 4 + 3];
    }
#pragma unroll
    for (int off = 32; off > 0; off >>= 1)
        sum += __shfl_xor(sum, off, 64);

    const float inv = 1.f / fmaxf(sum, 1e-30f);
    unsigned short* d = (unsigned short*)dst + row * Nc;
#pragma unroll
    for (int i = 0; i < 3; ++i) {
        unsigned short o[4];
#pragma unroll
        for (int j = 0; j < 4; ++j) {
            const bf16 b = __float2bfloat16(e[i * 4 + j] * inv);
            o[j] = *(const unsigned short*)&b;
        }
        *(uint2*)&d[i * 256 + lane * 4] = *(const uint2*)o;
    }
}

// ---------------------------------------------------------------------------
// Gate network + Smix — r7-validated 2-elem body, 32x16 tiling (frozen;
// r11 lesson: this tiling is load-bearing for L2 reuse).
// ---------------------------------------------------------------------------
__global__ __launch_bounds__(256) void gates_smix(
    const float* __restrict__ S1g, const float* __restrict__ S2g,
    const bf16* __restrict__ Crg, const bf16* __restrict__ Clg,
    float* __restrict__ Smixg, const float* __restrict__ smallf)
{
    __shared__ float t1t[32][17], t2t[32][17];

    const long mat = (long)blockIdx.z * Nc * Nc;
    const float* S1 = S1g + mat;
    const float* S2 = S2g + mat;
    const unsigned short* Cr = (const unsigned short*)Crg + mat;
    const unsigned short* Cl = (const unsigned short*)Clg + mat;
    float* Smix = Smixg + mat;

    const int tid = threadIdx.x;

    const int n0 = blockIdx.y * 16, m0 = blockIdx.x * 32;
    {
        const int r = tid >> 3, c2 = (tid & 7) * 2;
        const float2 a = *(const float2*)&S1[(long)(m0 + r) * Nc + n0 + c2];
        const float2 b = *(const float2*)&S2[(long)(m0 + r) * Nc + n0 + c2];
        t1t[r][c2] = a.x; t1t[r][c2 + 1] = a.y;
        t2t[r][c2] = b.x; t2t[r][c2 + 1] = b.y;
    }
    __syncthreads();

    const int tx = tid & 15, ty = tid >> 4;
    const int n = n0 + ty;
    const long idx = (long)n * Nc + m0 + tx * 2;

    const float2 s1v = *(const float2*)&S1[idx];
    const float2 s2v = *(const float2*)&S2[idx];
    const unsigned cru = *(const unsigned*)&Cr[idx];
    const unsigned clu = *(const unsigned*)&Cl[idx];

    const f32x2 s1a = {s1v.x, s1v.y};
    const f32x2 s2a = {s2v.x, s2v.y};
    const f32x2 cra = {__uint_as_float((cru & 0xffffu) << 16),
                       __uint_as_float(cru & 0xffff0000u)};
    const f32x2 cla = {__uint_as_float((clu & 0xffffu) << 16),
                       __uint_as_float(clu & 0xffff0000u)};
    const f32x2 s1t = {t1t[tx * 2][ty], t1t[tx * 2 + 1][ty]};
    const f32x2 s2t = {t2t[tx * 2][ty], t2t[tx * 2 + 1][ty]};

    f32x2 g0 = *(const f32x2*)&smallf[384];
    f32x2 g1 = *(const f32x2*)&smallf[386];
    f32x2 g2 = *(const f32x2*)&smallf[388];
    f32x2 g3 = *(const f32x2*)&smallf[390];

    const f32x2 gc1  = splat2(-2.30220902f);
    const f32x2 gc3  = splat2(-0.10294357f);
    const f32x2 one2 = splat2(1.f);

#pragma unroll
    for (int u = 0; u < 16; ++u) {
        const f32x2* cw = (const f32x2*)&smallf[u * 24];
        f32x2 h = cw[6];
        h = fma2(s1a, cw[0], h);
        h = fma2(s2a, cw[1], h);
        h = fma2(s1t, cw[2], h);
        h = fma2(s2t, cw[3], h);
        h = fma2(cra, cw[4], h);
        h = fma2(cla, cw[5], h);
        const f32x2 hh = h * h;
        const f32x2 z2 = h * fma2(hh, gc3, gc1);
        f32x2 e;  e[0]  = vexp2(z2[0]); e[1]  = vexp2(z2[1]);
        const f32x2 d = one2 + e;
        f32x2 rc; rc[0] = vrcp(d[0]);   rc[1] = vrcp(d[1]);
        const f32x2 hid = h * rc;
        g0 = fma2(hid, cw[8],  g0);
        g1 = fma2(hid, cw[9],  g1);
        g2 = fma2(hid, cw[10], g2);
        g3 = fma2(hid, cw[11], g3);
    }

    const f32x2 nl2e = splat2(-1.44269504f);
    const f32x2 ln2v = splat2(0.69314718f);
    auto sig2 = [&](f32x2 x) -> f32x2 {
        const f32x2 t = x * nl2e;
        f32x2 e;  e[0] = vexp2(t[0]); e[1] = vexp2(t[1]);
        const f32x2 d = one2 + e;
        f32x2 r;  r[0] = vrcp(d[0]);  r[1] = vrcp(d[1]);
        return r;
    };
    const f32x2 ga2 = sig2(g0);
    const f32x2 go2 = sig2(g1);
    const f32x2 gn2 = sig2(g2);
    const f32x2 gc2 = sig2(g3);

    const f32x2 dd = s1a - s2a;
    f32x2 ad; ad[0] = fabsf(dd[0]); ad[1] = fabsf(dd[1]);
    const f32x2 t2 = ad * nl2e;
    f32x2 ee; ee[0] = vexp2(t2[0]); ee[1] = vexp2(t2[1]);
    const f32x2 lp = one2 + ee;
    f32x2 lg; lg[0] = vlog2(lp[0]); lg[1] = vlog2(lp[1]);
    const f32x2 mx2 = __builtin_elementwise_max(s1a, s2a);
    const f32x2 lae = fma2(lg, ln2v, mx2);

    f32x2 o2 = s1a;
    o2 = fma2(ga2, s2a, o2);
    o2 = fma2(go2, lae - s1a, o2);
    o2 = fma2(gn2, s2a * splat2(-BETA_NOT), o2);
    o2 = fma2(gc2, cra, o2);
    *(float2*)&Smix[idx] = (float2){o2[0], o2[1]};
}

// ---------------------------------------------------------------------------
// Final projection, half-height tiles — 192 blocks (validated r9).
// ---------------------------------------------------------------------------
__global__ __launch_bounds__(256) void proj_n64h(
    const bf16* __restrict__ yc, const bf16* __restrict__ pwt,
    const void* __restrict__ xraw, void* __restrict__ out)
{
    constexpr int K = Dc;  // 512
    constexpr int N = Dc;  // 512
    __shared__ unsigned short Asm[64 * 72];
    __shared__ unsigned short Bsm[64 * 72];
    __shared__ int is32s;
    if (threadIdx.x == 0) is32s = sniff_is_fp32(xraw);

    const bf16* A  = yc  + (long)(blockIdx.y * 64) * K;
    const bf16* Bt = pwt + (long)(blockIdx.x * 64) * K;

    N64hAcc R;
    n64h_core(A, Bt, K, Asm, Bsm, R);   // internal barriers publish is32s

    const int is32 = is32s;
    const int tid = threadIdx.x;
    const int wave = tid >> 6, lane = tid & 63, q = lane >> 4, ln = lane & 15;
#pragma unroll
    for (int nt = 0; nt < 4; ++nt) {
        const int col  = blockIdx.x * 64 + nt * 16 + ln;
        const int rowb = blockIdx.y * 64 + wave * 16 + q * 4;
#pragma unroll
        for (int r = 0; r < 4; ++r) {
            const long o = (long)(rowb + r) * N + col;
            if (is32) ((float*)out)[o] = R.acc[nt][r];
            else      ((bf16*)out)[o] = __float2bfloat16(R.acc[nt][r]);
        }
    }
}

// ---------------------------------------------------------------------------
extern "C" void kernel_launch(void* const* d_in, const int* in_sizes, int n_in,
                              void* d_out, int out_size, void* d_ws, size_t ws_size,
                              hipStream_t stream)
{
    const size_t HD   = (size_t)BHc * Nc * DKc;   // 786432
    const size_t HDh  = HD / 2;                   // float-slots for HD bf16
    const size_t MAT  = (size_t)Nc * Nc;          // 589824
    const size_t MATS = (size_t)BHc * MAT;        // 9437184
    const long   HSTR = (long)Nc * DKc;           // 49152 per-head stride

    float* ws = (float*)d_ws;
    size_t off = 0;
    auto alloc = [&](size_t n) { float* p = ws + off; off += n; return p; };

    bf16* xb  = (bf16*)alloc(HDh);
    bf16* w1t = (bf16*)alloc(HDh);
    bf16* w2t = (bf16*)alloc(HDh);
    bf16* pwt = (bf16*)alloc((size_t)Dc * Dc / 2);
    float* smallf = alloc(512);
    // q1|q2 and k1|k2 adjacent -> single merged fused-S launch (32 batches)
    bf16* q1b = (bf16*)alloc(HDh); bf16* q2b = (bf16*)alloc(HDh);
    bf16* k1b = (bf16*)alloc(HDh); bf16* k2b = (bf16*)alloc(HDh);
    bf16* v1t = (bf16*)alloc(HDh); bf16* v2t = (bf16*)alloc(HDh);  // adjacent
    bf16* trt = (bf16*)alloc(HDh);
    float* S1   = alloc(MATS);       // S1/S2 adjacent
    float* S2   = alloc(MATS);
    float* Smix = alloc(MATS);       // region reused: A1tb|A2tb, then Smix
    bf16* A1b = (bf16*)alloc(MATS / 2);  // A1b/A2b adjacent
    bf16* A2b = (bf16*)alloc(MATS / 2);
    bf16* Crb = (bf16*)alloc(MATS / 2);  // Crb/Clb adjacent (merged launch)
    bf16* Clb = (bf16*)alloc(MATS / 2);
    bf16* yb1 = (bf16*)alloc(HDh);
    bf16* yc  = (bf16*)alloc(HDh);

    const size_t NEED_BASE = off * sizeof(float);
    bf16* Crawb = (bf16*)alloc(MATS / 2);          // raw C_right (Path A only)
    const size_t NEED_A = off * sizeof(float);
    const int pathA = ws_size >= NEED_A;

    // aliases into dead regions
    bf16* A1tb = (bf16*)Smix;            // live steps 3-4 (dead once gates writes Smix)
    bf16* A2tb = ((bf16*)Smix) + MATS;
    bf16* Ab   = (bf16*)S1;              // S1 dead after gates

    if (ws_size < NEED_BASE) {
        fill_sentinel<<<dim3(3072), 256, 0, stream>>>((unsigned short*)d_out);
        return;
    }

    // 0+1. FUSED convert + W/pw transpose (one launch; kills w1b/w2b/pwb
    //      round-trip). Then QKV 64x128 tiles (V written transposed).
    convert_tr<<<dim3(833), 256, 0, stream>>>(
        d_in[0], d_in[1], d_in[2], d_in[3], d_in[4], d_in[5], d_in[6], d_in[7],
        d_in[8], xb, w1t, w2t, pwt, smallf);
    qkv_mfma64<<<dim3(12, 24, 2), 256, 0, stream>>>(
        xb, w1t, w2t, q1b, k1b, v1t, q2b, k2b, v2t);

    // 2+3. FUSED: S = scale*q@k^T, row softmax -> A, A^T (validated r10)
    sgemm_softmax<<<dim3(1536), 256, 0, stream>>>(
        q1b, k1b, S1, A1b, A1tb);

    // 4. Cr|Cl in ONE 32-batch launch; XCD-pinned 1-D grid; 2-phase K-loop;
    //    Path A also stores raw C_right.
    if (pathA)
        gemm_nt_mfma<1, bf16, 1, 1, 1><<<dim3(1152), 256, 0, stream>>>(
            A1b, A1tb, Crb, Crawb, Nc, Nc, Nc, (long)MAT, (long)MAT, (long)MAT, 1.f);
    else
        gemm_nt_mfma<1, bf16, 1, 1, 0><<<dim3(1152), 256, 0, stream>>>(
            A1b, A1tb, Crb, nullptr, Nc, Nc, Nc, (long)MAT, (long)MAT, (long)MAT, 1.f);

    // 5. gates + Smix (r7-validated 2-elem body, 32x16 tiling)
    gates_smix<<<dim3(24, 48, BHc), 256, 0, stream>>>(S1, S2, Crb, Clb, Smix, smallf);

    // 6. A = softmax(Smix) -> bf16 (into S1 alias, wave-per-row)
    softmax_rows_w<<<(BHc * Nc) / 4, 256, 0, stream>>>(Smix, Ab);

    if (pathA) {
        // 7. merged y, half-height tiles: 192 blocks
        gemm_n64_both_h<<<dim3(1, 12, BHc), 256, 0, stream>>>(
            Ab, v1t, Crawb, v2t, smallf, yc, Nc, (long)MAT, HSTR);
    } else {
        // Path B fallback (v1t/v2t already transposed)
        gemm_n64_pair<<<dim3(1, 6, 2 * BHc), 256, 0, stream>>>(
            A2b, v2t, trt, Ab, v1t, yb1, Nc, Nc, (long)MAT, HSTR, HSTR);
        gemm_n64_combine<<<dim3(1, 6, BHc), 256, 0, stream>>>(
            A1b, trt, yb1, smallf, yc, Nc, Nc, (long)MAT, HSTR);
    }

    // 9. proj, half-height tiles: 192 blocks
    proj_n64h<<<dim3(8, 24, 1), 256, 0, stream>>>(yc, pwt, d_in[0], d_out);
}

// Round 15
// 309.821 us; speedup vs baseline: 1.0737x; 1.0507x over previous
//
#include <hip/hip_runtime.h>
#include <hip/hip_bf16.h>
#include <math.h>

typedef __hip_bfloat16 bf16;
typedef __attribute__((ext_vector_type(8))) short short8;   // 8 bf16 (4 VGPRs)
typedef __attribute__((ext_vector_type(4))) float f32x4;
typedef __attribute__((ext_vector_type(2))) float f32x2;
#define DEVINL __device__ __forceinline__

constexpr int Bc  = 2;
constexpr int Nc  = 768;
constexpr int Dc  = 512;
constexpr int Hc  = 8;
constexpr int DKc = 64;
constexpr int BHc = Bc * Hc;
constexpr float SCALE    = 0.125f;   // 1/sqrt(64)
constexpr float EPSF     = 1e-6f;
constexpr float BETA_NOT = 0.5f;

DEVINL float ldf(const float* p, long i) { return p[i]; }
DEVINL float ldf(const bf16* p, long i) { return __bfloat162float(p[i]); }
DEVINL void stf(float* p, long i, float v) { p[i] = v; }
DEVINL void stf(bf16* p, long i, float v) { p[i] = __float2bfloat16(v); }

DEVINL float sigf(float x) { return __fdividef(1.f, 1.f + __expf(-x)); }

// packed fp32 pair helpers — backend selects v_pk_fma_f32/v_pk_mul_f32 (r3:
// validated -41% on gates_smix; r4 pair-dup operands -12%; r5 s_load weights).
DEVINL f32x2 fma2(f32x2 a, f32x2 b, f32x2 c) { return __builtin_elementwise_fma(a, b, c); }
DEVINL f32x2 splat2(float x) { return (f32x2){x, x}; }
// guard-free transcendentals (libm exp2f adds a denormal guard: +13% in r2)
DEVINL float vexp2(float x) { float r; asm("v_exp_f32 %0, %1" : "=v"(r) : "v"(x)); return r; }
DEVINL float vrcp(float x)  { float r; asm("v_rcp_f32 %0, %1" : "=v"(r) : "v"(x)); return r; }
DEVINL float vlog2(float x) { float r; asm("v_log_f32 %0, %1" : "=v"(r) : "v"(x)); return r; }

// async global->LDS, 16B per lane; LDS dest = wave-uniform base + lane*16.
DEVINL void gl_lds16(const void* g, void* l) {
    __builtin_amdgcn_global_load_lds(
        (const __attribute__((address_space(1))) void*)g,
        (__attribute__((address_space(3))) void*)l, 16, 0, 0);
}

// ---------------------------------------------------------------------------
// Dtype sniffer — vectorized (validated round 9).
// ---------------------------------------------------------------------------
DEVINL int sniff_is_fp32(const void* xraw) {
    const uint4* p4 = (const uint4*)xraw;
    float mx = 0.f;
#pragma unroll
    for (int j = 0; j < 16; ++j) {
        const uint4 u = p4[j];
        const unsigned w[4] = {u.x, u.y, u.z, u.w};
#pragma unroll
        for (int t = 0; t < 4; ++t) {
            mx = fmaxf(mx, fabsf(__uint_as_float((w[t] & 0xffffu) << 16)));
            mx = fmaxf(mx, fabsf(__uint_as_float(w[t] & 0xffff0000u)));
        }
    }
    return mx > 1000.f ? 1 : 0;
}

DEVINL float cvt_elem(const void* s, long j, int is32) {
    return is32 ? ((const float*)s)[j]
                : __bfloat162float(((const bf16*)s)[j]);
}

// ---------------------------------------------------------------------------
// FUSED convert + W/pw TRANSPOSE (validated r14 — neutral-positive, 1 launch).
// ---------------------------------------------------------------------------
__global__ __launch_bounds__(256) void convert_tr(
    const void* x, const void* w1, const void* w2, const void* pw,
    const void* c1w, const void* c1b, const void* c2w, const void* c2b,
    const void* ch,
    bf16* xb, bf16* w1t, bf16* w2t, bf16* pwt, float* smallf)
{
    __shared__ unsigned short tile[64][68];
    __shared__ int is32s;
    if (threadIdx.x == 0) is32s = sniff_is_fp32(x);
    __syncthreads();
    const int is32 = is32s;
    const int t = blockIdx.x;
    const int tid = threadIdx.x;

    if (t < 448) {
        const void* src; bf16* dst; int R, C, bx, by;
        if (t < 192)      { src = w1; dst = w1t; R = Dc; C = 3 * Dc;
                            bx = t % 24;         by = t / 24; }
        else if (t < 384) { src = w2; dst = w2t; R = Dc; C = 3 * Dc;
                            bx = (t - 192) % 24; by = (t - 192) / 24; }
        else              { src = pw; dst = pwt; R = Dc; C = Dc;
                            bx = (t - 384) % 8;  by = (t - 384) / 8; }
        const int r0 = by * 64, c0 = bx * 64;
        const int lr = tid >> 4, lc4 = (tid & 15) * 4;
#pragma unroll
        for (int i = 0; i < 4; ++i) {
            const int r = lr + i * 16;
            const long base = (long)(r0 + r) * C + c0 + lc4;
            unsigned short v[4];
            if (is32) {
                const float4 f = *(const float4*)&((const float*)src)[base];
                const bf16 b0 = __float2bfloat16(f.x);
                const bf16 b1 = __float2bfloat16(f.y);
                const bf16 b2 = __float2bfloat16(f.z);
                const bf16 b3 = __float2bfloat16(f.w);
                v[0] = *(const unsigned short*)&b0;
                v[1] = *(const unsigned short*)&b1;
                v[2] = *(const unsigned short*)&b2;
                v[3] = *(const unsigned short*)&b3;
            } else {
                *(uint2*)v = *(const uint2*)&((const unsigned short*)src)[base];
            }
            *(uint2*)&tile[r][lc4] = *(const uint2*)v;
        }
        __syncthreads();
#pragma unroll
        for (int i = 0; i < 4; ++i) {
            const int r = lr + i * 16;
            unsigned short v[4];
#pragma unroll
            for (int j = 0; j < 4; ++j) v[j] = tile[lc4 + j][r];
            *(uint2*)&((unsigned short*)dst)[(long)(c0 + r) * R + r0 + lc4] =
                *(const uint2*)v;
        }
    } else if (t < 832) {
        const long i0 = (long)(t - 448) * 2048 + tid * 8;
        if (is32) {
            const float4 a = *(const float4*)&((const float*)x)[i0];
            const float4 b = *(const float4*)&((const float*)x)[i0 + 4];
            const float f[8] = {a.x, a.y, a.z, a.w, b.x, b.y, b.z, b.w};
            unsigned short o[8];
#pragma unroll
            for (int j = 0; j < 8; ++j) {
                const bf16 bb = __float2bfloat16(f[j]);
                o[j] = *(const unsigned short*)&bb;
            }
            *(uint4*)&((unsigned short*)xb)[i0] = *(const uint4*)o;
        } else {
            *(uint4*)&((unsigned short*)xb)[i0] =
                *(const uint4*)&((const unsigned short*)x)[i0];
        }
    } else {
#pragma unroll
        for (int base = 0; base < 512; base += 256) {
            const int i = base + tid;
            if (i < 384) {
                const int u = i / 24, k = i % 24;
                float v = 0.f;
                if (k < 12)      v = cvt_elem(c1w, u * 6 + (k >> 1), is32);
                else if (k < 14) v = cvt_elem(c1b, u, is32);
                else if (k >= 16) { const int o = (k - 16) >> 1;
                                    v = cvt_elem(c2w, o * 16 + u, is32); }
                smallf[i] = v;
            } else if (i < 392) smallf[i] = cvt_elem(c2b, (i - 384) >> 1, is32);
            else if (i < 394) smallf[i] = cvt_elem(ch, 0, is32);
            else smallf[i] = 0.f;
        }
    }
}

__global__ __launch_bounds__(256) void fill_sentinel(unsigned short* o) {
    const long i = (long)blockIdx.x * 256 + threadIdx.x;
    if (i < (long)Bc * Nc * Dc) o[i] = 0x40E0;  // bf16 7.0
}

// ---------------------------------------------------------------------------
// Round 22 (validated): FUSED S-GEMM + row softmax + A-transpose.
// ---------------------------------------------------------------------------
__global__ __launch_bounds__(256) void sgemm_softmax(
    const bf16* __restrict__ qg, const bf16* __restrict__ kg,
    float* __restrict__ Sg, bf16* __restrict__ Ag_, bf16* __restrict__ Atg)
{
    __shared__ unsigned short Bsm[256 * 72];   // 36 KB; aliased for A^T stage
    __shared__ unsigned short Asm16[16 * 72];  // 2.25 KB
    __shared__ float red[4][16];

    const int wg  = blockIdx.x;
    const int xcd = wg & 7, tt = wg >> 3;
    const int z   = xcd + 8 * (tt / 48);
    const int by  = tt % 48;
    const long MAT = (long)Nc * Nc;

    const bf16* Q  = qg + (long)z * (Nc * DKc) + (long)(by * 16) * DKc;
    const bf16* Km = kg + (long)z * (Nc * DKc);
    float* S  = Sg  + (long)z * MAT + (long)(by * 16) * Nc;
    bf16*  A  = Ag_ + (long)z * MAT + (long)(by * 16) * Nc;
    bf16*  At = Atg + (long)z * MAT;           // write At[m][by*16 + n]

    const int tid  = threadIdx.x;
    const int wv   = tid >> 6;
    const int lane = tid & 63;
    const int q    = lane >> 4;
    const int ln   = lane & 15;
    const int sr   = tid >> 3, k8 = tid & 7;

    if (tid < 128) {
        const int row = tid >> 3, kk = tid & 7;
        *(uint4*)&Asm16[row * 72 + kk * 8] = *(const uint4*)&Q[row * 64 + kk * 8];
    }

    f32x4 acc[12];
#pragma unroll
    for (int j = 0; j < 12; ++j) acc[j] = (f32x4){0.f, 0.f, 0.f, 0.f};

    for (int c = 0; c < 3; ++c) {
        __syncthreads();
#pragma unroll
        for (int i = 0; i < 8; ++i) {
            const int row = sr + i * 32;
            *(uint4*)&Bsm[row * 72 + k8 * 8] =
                *(const uint4*)&Km[(long)(c * 256 + row) * 64 + k8 * 8];
        }
        __syncthreads();
#pragma unroll
        for (int kc = 0; kc < 2; ++kc) {
            const short8 af = *(const short8*)&Asm16[ln * 72 + kc * 32 + q * 8];
#pragma unroll
            for (int t = 0; t < 4; ++t) {
                const int nl = wv * 64 + t * 16 + ln;
                const short8 bfr = *(const short8*)&Bsm[nl * 72 + kc * 32 + q * 8];
                acc[c * 4 + t] = __builtin_amdgcn_mfma_f32_16x16x32_bf16(
                    af, bfr, acc[c * 4 + t], 0, 0, 0);
            }
        }
    }

    float mrow[4] = {-1e30f, -1e30f, -1e30f, -1e30f};
#pragma unroll
    for (int j = 0; j < 12; ++j) {
        const int c = j >> 2, t = j & 3;
        const int col = c * 256 + wv * 64 + t * 16 + ln;
#pragma unroll
        for (int r = 0; r < 4; ++r) {
            const float v = acc[j][r] * SCALE;
            acc[j][r] = v;
            S[(long)(q * 4 + r) * Nc + col] = v;
            mrow[r] = fmaxf(mrow[r], v);
        }
    }
#pragma unroll
    for (int off = 8; off > 0; off >>= 1)
#pragma unroll
        for (int r = 0; r < 4; ++r)
            mrow[r] = fmaxf(mrow[r], __shfl_xor(mrow[r], off, 16));
    if (ln == 0)
#pragma unroll
        for (int r = 0; r < 4; ++r) red[wv][q * 4 + r] = mrow[r];
    __syncthreads();
    float m4[4];
#pragma unroll
    for (int r = 0; r < 4; ++r)
        m4[r] = fmaxf(fmaxf(red[0][q * 4 + r], red[1][q * 4 + r]),
                      fmaxf(red[2][q * 4 + r], red[3][q * 4 + r]));
    __syncthreads();

    float srow[4] = {0.f, 0.f, 0.f, 0.f};
#pragma unroll
    for (int j = 0; j < 12; ++j)
#pragma unroll
        for (int r = 0; r < 4; ++r) {
            const float e = __expf(acc[j][r] - m4[r]);
            acc[j][r] = e;
            srow[r] += e;
        }
#pragma unroll
    for (int off = 8; off > 0; off >>= 1)
#pragma unroll
        for (int r = 0; r < 4; ++r)
            srow[r] += __shfl_xor(srow[r], off, 16);
    if (ln == 0)
#pragma unroll
        for (int r = 0; r < 4; ++r) red[wv][q * 4 + r] = srow[r];
    __syncthreads();
    float inv[4];
#pragma unroll
    for (int r = 0; r < 4; ++r)
        inv[r] = 1.f / fmaxf(red[0][q * 4 + r] + red[1][q * 4 + r] +
                             red[2][q * 4 + r] + red[3][q * 4 + r], 1e-30f);

    unsigned short* ATl = Bsm;   // 768*20*2 = 30.7 KB <= 36 KB
#pragma unroll
    for (int j = 0; j < 12; ++j) {
        const int c = j >> 2, t = j & 3;
        const int col = c * 256 + wv * 64 + t * 16 + ln;
#pragma unroll
        for (int r = 0; r < 4; ++r) {
            const bf16 b = __float2bfloat16(acc[j][r] * inv[r]);
            const unsigned short u = *(const unsigned short*)&b;
            A[(long)(q * 4 + r) * Nc + col] = *(const bf16*)&u;
            ATl[col * 20 + q * 4 + r] = u;
        }
    }
    __syncthreads();
#pragma unroll
    for (int s = 0; s < 3; ++s) {
        const int m = tid + s * 256;
        uint2 v0 = *(const uint2*)&ATl[m * 20 + 0];
        uint2 v1 = *(const uint2*)&ATl[m * 20 + 4];
        uint2 v2 = *(const uint2*)&ATl[m * 20 + 8];
        uint2 v3 = *(const uint2*)&ATl[m * 20 + 12];
        unsigned short* d = (unsigned short*)&At[(long)m * Nc + by * 16];
        *(uint2*)&d[0]  = v0;
        *(uint2*)&d[4]  = v1;
        *(uint2*)&d[8]  = v2;
        *(uint2*)&d[12] = v3;
    }
}

// ---------------------------------------------------------------------------
// MFMA bf16 NT GEMM — 2-phase double-buffered K-loop (validated r7).
// ---------------------------------------------------------------------------
template <int EPI, typename TC, int XORB = 0, int XCDSWZ = 0, int RAW = 0>
__global__ __launch_bounds__(256) void gemm_nt_mfma(
    const bf16* __restrict__ Ag, const bf16* __restrict__ Btg,
    TC* __restrict__ Cg, bf16* __restrict__ Craw, int M, int N, int K,
    long sA, long sB, long sC, float alpha)
{
    __shared__ unsigned short Asm[2 * 128 * 32];
    __shared__ unsigned short Bsm[2 * 128 * 32];
    constexpr int BUF = 128 * 32;   // elements per buffer

    int bx, by, bz;
    if (XCDSWZ) {
        const int wg = blockIdx.x;
        const int xcd = wg & 7, t = wg >> 3;
        bz = xcd + 8 * (t / 36);
        const int tile = t % 36;
        bx = tile % 6; by = tile / 6;
    } else { bx = blockIdx.x; by = blockIdx.y; bz = blockIdx.z; }

    const int tid  = threadIdx.x;
    const int wv   = tid >> 6;
    const int lane = tid & 63;
    const int q    = lane >> 4;
    const int ln   = lane & 15;
    const int wm   = wv & 1;
    const int wn   = wv >> 1;

    const int zb = XORB ? (bz ^ 16) : bz;
    const bf16* A  = Ag  + (long)bz * sA + (long)(by * 128) * K;
    const bf16* Bt = Btg + (long)zb * sB + (long)(bx * 128) * K;
    TC*         C  = Cg  + (long)bz * sC;

    const int sr = lane >> 2, sc = lane & 3;
    const int scs = sc ^ (sr & 3);          // source col-block pre-swizzle
    const bf16* gA0 = A  + (long)(wv * 32 + sr)      * K + scs * 8;
    const bf16* gA1 = A  + (long)(wv * 32 + 16 + sr) * K + scs * 8;
    const bf16* gB0 = Bt + (long)(wv * 32 + sr)      * K + scs * 8;
    const bf16* gB1 = Bt + (long)(wv * 32 + 16 + sr) * K + scs * 8;
    unsigned short* lA0 = &Asm[(wv * 32)      * 32];
    unsigned short* lA1 = &Asm[(wv * 32 + 16) * 32];
    unsigned short* lB0 = &Bsm[(wv * 32)      * 32];
    unsigned short* lB1 = &Bsm[(wv * 32 + 16) * 32];

    f32x4 acc[4][4];
#pragma unroll
    for (int i = 0; i < 4; ++i)
#pragma unroll
        for (int j = 0; j < 4; ++j)
            acc[i][j] = (f32x4){0.f, 0.f, 0.f, 0.f};

    const int qs = (q ^ (ln & 3)) * 8;      // swizzled read block

    gl_lds16(gA0, lA0);
    gl_lds16(gA1, lA1);
    gl_lds16(gB0, lB0);
    gl_lds16(gB1, lB1);
    __syncthreads();

    int cur = 0;
    for (int k0 = 0; k0 < K; k0 += 32) {
        const int nxt = cur ^ 1;
        if (k0 + 32 < K) {
            const int no = nxt * BUF;
            gl_lds16(gA0 + k0 + 32, lA0 + no);
            gl_lds16(gA1 + k0 + 32, lA1 + no);
            gl_lds16(gB0 + k0 + 32, lB0 + no);
            gl_lds16(gB1 + k0 + 32, lB1 + no);
        }

        const unsigned short* Ac = &Asm[cur * BUF];
        const unsigned short* Bc = &Bsm[cur * BUF];
        short8 af[4], bfr[4];
#pragma unroll
        for (int mt = 0; mt < 4; ++mt) {
            int m = wm * 64 + mt * 16 + ln;
            af[mt] = *(const short8*)&Ac[m * 32 + qs];
        }
#pragma unroll
        for (int nt = 0; nt < 4; ++nt) {
            int n = wn * 64 + nt * 16 + ln;
            bfr[nt] = *(const short8*)&Bc[n * 32 + qs];
        }
#pragma unroll
        for (int mt = 0; mt < 4; ++mt)
#pragma unroll
            for (int nt = 0; nt < 4; ++nt)
                acc[mt][nt] = __builtin_amdgcn_mfma_f32_16x16x32_bf16(
                    af[mt], bfr[nt], acc[mt][nt], 0, 0, 0);

        __syncthreads();
        cur = nxt;
    }

#pragma unroll
    for (int mt = 0; mt < 4; ++mt) {
#pragma unroll
        for (int nt = 0; nt < 4; ++nt) {
            const int col = bx * 128 + wn * 64 + nt * 16 + ln;
            const int rowb = by * 128 + wm * 64 + mt * 16 + q * 4;
#pragma unroll
            for (int r = 0; r < 4; ++r) {
                float vraw = acc[mt][nt][r] * alpha;
                if (RAW) {
                    if (bz < 16)
                        Craw[(long)bz * M * N + (long)(rowb + r) * N + col] =
                            __float2bfloat16(vraw);
                }
                float v = vraw;
                if (EPI == 1) v = __logf(fmaxf(v, 0.f) + EPSF);
                stf(C, (long)(rowb + r) * N + col, v);
            }
        }
    }
}

// ---------------------------------------------------------------------------
// QKV via MFMA — 64x128 tiles (validated r13).
// ---------------------------------------------------------------------------
__global__ __launch_bounds__(256) void qkv_mfma64(
    const bf16* __restrict__ X,
    const bf16* __restrict__ w1t, const bf16* __restrict__ w2t,
    bf16* __restrict__ q1, bf16* __restrict__ k1, bf16* __restrict__ v1t,
    bf16* __restrict__ q2, bf16* __restrict__ k2, bf16* __restrict__ v2t)
{
    constexpr int K = Dc;  // 512
    __shared__ unsigned short Asm[2 * 64 * 32];    // 8 KB
    __shared__ unsigned short Bsm[2 * 128 * 32];   // 16 KB
    constexpr int ABUF = 64 * 32, BBUF = 128 * 32;

    const int tid  = threadIdx.x;
    const int wv   = tid >> 6;
    const int lane = tid & 63;
    const int q    = lane >> 4;
    const int ln   = lane & 15;
    const int wm   = wv & 1;
    const int wn   = wv >> 1;
    const int set  = blockIdx.z;

    const bf16* Wt = set ? w2t : w1t;
    bf16* Q  = set ? q2 : q1;
    bf16* Ko = set ? k2 : k1;
    bf16* Vt = set ? v2t : v1t;

    const bf16* A  = X  + (long)(blockIdx.y * 64) * K;
    const bf16* Bt = Wt + (long)(blockIdx.x * 128) * K;

    const int sr = lane >> 2, sc = lane & 3;
    const int scs = sc ^ (sr & 3);
    const bf16* gA0 = A  + (long)(wv * 16 + sr)      * K + scs * 8;
    const bf16* gB0 = Bt + (long)(wv * 32 + sr)      * K + scs * 8;
    const bf16* gB1 = Bt + (long)(wv * 32 + 16 + sr) * K + scs * 8;
    unsigned short* lA0 = &Asm[(wv * 16)      * 32];
    unsigned short* lB0 = &Bsm[(wv * 32)      * 32];
    unsigned short* lB1 = &Bsm[(wv * 32 + 16) * 32];

    f32x4 acc[2][4];
#pragma unroll
    for (int i = 0; i < 2; ++i)
#pragma unroll
        for (int j = 0; j < 4; ++j)
            acc[i][j] = (f32x4){0.f, 0.f, 0.f, 0.f};

    const int qs = (q ^ (ln & 3)) * 8;

    gl_lds16(gA0, lA0);
    gl_lds16(gB0, lB0);
    gl_lds16(gB1, lB1);
    __syncthreads();

    int cur = 0;
    for (int k0 = 0; k0 < K; k0 += 32) {
        const int nxt = cur ^ 1;
        if (k0 + 32 < K) {
            gl_lds16(gA0 + k0 + 32, lA0 + nxt * ABUF);
            gl_lds16(gB0 + k0 + 32, lB0 + nxt * BBUF);
            gl_lds16(gB1 + k0 + 32, lB1 + nxt * BBUF);
        }

        const unsigned short* Ac = &Asm[cur * ABUF];
        const unsigned short* Bc = &Bsm[cur * BBUF];
        short8 af[2], bfr[4];
#pragma unroll
        for (int mt = 0; mt < 2; ++mt) {
            int m = wm * 32 + mt * 16 + ln;
            af[mt] = *(const short8*)&Ac[m * 32 + qs];
        }
#pragma unroll
        for (int nt = 0; nt < 4; ++nt) {
            int n = wn * 64 + nt * 16 + ln;
            bfr[nt] = *(const short8*)&Bc[n * 32 + qs];
        }
#pragma unroll
        for (int mt = 0; mt < 2; ++mt)
#pragma unroll
            for (int nt = 0; nt < 4; ++nt)
                acc[mt][nt] = __builtin_amdgcn_mfma_f32_16x16x32_bf16(
                    af[mt], bfr[nt], acc[mt][nt], 0, 0, 0);

        __syncthreads();
        cur = nxt;
    }

#pragma unroll
    for (int mt = 0; mt < 2; ++mt) {
#pragma unroll
        for (int nt = 0; nt < 4; ++nt) {
            const int col  = blockIdx.x * 128 + wn * 64 + nt * 16 + ln;
            const int rowb = blockIdx.y * 64 + wm * 32 + mt * 16 + q * 4;
            const int t = col >> 9;
            const int h = (col >> 6) & 7;
            const int dk = col & 63;
            if (t == 2) {
                // V: transposed store — 4 consecutive rows -> one 8B write
                const int b = rowb >= Nc ? 1 : 0;
                const int n = rowb - b * Nc;
                unsigned short o[4];
#pragma unroll
                for (int r = 0; r < 4; ++r) {
                    const bf16 bb = __float2bfloat16(acc[mt][nt][r]);
                    o[r] = *(const unsigned short*)&bb;
                }
                unsigned short* d = (unsigned short*)Vt +
                    (((long)b * Hc + h) * DKc + dk) * Nc + n;
                *(uint2*)d = *(const uint2*)o;
            } else {
                bf16* dst = (t == 0) ? Q : Ko;
#pragma unroll
                for (int r = 0; r < 4; ++r) {
                    const int row = rowb + r;
                    const int b = row >= Nc ? 1 : 0;
                    const int n = row - b * Nc;
                    dst[(((long)b * Hc + h) * Nc + n) * DKc + dk] =
                        __float2bfloat16(acc[mt][nt][r]);
                }
            }
        }
    }
}

// ---------------------------------------------------------------------------
// MFMA bf16 NT narrow GEMM core (validated): acc = A(128,K) @ Bt(64,K)^T.
// ---------------------------------------------------------------------------
struct N64Acc { f32x4 acc[2][4]; };

template <typename DUMMY = void>
DEVINL void n64_core(const bf16* A, const bf16* Bt, int K,
                     unsigned short* Asm, unsigned short* Bsm, N64Acc& R)
{
    const int tid  = threadIdx.x;
    const int wave = tid >> 6;
    const int lane = tid & 63;
    const int q    = lane >> 4;
    const int ln   = lane & 15;

    const int sr = tid >> 3, k8 = tid & 7;
    const bf16* pa[4];
    const bf16* pb[2];
    int wa[4], wb[2];
#pragma unroll
    for (int i = 0; i < 4; ++i) {
        pa[i] = A + (long)(sr + i * 32) * K + k8 * 8;
        wa[i] = (sr + i * 32) * 72 + k8 * 8;
    }
#pragma unroll
    for (int i = 0; i < 2; ++i) {
        pb[i] = Bt + (long)(sr + i * 32) * K + k8 * 8;
        wb[i] = (sr + i * 32) * 72 + k8 * 8;
    }

#pragma unroll
    for (int i = 0; i < 2; ++i)
#pragma unroll
        for (int j = 0; j < 4; ++j)
            R.acc[i][j] = (f32x4){0.f, 0.f, 0.f, 0.f};

    for (int k0 = 0; k0 < K; k0 += 64) {
        uint4 va[4], vb[2];
#pragma unroll
        for (int i = 0; i < 4; ++i) va[i] = *(const uint4*)(pa[i] + k0);
#pragma unroll
        for (int i = 0; i < 2; ++i) vb[i] = *(const uint4*)(pb[i] + k0);
        __syncthreads();
#pragma unroll
        for (int i = 0; i < 4; ++i) *(uint4*)&Asm[wa[i]] = va[i];
#pragma unroll
        for (int i = 0; i < 2; ++i) *(uint4*)&Bsm[wb[i]] = vb[i];
        __syncthreads();

#pragma unroll
        for (int kc = 0; kc < 2; ++kc) {
            short8 af[2], bfr[4];
#pragma unroll
            for (int mt = 0; mt < 2; ++mt) {
                int m = wave * 32 + mt * 16 + ln;
                af[mt] = *(const short8*)&Asm[m * 72 + kc * 32 + q * 8];
            }
#pragma unroll
            for (int nt = 0; nt < 4; ++nt) {
                int n = nt * 16 + ln;
                bfr[nt] = *(const short8*)&Bsm[n * 72 + kc * 32 + q * 8];
            }
#pragma unroll
            for (int mt = 0; mt < 2; ++mt)
#pragma unroll
                for (int nt = 0; nt < 4; ++nt)
                    R.acc[mt][nt] = __builtin_amdgcn_mfma_f32_16x16x32_bf16(
                        af[mt], bfr[nt], R.acc[mt][nt], 0, 0, 0);
        }
    }
}

// ---------------------------------------------------------------------------
// HALF-HEIGHT n64 core — acc = A(64,K) @ Bt(64,K)^T (validated r9).
// ---------------------------------------------------------------------------
struct N64hAcc { f32x4 acc[4]; };

template <typename DUMMY = void>
DEVINL void n64h_core(const bf16* A, const bf16* Bt, int K,
                      unsigned short* Asm, unsigned short* Bsm, N64hAcc& R)
{
    const int tid  = threadIdx.x;
    const int wave = tid >> 6;
    const int lane = tid & 63;
    const int q    = lane >> 4;
    const int ln   = lane & 15;

    const int sr = tid >> 3, k8 = tid & 7;   // sr 0..31, k8 0..7
    const bf16* pa[2];
    const bf16* pb[2];
    int wa[2], wb[2];
#pragma unroll
    for (int i = 0; i < 2; ++i) {
        pa[i] = A  + (long)(sr + i * 32) * K + k8 * 8;
        wa[i] = (sr + i * 32) * 72 + k8 * 8;
        pb[i] = Bt + (long)(sr + i * 32) * K + k8 * 8;
        wb[i] = wa[i];
    }

#pragma unroll
    for (int j = 0; j < 4; ++j)
        R.acc[j] = (f32x4){0.f, 0.f, 0.f, 0.f};

    for (int k0 = 0; k0 < K; k0 += 64) {
        uint4 va[2], vb[2];
#pragma unroll
        for (int i = 0; i < 2; ++i) va[i] = *(const uint4*)(pa[i] + k0);
#pragma unroll
        for (int i = 0; i < 2; ++i) vb[i] = *(const uint4*)(pb[i] + k0);
        __syncthreads();
#pragma unroll
        for (int i = 0; i < 2; ++i) *(uint4*)&Asm[wa[i]] = va[i];
#pragma unroll
        for (int i = 0; i < 2; ++i) *(uint4*)&Bsm[wb[i]] = vb[i];
        __syncthreads();

#pragma unroll
        for (int kc = 0; kc < 2; ++kc) {
            short8 af;
            af = *(const short8*)&Asm[(wave * 16 + ln) * 72 + kc * 32 + q * 8];
            short8 bfr[4];
#pragma unroll
            for (int nt = 0; nt < 4; ++nt) {
                int n = nt * 16 + ln;
                bfr[nt] = *(const short8*)&Bsm[n * 72 + kc * 32 + q * 8];
            }
#pragma unroll
            for (int nt = 0; nt < 4; ++nt)
                R.acc[nt] = __builtin_amdgcn_mfma_f32_16x16x32_bf16(
                    af, bfr[nt], R.acc[nt], 0, 0, 0);
        }
    }
}

// ---------------------------------------------------------------------------
// Round 27: FUSED row-softmax + merged y kernel (Path A). Each block owns
// COMPLETE rows of Smix (64 rows x 768 = full K), so the softmax is
// block-local: phase 0 computes per-row max/inv (wave-per-row, validated
// softmax_rows_w math); phase 1 is the n64h K-loop with A-staging loading
// Smix f32 and converting bf16(exp(v-m)*inv) on the fly — identical values
// and rounding to softmax_rows_w -> absmax unchanged. Kills the softmax6
// launch and the A bf16 round-trip (-37.7 MB HBM). R2 core unchanged.
// ---------------------------------------------------------------------------
__global__ __launch_bounds__(256) void gemm_n64_both_sm(
    const float* __restrict__ Smixg, const bf16* __restrict__ v1t,
    const bf16* __restrict__ Craw, const bf16* __restrict__ v2t,
    const float* __restrict__ smallf, bf16* __restrict__ yc,
    long sA, long sB)
{
    __shared__ unsigned short Asm[64 * 72];
    __shared__ unsigned short Bsm[64 * 72];
    __shared__ float mrow[64], irow[64];

    const int bh = blockIdx.z;
    const int by = blockIdx.y;
    const float* Sx = Smixg + (long)bh * (Nc * Nc) + (long)(by * 64) * Nc;

    const int tid  = threadIdx.x;
    const int wave = tid >> 6;
    const int lane = tid & 63;
    const int q    = lane >> 4;
    const int ln   = lane & 15;

    // ---- phase 0: row stats (wave-per-row; 16 rows per wave) ----
    for (int rr = 0; rr < 16; ++rr) {
        const int row = wave * 16 + rr;
        const float* s = &Sx[(long)row * Nc];
        float4 v[3];
#pragma unroll
        for (int i = 0; i < 3; ++i)
            v[i] = *(const float4*)&s[i * 256 + lane * 4];
        float m = -1e30f;
#pragma unroll
        for (int i = 0; i < 3; ++i)
            m = fmaxf(m, fmaxf(fmaxf(v[i].x, v[i].y), fmaxf(v[i].z, v[i].w)));
#pragma unroll
        for (int off = 32; off > 0; off >>= 1)
            m = fmaxf(m, __shfl_xor(m, off, 64));
        float sum = 0.f;
#pragma unroll
        for (int i = 0; i < 3; ++i) {
            sum += __expf(v[i].x - m) + __expf(v[i].y - m) +
                   __expf(v[i].z - m) + __expf(v[i].w - m);
        }
#pragma unroll
        for (int off = 32; off > 0; off >>= 1)
            sum += __shfl_xor(sum, off, 64);
        if (lane == 0) {
            mrow[row] = m;
            irow[row] = 1.f / fmaxf(sum, 1e-30f);
        }
    }
    __syncthreads();

    // ---- phase 1: R1 = softmax(Smix) @ v1t (A converted during staging) ----
    const int sr = tid >> 3, k8 = tid & 7;
    const bf16* BtV = v1t + (long)bh * sB;
    const bf16* pb[2];
    int wz[2];
#pragma unroll
    for (int i = 0; i < 2; ++i) {
        pb[i] = BtV + (long)(sr + i * 32) * Nc + k8 * 8;
        wz[i] = (sr + i * 32) * 72 + k8 * 8;
    }

    N64hAcc R1;
#pragma unroll
    for (int j = 0; j < 4; ++j) R1.acc[j] = (f32x4){0.f, 0.f, 0.f, 0.f};

    for (int k0 = 0; k0 < Nc; k0 += 64) {
        float4 xa[2][2];
        uint4 vb[2];
#pragma unroll
        for (int i = 0; i < 2; ++i) {
            const long base = (long)(sr + i * 32) * Nc + k0 + k8 * 8;
            xa[i][0] = *(const float4*)&Sx[base];
            xa[i][1] = *(const float4*)&Sx[base + 4];
        }
#pragma unroll
        for (int i = 0; i < 2; ++i) vb[i] = *(const uint4*)(pb[i] + k0);
        __syncthreads();   // prior MFMA reads done
#pragma unroll
        for (int i = 0; i < 2; ++i) {
            const int row = sr + i * 32;
            const float m = mrow[row], iv = irow[row];
            const float* xf = (const float*)&xa[i][0];
            unsigned short o[8];
#pragma unroll
            for (int j = 0; j < 8; ++j) {
                const bf16 bb = __float2bfloat16(__expf(xf[j] - m) * iv);
                o[j] = *(const unsigned short*)&bb;
            }
            *(uint4*)&Asm[wz[i]] = *(const uint4*)o;
        }
#pragma unroll
        for (int i = 0; i < 2; ++i) *(uint4*)&Bsm[wz[i]] = vb[i];
        __syncthreads();

#pragma unroll
        for (int kc = 0; kc < 2; ++kc) {
            const short8 af =
                *(const short8*)&Asm[(wave * 16 + ln) * 72 + kc * 32 + q * 8];
            short8 bfr[4];
#pragma unroll
            for (int nt = 0; nt < 4; ++nt) {
                int n = nt * 16 + ln;
                bfr[nt] = *(const short8*)&Bsm[n * 72 + kc * 32 + q * 8];
            }
#pragma unroll
            for (int nt = 0; nt < 4; ++nt)
                R1.acc[nt] = __builtin_amdgcn_mfma_f32_16x16x32_bf16(
                    af, bfr[nt], R1.acc[nt], 0, 0, 0);
        }
    }

    // ---- phase 2: R2 = C_right_raw @ v2t (unchanged core) ----
    N64hAcc R2;
    n64h_core(Craw + (long)bh * sA + (long)(by * 64) * Nc,
              v2t + (long)bh * sB, Nc, Asm, Bsm, R2);

    const float w = sigf(smallf[392]);
    const int b = bh >> 3, h = bh & 7;
#pragma unroll
    for (int nt = 0; nt < 4; ++nt) {
        const int col  = nt * 16 + ln;
        const int rowb = by * 64 + wave * 16 + q * 4;
#pragma unroll
        for (int r = 0; r < 4; ++r) {
            const int n = rowb + r;
            yc[((long)(b * Nc + n)) * Dc + h * DKc + col] =
                __float2bfloat16(R1.acc[nt][r] + w * R2.acc[nt][r]);
        }
    }
}

// ---------------------------------------------------------------------------
// Merged pair launch (Path-B fallback only; validated round 11).
// ---------------------------------------------------------------------------
__global__ __launch_bounds__(256) void gemm_n64_pair(
    const bf16* __restrict__ A0g, const bf16* __restrict__ B0g, bf16* __restrict__ C0tg,
    const bf16* __restrict__ A1g, const bf16* __restrict__ B1g, bf16* __restrict__ C1g,
    int M, int K, long sA, long sB, long sC)
{
    __shared__ unsigned short Asm[128 * 72];
    __shared__ unsigned short Bsm[64 * 72];

    const int zz = blockIdx.z & 15;
    const int second = blockIdx.z >> 4;
    const bf16* A  = (second ? A1g : A0g) + (long)zz * sA + (long)(blockIdx.y * 128) * K;
    const bf16* Bt = (second ? B1g : B0g) + (long)zz * sB;

    N64Acc R;
    n64_core(A, Bt, K, Asm, Bsm, R);

    const int tid = threadIdx.x;
    const int wave = tid >> 6, lane = tid & 63, q = lane >> 4, ln = lane & 15;

    if (second) {
        bf16* C = C1g + (long)zz * sC;
#pragma unroll
        for (int mt = 0; mt < 2; ++mt) {
#pragma unroll
            for (int nt = 0; nt < 4; ++nt) {
                const int col  = nt * 16 + ln;
                const int rowb = blockIdx.y * 128 + wave * 32 + mt * 16 + q * 4;
#pragma unroll
                for (int r = 0; r < 4; ++r)
                    C[(long)(rowb + r) * 64 + col] = __float2bfloat16(R.acc[mt][nt][r]);
            }
        }
    } else {
        __syncthreads();
#pragma unroll
        for (int mt = 0; mt < 2; ++mt) {
#pragma unroll
            for (int nt = 0; nt < 4; ++nt) {
                const int col = nt * 16 + ln;
                const int rwb = wave * 32 + mt * 16 + q * 4;
#pragma unroll
                for (int r = 0; r < 4; ++r)
                    *(bf16*)&Asm[col * 136 + rwb + r] = __float2bfloat16(R.acc[mt][nt][r]);
            }
        }
        __syncthreads();
        bf16* Ct = C0tg + (long)zz * sC;
        const int dk  = tid >> 2;
        const int nc0 = (tid & 3) * 32;
        const int gn0 = blockIdx.y * 128;
#pragma unroll
        for (int c8 = 0; c8 < 4; ++c8) {
            uint4 v = *(const uint4*)&Asm[dk * 136 + nc0 + c8 * 8];
            *(uint4*)&Ct[(long)dk * Nc + gn0 + nc0 + c8 * 8] = v;
        }
    }
}

// y_chain GEMM with fused combine + permute (Path-B fallback only).
__global__ __launch_bounds__(256) void gemm_n64_combine(
    const bf16* __restrict__ A1b, const bf16* __restrict__ trt,
    const bf16* __restrict__ yb1, const float* __restrict__ smallf,
    bf16* __restrict__ yc, int M, int K, long sA, long sB)
{
    __shared__ unsigned short Asm[128 * 72];
    __shared__ unsigned short Bsm[64 * 72];

    const int bh = blockIdx.z;
    const bf16* A  = A1b + (long)bh * sA + (long)(blockIdx.y * 128) * K;
    const bf16* Bt = trt + (long)bh * sB;

    N64Acc R;
    n64_core(A, Bt, K, Asm, Bsm, R);

    const float w = sigf(smallf[392]);
    const int b = bh >> 3, h = bh & 7;
    const long yb1base = (long)bh * Nc * DKc;

    const int tid = threadIdx.x;
    const int wave = tid >> 6, lane = tid & 63, q = lane >> 4, ln = lane & 15;
#pragma unroll
    for (int mt = 0; mt < 2; ++mt) {
#pragma unroll
        for (int nt = 0; nt < 4; ++nt) {
            const int col  = nt * 16 + ln;
            const int rowb = blockIdx.y * 128 + wave * 32 + mt * 16 + q * 4;
#pragma unroll
            for (int r = 0; r < 4; ++r) {
                const int n = rowb + r;
                const float base = __bfloat162float(yb1[yb1base + (long)n * 64 + col]);
                yc[((long)(b * Nc + n)) * Dc + h * DKc + col] =
                    __float2bfloat16(base + w * R.acc[mt][nt][r]);
            }
        }
    }
}

// Path-B y_base GEMM (fallback only).
__global__ __launch_bounds__(256) void gemm_n64_yb(
    const bf16* __restrict__ Ag, const bf16* __restrict__ Btg,
    bf16* __restrict__ Cg, int M, int K, long sA, long sB, long sC)
{
    __shared__ unsigned short Asm[128 * 72];
    __shared__ unsigned short Bsm[64 * 72];

    const int zz = blockIdx.z;
    const bf16* A  = Ag + (long)zz * sA + (long)(blockIdx.y * 128) * K;
    const bf16* Bt = Btg + (long)zz * sB;

    N64Acc R;
    n64_core(A, Bt, K, Asm, Bsm, R);

    bf16* C = Cg + (long)zz * sC;
    const int tid = threadIdx.x;
    const int wave = tid >> 6, lane = tid & 63, q = lane >> 4, ln = lane & 15;
#pragma unroll
    for (int mt = 0; mt < 2; ++mt) {
#pragma unroll
        for (int nt = 0; nt < 4; ++nt) {
            const int col  = nt * 16 + ln;
            const int rowb = blockIdx.y * 128 + wave * 32 + mt * 16 + q * 4;
#pragma unroll
            for (int r = 0; r < 4; ++r)
                C[(long)(rowb + r) * 64 + col] = __float2bfloat16(R.acc[mt][nt][r]);
        }
    }
}

// ---------------------------------------------------------------------------
// Row softmax over width 768 — wave-per-row (Path-B fallback only now).
// ---------------------------------------------------------------------------
__global__ __launch_bounds__(256) void softmax_rows_w(
    const float* __restrict__ src, bf16* __restrict__ dst)
{
    const int wid  = threadIdx.x >> 6;
    const int lane = threadIdx.x & 63;
    const long row = (long)blockIdx.x * 4 + wid;
    const float* s = src + row * Nc;

    float4 v[3];
#pragma unroll
    for (int i = 0; i < 3; ++i)
        v[i] = *(const float4*)&s[i * 256 + lane * 4];

    float m = -1e30f;
#pragma unroll
    for (int i = 0; i < 3; ++i)
        m = fmaxf(m, fmaxf(fmaxf(v[i].x, v[i].y), fmaxf(v[i].z, v[i].w)));
#pragma unroll
    for (int off = 32; off > 0; off >>= 1)
        m = fmaxf(m, __shfl_xor(m, off, 64));

    float e[12];
    float sum = 0.f;
#pragma unroll
    for (int i = 0; i < 3; ++i) {
        e[i * 4 + 0] = __expf(v[i].x - m);
        e[i * 4 + 1] = __expf(v[i].y - m);
        e[i * 4 + 2] = __expf(v[i].z - m);
        e[i * 4 + 3] = __expf(v[i].w - m);
        sum += e[i * 4 + 0] + e[i * 4 + 1] + e[i * 4 + 2] + e[i * 4 + 3];
    }
#pragma unroll
    for (int off = 32; off > 0; off >>= 1)
        sum += __shfl_xor(sum, off, 64);

    const float inv = 1.f / fmaxf(sum, 1e-30f);
    unsigned short* d = (unsigned short*)dst + row * Nc;
#pragma unroll
    for (int i = 0; i < 3; ++i) {
        unsigned short o[4];
#pragma unroll
        for (int j = 0; j < 4; ++j) {
            const bf16 b = __float2bfloat16(e[i * 4 + j] * inv);
            o[j] = *(const unsigned short*)&b;
        }
        *(uint2*)&d[i * 256 + lane * 4] = *(const uint2*)o;
    }
}

// ---------------------------------------------------------------------------
// Gate network + Smix — r7-validated 2-elem body, 32x16 tiling (frozen;
// r11 lesson: this tiling is load-bearing for L2 reuse).
// ---------------------------------------------------------------------------
__global__ __launch_bounds__(256) void gates_smix(
    const float* __restrict__ S1g, const float* __restrict__ S2g,
    const bf16* __restrict__ Crg, const bf16* __restrict__ Clg,
    float* __restrict__ Smixg, const float* __restrict__ smallf)
{
    __shared__ float t1t[32][17], t2t[32][17];

    const long mat = (long)blockIdx.z * Nc * Nc;
    const float* S1 = S1g + mat;
    const float* S2 = S2g + mat;
    const unsigned short* Cr = (const unsigned short*)Crg + mat;
    const unsigned short* Cl = (const unsigned short*)Clg + mat;
    float* Smix = Smixg + mat;

    const int tid = threadIdx.x;

    const int n0 = blockIdx.y * 16, m0 = blockIdx.x * 32;
    {
        const int r = tid >> 3, c2 = (tid & 7) * 2;
        const float2 a = *(const float2*)&S1[(long)(m0 + r) * Nc + n0 + c2];
        const float2 b = *(const float2*)&S2[(long)(m0 + r) * Nc + n0 + c2];
        t1t[r][c2] = a.x; t1t[r][c2 + 1] = a.y;
        t2t[r][c2] = b.x; t2t[r][c2 + 1] = b.y;
    }
    __syncthreads();

    const int tx = tid & 15, ty = tid >> 4;
    const int n = n0 + ty;
    const long idx = (long)n * Nc + m0 + tx * 2;

    const float2 s1v = *(const float2*)&S1[idx];
    const float2 s2v = *(const float2*)&S2[idx];
    const unsigned cru = *(const unsigned*)&Cr[idx];
    const unsigned clu = *(const unsigned*)&Cl[idx];

    const f32x2 s1a = {s1v.x, s1v.y};
    const f32x2 s2a = {s2v.x, s2v.y};
    const f32x2 cra = {__uint_as_float((cru & 0xffffu) << 16),
                       __uint_as_float(cru & 0xffff0000u)};
    const f32x2 cla = {__uint_as_float((clu & 0xffffu) << 16),
                       __uint_as_float(clu & 0xffff0000u)};
    const f32x2 s1t = {t1t[tx * 2][ty], t1t[tx * 2 + 1][ty]};
    const f32x2 s2t = {t2t[tx * 2][ty], t2t[tx * 2 + 1][ty]};

    f32x2 g0 = *(const f32x2*)&smallf[384];
    f32x2 g1 = *(const f32x2*)&smallf[386];
    f32x2 g2 = *(const f32x2*)&smallf[388];
    f32x2 g3 = *(const f32x2*)&smallf[390];

    const f32x2 gc1  = splat2(-2.30220902f);
    const f32x2 gc3  = splat2(-0.10294357f);
    const f32x2 one2 = splat2(1.f);

#pragma unroll
    for (int u = 0; u < 16; ++u) {
        const f32x2* cw = (const f32x2*)&smallf[u * 24];
        f32x2 h = cw[6];
        h = fma2(s1a, cw[0], h);
        h = fma2(s2a, cw[1], h);
        h = fma2(s1t, cw[2], h);
        h = fma2(s2t, cw[3], h);
        h = fma2(cra, cw[4], h);
        h = fma2(cla, cw[5], h);
        const f32x2 hh = h * h;
        const f32x2 z2 = h * fma2(hh, gc3, gc1);
        f32x2 e;  e[0]  = vexp2(z2[0]); e[1]  = vexp2(z2[1]);
        const f32x2 d = one2 + e;
        f32x2 rc; rc[0] = vrcp(d[0]);   rc[1] = vrcp(d[1]);
        const f32x2 hid = h * rc;
        g0 = fma2(hid, cw[8],  g0);
        g1 = fma2(hid, cw[9],  g1);
        g2 = fma2(hid, cw[10], g2);
        g3 = fma2(hid, cw[11], g3);
    }

    const f32x2 nl2e = splat2(-1.44269504f);
    const f32x2 ln2v = splat2(0.69314718f);
    auto sig2 = [&](f32x2 x) -> f32x2 {
        const f32x2 t = x * nl2e;
        f32x2 e;  e[0] = vexp2(t[0]); e[1] = vexp2(t[1]);
        const f32x2 d = one2 + e;
        f32x2 r;  r[0] = vrcp(d[0]);  r[1] = vrcp(d[1]);
        return r;
    };
    const f32x2 ga2 = sig2(g0);
    const f32x2 go2 = sig2(g1);
    const f32x2 gn2 = sig2(g2);
    const f32x2 gc2 = sig2(g3);

    const f32x2 dd = s1a - s2a;
    f32x2 ad; ad[0] = fabsf(dd[0]); ad[1] = fabsf(dd[1]);
    const f32x2 t2 = ad * nl2e;
    f32x2 ee; ee[0] = vexp2(t2[0]); ee[1] = vexp2(t2[1]);
    const f32x2 lp = one2 + ee;
    f32x2 lg; lg[0] = vlog2(lp[0]); lg[1] = vlog2(lp[1]);
    const f32x2 mx2 = __builtin_elementwise_max(s1a, s2a);
    const f32x2 lae = fma2(lg, ln2v, mx2);

    f32x2 o2 = s1a;
    o2 = fma2(ga2, s2a, o2);
    o2 = fma2(go2, lae - s1a, o2);
    o2 = fma2(gn2, s2a * splat2(-BETA_NOT), o2);
    o2 = fma2(gc2, cra, o2);
    *(float2*)&Smix[idx] = (float2){o2[0], o2[1]};
}

// ---------------------------------------------------------------------------
// Final projection, half-height tiles — 192 blocks (validated r9).
// ---------------------------------------------------------------------------
__global__ __launch_bounds__(256) void proj_n64h(
    const bf16* __restrict__ yc, const bf16* __restrict__ pwt,
    const void* __restrict__ xraw, void* __restrict__ out)
{
    constexpr int K = Dc;  // 512
    constexpr int N = Dc;  // 512
    __shared__ unsigned short Asm[64 * 72];
    __shared__ unsigned short Bsm[64 * 72];
    __shared__ int is32s;
    if (threadIdx.x == 0) is32s = sniff_is_fp32(xraw);

    const bf16* A  = yc  + (long)(blockIdx.y * 64) * K;
    const bf16* Bt = pwt + (long)(blockIdx.x * 64) * K;

    N64hAcc R;
    n64h_core(A, Bt, K, Asm, Bsm, R);   // internal barriers publish is32s

    const int is32 = is32s;
    const int tid = threadIdx.x;
    const int wave = tid >> 6, lane = tid & 63, q = lane >> 4, ln = lane & 15;
#pragma unroll
    for (int nt = 0; nt < 4; ++nt) {
        const int col  = blockIdx.x * 64 + nt * 16 + ln;
        const int rowb = blockIdx.y * 64 + wave * 16 + q * 4;
#pragma unroll
        for (int r = 0; r < 4; ++r) {
            const long o = (long)(rowb + r) * N + col;
            if (is32) ((float*)out)[o] = R.acc[nt][r];
            else      ((bf16*)out)[o] = __float2bfloat16(R.acc[nt][r]);
        }
    }
}

// ---------------------------------------------------------------------------
extern "C" void kernel_launch(void* const* d_in, const int* in_sizes, int n_in,
                              void* d_out, int out_size, void* d_ws, size_t ws_size,
                              hipStream_t stream)
{
    const size_t HD   = (size_t)BHc * Nc * DKc;   // 786432
    const size_t HDh  = HD / 2;                   // float-slots for HD bf16
    const size_t MAT  = (size_t)Nc * Nc;          // 589824
    const size_t MATS = (size_t)BHc * MAT;        // 9437184
    const long   HSTR = (long)Nc * DKc;           // 49152 per-head stride

    float* ws = (float*)d_ws;
    size_t off = 0;
    auto alloc = [&](size_t n) { float* p = ws + off; off += n; return p; };

    bf16* xb  = (bf16*)alloc(HDh);
    bf16* w1t = (bf16*)alloc(HDh);
    bf16* w2t = (bf16*)alloc(HDh);
    bf16* pwt = (bf16*)alloc((size_t)Dc * Dc / 2);
    float* smallf = alloc(512);
    // q1|q2 and k1|k2 adjacent -> single merged fused-S launch (32 batches)
    bf16* q1b = (bf16*)alloc(HDh); bf16* q2b = (bf16*)alloc(HDh);
    bf16* k1b = (bf16*)alloc(HDh); bf16* k2b = (bf16*)alloc(HDh);
    bf16* v1t = (bf16*)alloc(HDh); bf16* v2t = (bf16*)alloc(HDh);  // adjacent
    bf16* trt = (bf16*)alloc(HDh);
    float* S1   = alloc(MATS);       // S1/S2 adjacent
    float* S2   = alloc(MATS);
    float* Smix = alloc(MATS);       // region reused: A1tb|A2tb, then Smix
    bf16* A1b = (bf16*)alloc(MATS / 2);  // A1b/A2b adjacent
    bf16* A2b = (bf16*)alloc(MATS / 2);
    bf16* Crb = (bf16*)alloc(MATS / 2);  // Crb/Clb adjacent (merged launch)
    bf16* Clb = (bf16*)alloc(MATS / 2);
    bf16* yb1 = (bf16*)alloc(HDh);
    bf16* yc  = (bf16*)alloc(HDh);

    const size_t NEED_BASE = off * sizeof(float);
    bf16* Crawb = (bf16*)alloc(MATS / 2);          // raw C_right (Path A only)
    const size_t NEED_A = off * sizeof(float);
    const int pathA = ws_size >= NEED_A;

    // aliases into dead regions
    bf16* A1tb = (bf16*)Smix;            // live steps 3-4 (dead once gates writes Smix)
    bf16* A2tb = ((bf16*)Smix) + MATS;
    bf16* Ab   = (bf16*)S1;              // Path B only: S1 dead after gates

    if (ws_size < NEED_BASE) {
        fill_sentinel<<<dim3(3072), 256, 0, stream>>>((unsigned short*)d_out);
        return;
    }

    // 0+1. FUSED convert + W/pw transpose; QKV 64x128 tiles (V transposed)
    convert_tr<<<dim3(833), 256, 0, stream>>>(
        d_in[0], d_in[1], d_in[2], d_in[3], d_in[4], d_in[5], d_in[6], d_in[7],
        d_in[8], xb, w1t, w2t, pwt, smallf);
    qkv_mfma64<<<dim3(12, 24, 2), 256, 0, stream>>>(
        xb, w1t, w2t, q1b, k1b, v1t, q2b, k2b, v2t);

    // 2+3. FUSED: S = scale*q@k^T, row softmax -> A, A^T (validated r10)
    sgemm_softmax<<<dim3(1536), 256, 0, stream>>>(
        q1b, k1b, S1, A1b, A1tb);

    // 4. Cr|Cl in ONE 32-batch launch; XCD-pinned 1-D grid; 2-phase K-loop;
    //    Path A also stores raw C_right.
    if (pathA)
        gemm_nt_mfma<1, bf16, 1, 1, 1><<<dim3(1152), 256, 0, stream>>>(
            A1b, A1tb, Crb, Crawb, Nc, Nc, Nc, (long)MAT, (long)MAT, (long)MAT, 1.f);
    else
        gemm_nt_mfma<1, bf16, 1, 1, 0><<<dim3(1152), 256, 0, stream>>>(
            A1b, A1tb, Crb, nullptr, Nc, Nc, Nc, (long)MAT, (long)MAT, (long)MAT, 1.f);

    // 5. gates + Smix (r7-validated 2-elem body, 32x16 tiling)
    gates_smix<<<dim3(24, 48, BHc), 256, 0, stream>>>(S1, S2, Crb, Clb, Smix, smallf);

    if (pathA) {
        // 6+7. FUSED row-softmax + merged y (one launch, 192 blocks):
        //      reads Smix directly, converts during A-staging.
        gemm_n64_both_sm<<<dim3(1, 12, BHc), 256, 0, stream>>>(
            Smix, v1t, Crawb, v2t, smallf, yc, (long)MAT, HSTR);
    } else {
        // Path B fallback (round-12 structure)
        softmax_rows_w<<<(BHc * Nc) / 4, 256, 0, stream>>>(Smix, Ab);
        gemm_n64_pair<<<dim3(1, 6, 2 * BHc), 256, 0, stream>>>(
            A2b, v2t, trt, Ab, v1t, yb1, Nc, Nc, (long)MAT, HSTR, HSTR);
        gemm_n64_combine<<<dim3(1, 6, BHc), 256, 0, stream>>>(
            A1b, trt, yb1, smallf, yc, Nc, Nc, (long)MAT, HSTR);
    }

    // 9. proj, half-height tiles: 192 blocks
    proj_n64h<<<dim3(8, 24, 1), 256, 0, stream>>>(yc, pwt, d_in[0], d_out);
}